// Round 4
// baseline (1714.886 us; speedup 1.0000x reference)
//
#include <hip/hip_runtime.h>
#include <cstddef>

// ---- problem constants ----
constexpr int kT   = 1024;
constexpr int kB   = 64;
constexpr int kDIN = 17;
constexpr int kHM  = 150;   // main hidden (per dir)
constexpr int kHH  = 128;   // hier hidden (per dir)
constexpr int kM   = 16;    // measure length
constexpr int kD2  = 300;   // 2*kHM
constexpr int kDH2 = 256;   // 2*kHH
constexpr int kNP  = 35;
constexpr int kNK  = 15;

// ---- workspace layout (float offsets, all 16-float aligned) ----
constexpr size_t OFF_RNN    = 0;          // [1024][64][300]   19,660,800
constexpr size_t OFF_HV     = 19660800;   // [4096][16][256]   16,777,216
constexpr size_t OFF_CTX    = 36438016;   // [4096][256]        1,048,576
constexpr size_t OFF_PT     = 37486592;   // [256][256]            65,536
constexpr size_t OFF_U      = 37552128;   // [256]
constexpr size_t OFF_W      = 37552384;   // [256]
constexpr size_t OFF_C0     = 37552640;   // [16]
constexpr size_t OFF_ACC    = 37552656;   // [16] (sp,cp,sk,ck)
constexpr size_t OFF_KSLOGP = 37552672;   // [4096][15]            61,440
constexpr size_t OFF_CLOG   = 37614112;   // [4096][35]           143,360
constexpr size_t OFF_BPACKM = 37757472;   // ushort [2][30][6][64][8] = 184,320 us = 92,160 f
constexpr size_t OFF_BPACK  = 37907792;   // ushort [2][24][14][64][8] = 344,064 us = 172,032 f
// total < 38.1M floats = ~152.4 MB

typedef __bf16 bf16x8 __attribute__((ext_vector_type(8)));
typedef float f32x4 __attribute__((ext_vector_type(4)));

__device__ __forceinline__ unsigned short f2bf(float f) {
  unsigned u = __float_as_uint(f);
  u += 0x7FFFu + ((u >> 16) & 1u);   // round-to-nearest-even
  return (unsigned short)(u >> 16);
}
__device__ __forceinline__ float sigm(float x) { return 1.f / (1.f + __expf(-x)); }

// PT[e][c] = sum_a Wq[a][c]*Wv[a][e]   (= (Wq^T Wv)[c][e])
__global__ void k_pt(const float* __restrict__ Wq, const float* __restrict__ Wv,
                     float* __restrict__ PT) {
  const int e = blockIdx.x, c = threadIdx.x;
  float acc = 0.f;
  for (int a = 0; a < 256; a++) acc += Wq[a * 256 + c] * Wv[a * 256 + e];
  PT[e * 256 + c] = acc;
}

__global__ void k_small(const float* __restrict__ Wq, const float* __restrict__ bq,
                        const float* __restrict__ Wv, const float* __restrict__ bv,
                        float* __restrict__ u, float* __restrict__ w,
                        float* __restrict__ c0, float* __restrict__ acc) {
  const int a = threadIdx.x; // 256
  float us = 0.f, ws = 0.f;
  for (int j = 0; j < 256; j++) {
    us += Wq[j * 256 + a] * bv[j];
    ws += bq[j] * Wv[j * 256 + a];
  }
  u[a] = us; w[a] = ws;
  if (a == 0) {
    float c = 0.f;
    for (int j = 0; j < 256; j++) c += bq[j] * bv[j];
    c0[0] = c;
    acc[0] = acc[1] = acc[2] = acc[3] = 0.f;
  }
}

// ---------------------------------------------------------------------------
// Repack hier weights into bf16 MFMA B-fragment order (validated r2):
// bpack[d][nt(24)][kt(14)][lane(64)][j(8)]
__global__ void k_repack(const float* __restrict__ hWih_f, const float* __restrict__ hWhh_f,
                         const float* __restrict__ hWih_b, const float* __restrict__ hWhh_b,
                         unsigned short* __restrict__ bpack) {
  const int bid = blockIdx.x;           // 2*24*14 = 672
  const int kt = bid % 14;
  const int nt = (bid / 14) % 24;
  const int d  = bid / (14 * 24);
  const float* Wih = d ? hWih_b : hWih_f;   // [384][300]
  const float* Whh = d ? hWhh_b : hWhh_f;   // [384][128]
  const int lane = threadIdx.x;
  const int n = nt * 16 + (lane & 15);
  const int kbase = kt * 32 + (lane >> 4) * 8;
  unsigned short* dst = bpack + ((((size_t)d * 24 + nt) * 14 + kt) * 64 + lane) * 8;
#pragma unroll
  for (int j = 0; j < 8; j++) {
    const int k = kbase + j;
    float f = 0.f;
    if (k < 300) f = Wih[n * 300 + k];
    else if (k >= 320) f = Whh[n * 128 + (k - 320)];
    dst[j] = f2bf(f);
  }
}

// ---------------------------------------------------------------------------
// Repack MAIN-GRU weights (validated r3): slot s = gt*16+col, type=s/160
// (r,z,n), j=s%160 (valid j<150). kt 0..4 -> Whh col kt*32+(lane>>4)*8+jj;
// kt 5 -> Wih col (lane>>4)*8+jj (valid <17).
// bpackM[d][gt(30)][kt(6)][lane(64)][jj(8)]
__global__ void k_repack_main(const float* __restrict__ mWih_f, const float* __restrict__ mWhh_f,
                              const float* __restrict__ mWih_b, const float* __restrict__ mWhh_b,
                              unsigned short* __restrict__ bpackM) {
  const int bid = blockIdx.x;          // 2*30*6 = 360
  const int kt = bid % 6;
  const int gt = (bid / 6) % 30;
  const int d  = bid / 180;
  const float* Wih = d ? mWih_b : mWih_f;  // [450][17]
  const float* Whh = d ? mWhh_b : mWhh_f;  // [450][150]
  const int lane = threadIdx.x;
  const int slot = gt * 16 + (lane & 15);
  const int type = slot / 160, j = slot - type * 160;
  const int row = type * 150 + j;
  const bool valid = (j < 150);
  const int kbase = (lane >> 4) * 8;
  unsigned short* dst = bpackM + ((((size_t)d * 30 + gt) * 6 + kt) * 64 + lane) * 8;
#pragma unroll
  for (int jj = 0; jj < 8; jj++) {
    float f = 0.f;
    if (valid) {
      if (kt < 5) {
        const int k = kt * 32 + kbase + jj;
        if (k < 150) f = Whh[row * 150 + k];
      } else {
        const int k = kbase + jj;
        if (k < 17) f = Wih[row * 17 + k];
      }
    }
    dst[jj] = f2bf(f);
  }
}

// ---------------------------------------------------------------------------
// Main bi-GRU via M=1 MFMA, 5 waves (320 thr). Wave w owns gate-tile triples
// {2w,10+2w,20+2w} and {2w+1,11+2w,21+2w} -> 36 B-frags (144 VGPR) in regs.
// A = bf16 [h(160)] from double-buffered LDS + x from LDS-resident xall
// (all 1024 steps preloaded, 64 KB). LDS pipe per step: 5 waves x 6 b128
// (halved vs r3's 10x6). One barrier per step. Lanes q<2 do activation
// (q selects triple; acc rows are broadcast copies so acc[0] is valid).
__global__ __launch_bounds__(320, 2) void k_main_gru_mfma(
    const float* __restrict__ x,               // [1024][64][17]
    const unsigned short* __restrict__ bpackM, // [2][30][6][64][8]
    const float* __restrict__ bihf, const float* __restrict__ bhhf,
    const float* __restrict__ bihb, const float* __restrict__ bhhb,
    float* __restrict__ rnn)                   // [1024][64][300]
{
  const int d = blockIdx.x & 1, b = blockIdx.x >> 1;
  const int tid = threadIdx.x, w = tid >> 6, lane = tid & 63;
  const int col = lane & 15, q = lane >> 4, q8 = q * 8;
  __shared__ __align__(16) unsigned short hx[2][160];      // h (150 valid, pad 0)
  __shared__ __align__(16) unsigned short xall[kT][32];    // all x, bf16, pad 0
  for (int i = tid; i < 2 * 160; i += 320) ((unsigned short*)hx)[i] = 0;
  for (int i = tid; i < kT * 32; i += 320) {
    const int t = i >> 5, c = i & 31;
    xall[t][c] = (c < kDIN) ? f2bf(x[((size_t)t * kB + b) * kDIN + c]) : (unsigned short)0;
  }
  const float* bih = d ? bihb : bihf;
  const float* bhh = d ? bhhb : bhhf;
  const int jj = 32 * w + (q & 1) * 16 + col;
  const bool actv = (q < 2) && (jj < kHM);
  float br = 0.f, bz = 0.f, bnx = 0.f, bnh = 0.f;
  if (actv) {
    br  = bih[jj] + bhh[jj];
    bz  = bih[150 + jj] + bhh[150 + jj];
    bnx = bih[300 + jj];
    bnh = bhh[300 + jj];
  }
  // 36 B-fragments in registers (6 tiles x 6 kt)
  bf16x8 bw[6][6];
  const unsigned short* bp = bpackM + (size_t)d * 30 * 6 * 64 * 8;
  const int gts[6] = { 2 * w, 2 * w + 1, 10 + 2 * w, 11 + 2 * w, 20 + 2 * w, 21 + 2 * w };
#pragma unroll
  for (int i = 0; i < 6; i++)
#pragma unroll
    for (int kt = 0; kt < 6; kt++)
      bw[i][kt] = *(const bf16x8*)&bp[(((size_t)gts[i] * 6 + kt) * 64 + lane) * 8];
  float h_old = 0.f;
  __syncthreads();

  for (int t = 0; t < kT; t++) {
    const int tx = d ? (kT - 1 - t) : t;
    const int buf = t & 1;
    f32x4 aR0 = (f32x4)(0.f), aR1 = (f32x4)(0.f);
    f32x4 aZ0 = (f32x4)(0.f), aZ1 = (f32x4)(0.f);
    f32x4 aN0 = (f32x4)(0.f), aN1 = (f32x4)(0.f);
    f32x4 aX0 = (f32x4)(0.f), aX1 = (f32x4)(0.f);
#pragma unroll
    for (int kt = 0; kt < 6; kt++) {
      const bf16x8 af = (kt < 5) ? *(const bf16x8*)&hx[buf][kt * 32 + q8]
                                 : *(const bf16x8*)&xall[tx][q8];
      aR0 = __builtin_amdgcn_mfma_f32_16x16x32_bf16(af, bw[0][kt], aR0, 0, 0, 0);
      aR1 = __builtin_amdgcn_mfma_f32_16x16x32_bf16(af, bw[1][kt], aR1, 0, 0, 0);
      aZ0 = __builtin_amdgcn_mfma_f32_16x16x32_bf16(af, bw[2][kt], aZ0, 0, 0, 0);
      aZ1 = __builtin_amdgcn_mfma_f32_16x16x32_bf16(af, bw[3][kt], aZ1, 0, 0, 0);
      if (kt < 5) {
        aN0 = __builtin_amdgcn_mfma_f32_16x16x32_bf16(af, bw[4][kt], aN0, 0, 0, 0);
        aN1 = __builtin_amdgcn_mfma_f32_16x16x32_bf16(af, bw[5][kt], aN1, 0, 0, 0);
      } else {
        aX0 = __builtin_amdgcn_mfma_f32_16x16x32_bf16(af, bw[4][5], aX0, 0, 0, 0);
        aX1 = __builtin_amdgcn_mfma_f32_16x16x32_bf16(af, bw[5][5], aX1, 0, 0, 0);
      }
    }
    if (actv) {
      const float vR = q ? aR1[0] : aR0[0];
      const float vZ = q ? aZ1[0] : aZ0[0];
      const float vN = q ? aN1[0] : aN0[0];
      const float vX = q ? aX1[0] : aX0[0];
      const float r = sigm(vR + br);
      const float z = sigm(vZ + bz);
      const float n = tanhf(vX + bnx + r * (vN + bnh));
      h_old = (1.f - z) * n + z * h_old;
      hx[buf ^ 1][jj] = f2bf(h_old);
      rnn[((size_t)tx * kB + b) * kD2 + d * kHM + jj] = h_old;
    }
    __syncthreads();
  }
}

// ---------------------------------------------------------------------------
// Hier bi-GRU via bf16 MFMA 16x16x32 (validated round 2).
__global__ __launch_bounds__(256) void k_hier_mfma(
    const float* __restrict__ rnn,             // [1024][64][300]
    const unsigned short* __restrict__ bpack,  // [2][24][14][64][8]
    const float* __restrict__ bihf, const float* __restrict__ bhhf,
    const float* __restrict__ bihb, const float* __restrict__ bhhb,
    float* __restrict__ hv)                    // [4096][16][256]
{
  const int d = blockIdx.x & 1;
  const int bn0 = (blockIdx.x >> 1) * 16;
  const int tid = threadIdx.x;
  const int w = tid >> 6;
  const int lane = tid & 63;
  const int q = lane >> 4, col = lane & 15;

  __shared__ __align__(16) unsigned short x_s[2][16][328];
  __shared__ __align__(16) unsigned short h_s[16][136];
  __shared__ __align__(16) float h32[16][136];

  for (int i = tid; i < 16 * 136; i += 256) { ((unsigned short*)h_s)[i] = 0; ((float*)h32)[i] = 0.f; }
  for (int i = tid; i < 2 * 16 * 28; i += 256) {
    const int bb2 = i / (16 * 28), rr2 = (i / 28) & 15, cc2 = 300 + (i % 28);
    x_s[bb2][rr2][cc2] = 0;
  }
  const float* bih = d ? bihb : bihf;
  const float* bhh = d ? bhhb : bhhf;
  const int j0 = w * 16 + col, j1 = 64 + w * 16 + col;
  const float biR0 = bih[j0] + bhh[j0],             biR1 = bih[j1] + bhh[j1];
  const float biZ0 = bih[128 + j0] + bhh[128 + j0], biZ1 = bih[128 + j1] + bhh[128 + j1];
  const float biNX0 = bih[256 + j0], biNX1 = bih[256 + j1];
  const float biNH0 = bhh[256 + j0], biNH1 = bhh[256 + j1];

  {
    const int mx0 = d ? 15 : 0;
    for (int i = tid; i < 16 * 300; i += 256) {
      const int r = i / 300, c = i - r * 300;
      const int bn = bn0 + r, bb = bn >> 6, nn = bn & 63;
      x_s[0][r][c] = f2bf(rnn[((nn * 16 + mx0) * 64 + bb) * 300 + c]);
    }
  }
  __syncthreads();

  const unsigned short* bpd = bpack + (size_t)d * 24 * 14 * 64 * 8;

  for (int m = 0; m < kM; m++) {
    const int mx = d ? (15 - m) : m;
    const int buf = m & 1;
    f32x4 aR[2], aZ[2], aNX[2], aNH[2];
#pragma unroll
    for (int t = 0; t < 2; t++) {
      aR[t] = (f32x4)(0.f); aZ[t] = (f32x4)(0.f);
      aNX[t] = (f32x4)(0.f); aNH[t] = (f32x4)(0.f);
    }
#pragma unroll
    for (int kt = 0; kt < 14; kt++) {
      bf16x8 af;
      if (kt < 10) af = *(const bf16x8*)&x_s[buf][col][kt * 32 + q * 8];
      else         af = *(const bf16x8*)&h_s[col][(kt - 10) * 32 + q * 8];
#pragma unroll
      for (int t = 0; t < 6; t++) {
        const int nt = w + 4 * t;
        const bf16x8 bfr = *(const bf16x8*)&bpd[(((size_t)nt * 14 + kt) * 64 + lane) * 8];
        if (t < 2)        aR[t]      = __builtin_amdgcn_mfma_f32_16x16x32_bf16(af, bfr, aR[t], 0, 0, 0);
        else if (t < 4)   aZ[t - 2]  = __builtin_amdgcn_mfma_f32_16x16x32_bf16(af, bfr, aZ[t - 2], 0, 0, 0);
        else if (kt < 10) aNX[t - 4] = __builtin_amdgcn_mfma_f32_16x16x32_bf16(af, bfr, aNX[t - 4], 0, 0, 0);
        else              aNH[t - 4] = __builtin_amdgcn_mfma_f32_16x16x32_bf16(af, bfr, aNH[t - 4], 0, 0, 0);
      }
    }
    __syncthreads();
#pragma unroll
    for (int jt = 0; jt < 2; jt++) {
      const int j = jt ? j1 : j0;
      const float bR = jt ? biR1 : biR0, bZ = jt ? biZ1 : biZ0;
      const float bNX = jt ? biNX1 : biNX0, bNH = jt ? biNH1 : biNH0;
#pragma unroll
      for (int i = 0; i < 4; i++) {
        const int row = q * 4 + i;
        const float rr = sigm(aR[jt][i] + bR);
        const float zz = sigm(aZ[jt][i] + bZ);
        const float hn = aNH[jt][i] + bNH;
        const float nn2 = tanhf(aNX[jt][i] + bNX + rr * hn);
        const float ho = h32[row][j];
        const float hnew = (1.f - zz) * nn2 + zz * ho;
        h32[row][j] = hnew;
        h_s[row][j] = f2bf(hnew);
        hv[((size_t)(bn0 + row) * kM + mx) * kDH2 + d * kHH + j] = hnew;
      }
    }
    if (m + 1 < kM) {
      const int mxn = d ? (15 - (m + 1)) : (m + 1);
      for (int i = tid; i < 16 * 300; i += 256) {
        const int r = i / 300, c = i - r * 300;
        const int bn = bn0 + r, bb = bn >> 6, nn = bn & 63;
        x_s[buf ^ 1][r][c] = f2bf(rnn[((nn * 16 + mxn) * 64 + bb) * 300 + c]);
      }
    }
    __syncthreads();
  }
}

// ---------------------------------------------------------------------------
// Attention (collapsed): one measure-group n per block (4096 blocks).
__global__ __launch_bounds__(256) void k_attn(
    const float* __restrict__ hv, const float* __restrict__ PT,
    const float* __restrict__ u, const float* __restrict__ w,
    const float* __restrict__ c0p, float* __restrict__ ctx) {
  const int tid = threadIdx.x; // 256
  const int n = blockIdx.x;
  __shared__ __align__(16) float hvs[16][256];
  __shared__ __align__(16) float Ts[16][260];
  __shared__ float As[16][17];
  __shared__ float uh[16], wh[16], SM[16];
  const float c0 = c0p[0];
  {
    const float4* src = (const float4*)(hv + (size_t)n * 4096);
    float4* dst = (float4*)hvs;
    for (int i = tid; i < 1024; i += 256) dst[i] = src[i];
  }
  __syncthreads();
  float acc[16];
#pragma unroll
  for (int m2 = 0; m2 < 16; m2++) acc[m2] = 0.f;
  for (int k = 0; k < 256; k += 4) {
    const float p0 = PT[(k + 0) * 256 + tid];
    const float p1 = PT[(k + 1) * 256 + tid];
    const float p2 = PT[(k + 2) * 256 + tid];
    const float p3 = PT[(k + 3) * 256 + tid];
#pragma unroll
    for (int m2 = 0; m2 < 16; m2++) {
      const float4 hq = *(const float4*)&hvs[m2][k];
      acc[m2] += p0 * hq.x + p1 * hq.y + p2 * hq.z + p3 * hq.w;
    }
  }
#pragma unroll
  for (int m2 = 0; m2 < 16; m2++) Ts[m2][tid] = acc[m2];
  if (tid < 16) {
    float s = 0.f;
    for (int a = 0; a < 256; a++) s += u[a] * hvs[tid][a];
    uh[tid] = s;
  } else if (tid < 32) {
    float s = 0.f;
    for (int a = 0; a < 256; a++) s += w[a] * hvs[tid - 16][a];
    wh[tid - 16] = s;
  }
  __syncthreads();
  const int l = tid >> 4, mm = tid & 15;
  float sc = c0 + uh[l] + wh[mm];
  for (int a = 0; a < 256; a += 4) {
    const float4 hq = *(const float4*)&hvs[l][a];
    const float4 tq = *(const float4*)&Ts[mm][a];
    sc += hq.x * tq.x + hq.y * tq.y + hq.z * tq.z + hq.w * tq.w;
  }
  float mxv = sc;
#pragma unroll
  for (int o = 8; o >= 1; o >>= 1) mxv = fmaxf(mxv, __shfl_xor(mxv, o, 16));
  const float e = __expf(sc - mxv);
  float se = e;
#pragma unroll
  for (int o = 8; o >= 1; o >>= 1) se += __shfl_xor(se, o, 16);
  As[l][mm] = e / se;
  __syncthreads();
  if (tid < 16) {
    float s = 0.f;
    for (int l2 = 0; l2 < 16; l2++) s += As[l2][tid];
    SM[tid] = s;
  }
  __syncthreads();
  float cv = 0.f;
#pragma unroll
  for (int m2 = 0; m2 < 16; m2++) cv += SM[m2] * hvs[m2][tid];
  ctx[(size_t)n * 256 + tid] = cv;
}

// ---------------------------------------------------------------------------
__global__ void k_ctxlog(const float* __restrict__ ctx, const float* __restrict__ Wp,
                         const float* __restrict__ bp, const float* __restrict__ Wk,
                         const float* __restrict__ bk,
                         float* __restrict__ ctx_logits, float* __restrict__ ks_logp) {
  const int bn = blockIdx.x, lane = threadIdx.x; // 64 threads
  __shared__ __align__(16) float W2[35][260];
  __shared__ __align__(16) float Wks[15][260];
  __shared__ __align__(16) float cs[256];
  for (int i = lane; i < 35 * 256; i += 64) { const int j = i >> 8, k = i & 255; W2[j][k] = Wp[j * 556 + 300 + k]; }
  for (int i = lane; i < 15 * 256; i += 64) { const int j = i >> 8, k = i & 255; Wks[j][k] = Wk[j * 256 + k]; }
  for (int i = lane; i < 256; i += 64) cs[i] = ctx[(size_t)bn * 256 + i];
  __syncthreads();
  if (lane < 35) {
    float a0 = 0.f, a1 = 0.f, a2 = 0.f, a3 = 0.f;
    for (int k = 0; k < 256; k += 4) {
      const float4 wq = *(const float4*)&W2[lane][k];
      const float4 cq = *(const float4*)&cs[k];
      a0 += wq.x * cq.x; a1 += wq.y * cq.y; a2 += wq.z * cq.z; a3 += wq.w * cq.w;
    }
    ctx_logits[bn * kNP + lane] = (a0 + a1) + (a2 + a3) + bp[lane];
  }
  float kk = -1e30f;
  if (lane < 15) {
    float a0 = 0.f, a1 = 0.f, a2 = 0.f, a3 = 0.f;
    for (int k = 0; k < 256; k += 4) {
      const float4 wq = *(const float4*)&Wks[lane][k];
      const float4 cq = *(const float4*)&cs[k];
      a0 += wq.x * cq.x; a1 += wq.y * cq.y; a2 += wq.z * cq.z; a3 += wq.w * cq.w;
    }
    kk = (a0 + a1) + (a2 + a3) + bk[lane];
  }
  float mxv = kk;
#pragma unroll
  for (int o = 8; o >= 1; o >>= 1) mxv = fmaxf(mxv, __shfl_xor(mxv, o, 16));
  const float e = (lane < 15) ? __expf(kk - mxv) : 0.f;
  float se = e;
#pragma unroll
  for (int o = 8; o >= 1; o >>= 1) se += __shfl_xor(se, o, 16);
  if (lane < 15) ks_logp[bn * kNK + lane] = kk - mxv - __logf(se);
}

// ---------------------------------------------------------------------------
__global__ __launch_bounds__(256) void k_loss(
    const float* __restrict__ rnn, const float* __restrict__ Wp,
    const float* __restrict__ ctx_logits, const float* __restrict__ ks_logp,
    const int* __restrict__ pitches, const int* __restrict__ kss,
    float* __restrict__ acc) {
  __shared__ __align__(16) float W1[35][308];
  __shared__ __align__(16) float xrs[4][304];
  __shared__ float red[4][4];
  const int tid = threadIdx.x, w = tid >> 6, lane = tid & 63;
  for (int i = tid; i < 35 * 300; i += 256) {
    const int j = i / 300, k = i - j * 300;
    W1[j][k] = Wp[j * 556 + k];
  }
  __syncthreads();
  float sp = 0.f, cp = 0.f, sk = 0.f, ck = 0.f;
  for (int it = 0; it < 64; it++) {
    const int row = blockIdx.x * 256 + it * 4 + w; // row = t*64 + b
    const int t = row >> 6, b = row & 63;
    const float* rp = rnn + (size_t)row * kD2;
    for (int i = lane; i < kD2; i += 64) xrs[w][i] = rp[i];
    __syncthreads();
    const int bn = b * 64 + (t >> 4);
    float lg = -1e30f;
    if (lane < 35) {
      float a0 = 0.f, a1 = 0.f, a2 = 0.f, a3 = 0.f;
      for (int k = 0; k < kD2; k += 4) {
        const float4 wq = *(const float4*)&W1[lane][k];
        const float4 xq = *(const float4*)&xrs[w][k];
        a0 += wq.x * xq.x; a1 += wq.y * xq.y; a2 += wq.z * xq.z; a3 += wq.w * xq.w;
      }
      lg = (a0 + a1) + (a2 + a3) + ctx_logits[bn * kNP + lane];
    }
    float mxv = lg;
#pragma unroll
    for (int o = 32; o >= 1; o >>= 1) mxv = fmaxf(mxv, __shfl_xor(mxv, o, 64));
    const float e = (lane < 35) ? __expf(lg - mxv) : 0.f;
    float se = e;
#pragma unroll
    for (int o = 32; o >= 1; o >>= 1) se += __shfl_xor(se, o, 64);
    const int tp2 = pitches[row];
    if (tp2 != 34) { sp += (mxv + __logf(se)) - __shfl(lg, tp2, 64); cp += 1.f; }
    const int tk = kss[row];
    if (tk != 14) { sk -= ks_logp[bn * kNK + tk]; ck += 1.f; }
    __syncthreads();
  }
  if (lane == 0) { red[w][0] = sp; red[w][1] = cp; red[w][2] = sk; red[w][3] = ck; }
  __syncthreads();
  if (tid == 0) {
    float a0 = 0.f, a1 = 0.f, a2 = 0.f, a3 = 0.f;
    for (int q = 0; q < 4; q++) { a0 += red[q][0]; a1 += red[q][1]; a2 += red[q][2]; a3 += red[q][3]; }
    atomicAdd(&acc[0], a0); atomicAdd(&acc[1], a1);
    atomicAdd(&acc[2], a2); atomicAdd(&acc[3], a3);
  }
}

__global__ void k_final(const float* __restrict__ acc, float* __restrict__ out) {
  out[0] = acc[0] / fmaxf(acc[1], 1.f) + acc[2] / fmaxf(acc[3], 1.f);
}

// ---------------------------------------------------------------------------
extern "C" void kernel_launch(void* const* d_in, const int* in_sizes, int n_in,
                              void* d_out, int out_size, void* d_ws, size_t ws_size,
                              hipStream_t stream) {
  (void)in_sizes; (void)n_in; (void)out_size; (void)ws_size;
  const float* sent    = (const float*)d_in[0];
  const int*   pitches = (const int*)d_in[1];
  const int*   kss     = (const int*)d_in[2];
  const float* mWih_f  = (const float*)d_in[5];
  const float* mWhh_f  = (const float*)d_in[6];
  const float* mbih_f  = (const float*)d_in[7];
  const float* mbhh_f  = (const float*)d_in[8];
  const float* mWih_b  = (const float*)d_in[9];
  const float* mWhh_b  = (const float*)d_in[10];
  const float* mbih_b  = (const float*)d_in[11];
  const float* mbhh_b  = (const float*)d_in[12];
  const float* hWih_f  = (const float*)d_in[13];
  const float* hWhh_f  = (const float*)d_in[14];
  const float* hbih_f  = (const float*)d_in[15];
  const float* hbhh_f  = (const float*)d_in[16];
  const float* hWih_b  = (const float*)d_in[17];
  const float* hWhh_b  = (const float*)d_in[18];
  const float* hbih_b  = (const float*)d_in[19];
  const float* hbhh_b  = (const float*)d_in[20];
  const float* Wq      = (const float*)d_in[21];
  const float* bq      = (const float*)d_in[22];
  const float* Wv      = (const float*)d_in[23];
  const float* bv      = (const float*)d_in[24];
  const float* Wp      = (const float*)d_in[25];
  const float* bp      = (const float*)d_in[26];
  const float* Wk      = (const float*)d_in[27];
  const float* bk      = (const float*)d_in[28];
  float* ws  = (float*)d_ws;
  float* out = (float*)d_out;

  k_repack_main<<<360, 64, 0, stream>>>(mWih_f, mWhh_f, mWih_b, mWhh_b,
                                        (unsigned short*)(ws + OFF_BPACKM));
  k_repack<<<672, 64, 0, stream>>>(hWih_f, hWhh_f, hWih_b, hWhh_b,
                                   (unsigned short*)(ws + OFF_BPACK));
  k_pt<<<256, 256, 0, stream>>>(Wq, Wv, ws + OFF_PT);
  k_small<<<1, 256, 0, stream>>>(Wq, bq, Wv, bv, ws + OFF_U, ws + OFF_W, ws + OFF_C0, ws + OFF_ACC);

  k_main_gru_mfma<<<128, 320, 0, stream>>>(sent, (const unsigned short*)(ws + OFF_BPACKM),
                                           mbih_f, mbhh_f, mbih_b, mbhh_b, ws + OFF_RNN);
  k_hier_mfma<<<512, 256, 0, stream>>>(ws + OFF_RNN, (const unsigned short*)(ws + OFF_BPACK),
                                       hbih_f, hbhh_f, hbih_b, hbhh_b, ws + OFF_HV);
  k_attn<<<4096, 256, 0, stream>>>(ws + OFF_HV, ws + OFF_PT, ws + OFF_U, ws + OFF_W,
                                   ws + OFF_C0, ws + OFF_CTX);
  k_ctxlog<<<4096, 64, 0, stream>>>(ws + OFF_CTX, Wp, bp, Wk, bk,
                                    ws + OFF_CLOG, ws + OFF_KSLOGP);
  k_loss<<<256, 256, 0, stream>>>(ws + OFF_RNN, Wp, ws + OFF_CLOG, ws + OFF_KSLOGP,
                                  pitches, kss, ws + OFF_ACC);
  k_final<<<1, 1, 0, stream>>>(ws + OFF_ACC, out);
}

// Round 5
// 1316.467 us; speedup vs baseline: 1.3026x; 1.3026x over previous
//
#include <hip/hip_runtime.h>
#include <cstddef>

// ---- problem constants ----
constexpr int kT   = 1024;
constexpr int kB   = 64;
constexpr int kDIN = 17;
constexpr int kHM  = 150;   // main hidden (per dir)
constexpr int kHH  = 128;   // hier hidden (per dir)
constexpr int kM   = 16;    // measure length
constexpr int kD2  = 300;   // 2*kHM
constexpr int kDH2 = 256;   // 2*kHH
constexpr int kNP  = 35;
constexpr int kNK  = 15;

// ---- workspace layout (float offsets, 16-float aligned) ----
// rnn16: ushort [1024][64][320]  (cols 0..149 = d0, 160..309 = d1, rest pad0)
constexpr size_t OFF_RNN16  = 0;          // 20,971,520 us = 10,485,760 f
constexpr size_t OFF_HV16   = 10485760;   // ushort [4096][16][256] = 8,388,608 f
constexpr size_t OFF_CTX    = 18874368;   // f32 [4096][256] = 1,048,576
constexpr size_t OFF_PT     = 19922944;   // f32 [256][256] = 65,536
constexpr size_t OFF_PTPACK = 19988480;   // ushort [16][8][64][8] = 32,768 f
constexpr size_t OFF_U      = 20021248;   // [256]
constexpr size_t OFF_W      = 20021504;   // [256]
constexpr size_t OFF_C0     = 20021760;   // [16]
constexpr size_t OFF_ACC    = 20021776;   // [16]
constexpr size_t OFF_KSLOGP = 20021792;   // [4096][15]
constexpr size_t OFF_CLOG   = 20083232;   // [4096][35]
constexpr size_t OFF_BPACKM = 20226592;   // ushort [2][30][6][64][8] = 92,160 f
constexpr size_t OFF_BPACK  = 20318752;   // ushort [2][24][14][64][8] = 172,032 f
// total ~20.5M floats = 82 MB

typedef __bf16 bf16x8 __attribute__((ext_vector_type(8)));
typedef float f32x4 __attribute__((ext_vector_type(4)));

__device__ __forceinline__ unsigned short f2bf(float f) {
  unsigned u = __float_as_uint(f);
  u += 0x7FFFu + ((u >> 16) & 1u);
  return (unsigned short)(u >> 16);
}
__device__ __forceinline__ float bf2f(unsigned short v) {
  return __uint_as_float(((unsigned)v) << 16);
}
__device__ __forceinline__ float sigm(float x) {
  return __builtin_amdgcn_rcpf(1.f + __expf(-x));
}
__device__ __forceinline__ float tanh_fast(float x) {
  // exact identity tanh(x) = 1 - 2/(e^{2x}+1); abs err ~1e-7
  return 1.f - 2.f * __builtin_amdgcn_rcpf(__expf(2.f * x) + 1.f);
}

// PT[e][c] = sum_a Wq[a][c]*Wv[a][e]
__global__ void k_pt(const float* __restrict__ Wq, const float* __restrict__ Wv,
                     float* __restrict__ PT) {
  const int e = blockIdx.x, c = threadIdx.x;
  float acc = 0.f;
  for (int a = 0; a < 256; a++) acc += Wq[a * 256 + c] * Wv[a * 256 + e];
  PT[e * 256 + c] = acc;
}

// PTpack[nt(16)][kt(8)][lane(64)][8]: B[k=e][n=c] = PT[e][c], bf16
__global__ void k_ptpack(const float* __restrict__ PT, unsigned short* __restrict__ pp) {
  const int bid = blockIdx.x;           // 128 = nt*8+kt
  const int kt = bid & 7, nt = bid >> 3;
  const int lane = threadIdx.x;
  const int c = nt * 16 + (lane & 15);
  const int e0 = kt * 32 + (lane >> 4) * 8;
#pragma unroll
  for (int j = 0; j < 8; j++)
    pp[((size_t)bid * 64 + lane) * 8 + j] = f2bf(PT[(e0 + j) * 256 + c]);
}

__global__ void k_small(const float* __restrict__ Wq, const float* __restrict__ bq,
                        const float* __restrict__ Wv, const float* __restrict__ bv,
                        float* __restrict__ u, float* __restrict__ w,
                        float* __restrict__ c0, float* __restrict__ acc) {
  const int a = threadIdx.x; // 256
  float us = 0.f, ws = 0.f;
  for (int j = 0; j < 256; j++) {
    us += Wq[j * 256 + a] * bv[j];
    ws += bq[j] * Wv[j * 256 + a];
  }
  u[a] = us; w[a] = ws;
  if (a == 0) {
    float c = 0.f;
    for (int j = 0; j < 256; j++) c += bq[j] * bv[j];
    c0[0] = c;
    acc[0] = acc[1] = acc[2] = acc[3] = 0.f;
  }
}

// ---------------------------------------------------------------------------
// hier weights -> bf16 B-frags (validated r2): bpack[d][nt24][kt14][lane][8]
__global__ void k_repack(const float* __restrict__ hWih_f, const float* __restrict__ hWhh_f,
                         const float* __restrict__ hWih_b, const float* __restrict__ hWhh_b,
                         unsigned short* __restrict__ bpack) {
  const int bid = blockIdx.x;           // 672
  const int kt = bid % 14;
  const int nt = (bid / 14) % 24;
  const int d  = bid / (14 * 24);
  const float* Wih = d ? hWih_b : hWih_f;
  const float* Whh = d ? hWhh_b : hWhh_f;
  const int lane = threadIdx.x;
  const int n = nt * 16 + (lane & 15);
  const int kbase = kt * 32 + (lane >> 4) * 8;
  unsigned short* dst = bpack + ((((size_t)d * 24 + nt) * 14 + kt) * 64 + lane) * 8;
#pragma unroll
  for (int j = 0; j < 8; j++) {
    const int k = kbase + j;
    float f = 0.f;
    if (k < 300) f = Wih[n * 300 + k];
    else if (k >= 320) f = Whh[n * 128 + (k - 320)];
    dst[j] = f2bf(f);
  }
}

// main weights -> bf16 B-frags (validated r3): bpackM[d][gt30][kt6][lane][8]
__global__ void k_repack_main(const float* __restrict__ mWih_f, const float* __restrict__ mWhh_f,
                              const float* __restrict__ mWih_b, const float* __restrict__ mWhh_b,
                              unsigned short* __restrict__ bpackM) {
  const int bid = blockIdx.x;          // 360
  const int kt = bid % 6;
  const int gt = (bid / 6) % 30;
  const int d  = bid / 180;
  const float* Wih = d ? mWih_b : mWih_f;  // [450][17]
  const float* Whh = d ? mWhh_b : mWhh_f;  // [450][150]
  const int lane = threadIdx.x;
  const int slot = gt * 16 + (lane & 15);
  const int type = slot / 160, j = slot - type * 160;
  const int row = type * 150 + j;
  const bool valid = (j < 150);
  const int kbase = (lane >> 4) * 8;
  unsigned short* dst = bpackM + ((((size_t)d * 30 + gt) * 6 + kt) * 64 + lane) * 8;
#pragma unroll
  for (int jj = 0; jj < 8; jj++) {
    float f = 0.f;
    if (valid) {
      if (kt < 5) {
        const int k = kt * 32 + kbase + jj;
        if (k < 150) f = Whh[row * 150 + k];
      } else {
        const int k = kbase + jj;
        if (k < 17) f = Wih[row * 17 + k];
      }
    }
    dst[jj] = f2bf(f);
  }
}

// ---------------------------------------------------------------------------
// Main bi-GRU, M=1 MFMA, 10 waves (r3 config). New: LDS-resident xall,
// h-history ring (2x16 steps) flushed to global every 16 steps (amortizes
// the vmcnt(0) barrier drain), bf16 rnn output, fast tanh, split-kt accums.
__global__ __launch_bounds__(640, 2) void k_main_gru_mfma(
    const float* __restrict__ x,               // [1024][64][17]
    const unsigned short* __restrict__ bpackM, // [2][30][6][64][8]
    const float* __restrict__ bihf, const float* __restrict__ bhhf,
    const float* __restrict__ bihb, const float* __restrict__ bhhb,
    unsigned short* __restrict__ rnn16)        // [1024][64][320]
{
  const int d = blockIdx.x & 1, b = blockIdx.x >> 1;
  const int tid = threadIdx.x, w = tid >> 6, lane = tid & 63;
  const int col = lane & 15, q8 = (lane >> 4) * 8;
  __shared__ __align__(16) unsigned short hx[2][160];       // h, 150 valid + pad0
  __shared__ __align__(16) unsigned short hist[2][16][160]; // 16-step ring, dbuf
  __shared__ __align__(16) unsigned short xall[kT][32];     // all x, bf16
  for (int i = tid; i < 2 * 160; i += 640) ((unsigned short*)hx)[i] = 0;
  for (int i = tid; i < 2 * 16 * 160; i += 640) ((unsigned short*)hist)[i] = 0;
  for (int i = tid; i < kT * 32; i += 640) {
    const int t = i >> 5, c = i & 31;
    xall[t][c] = (c < kDIN) ? f2bf(x[((size_t)t * kB + b) * kDIN + c]) : (unsigned short)0;
  }
  const float* bih = d ? bihb : bihf;
  const float* bhh = d ? bhhb : bhhf;
  const int j = w * 16 + col;
  const bool actv = (lane < 16) && (j < kHM);
  float br = 0.f, bz = 0.f, bnx = 0.f, bnh = 0.f;
  if (actv) {
    br  = bih[j] + bhh[j];
    bz  = bih[150 + j] + bhh[150 + j];
    bnx = bih[300 + j];
    bnh = bhh[300 + j];
  }
  bf16x8 bw[3][6];
  const unsigned short* bp = bpackM + (size_t)d * 30 * 6 * 64 * 8;
  const int gts[3] = { w, 10 + w, 20 + w };
#pragma unroll
  for (int gi = 0; gi < 3; gi++)
#pragma unroll
    for (int kt = 0; kt < 6; kt++)
      bw[gi][kt] = *(const bf16x8*)&bp[(((size_t)gts[gi] * 6 + kt) * 64 + lane) * 8];
  float h_old = 0.f;
  __syncthreads();

  for (int t = 0; t < kT; t++) {
    const int tx = d ? (kT - 1 - t) : t;
    const int buf = t & 1;
    f32x4 aR0 = (f32x4)(0.f), aR1 = (f32x4)(0.f);
    f32x4 aZ0 = (f32x4)(0.f), aZ1 = (f32x4)(0.f);
    f32x4 aN0 = (f32x4)(0.f), aN1 = (f32x4)(0.f);
    f32x4 aX  = (f32x4)(0.f);
#pragma unroll
    for (int kt = 0; kt < 6; kt++) {
      const bf16x8 af = (kt < 5) ? *(const bf16x8*)&hx[buf][kt * 32 + q8]
                                 : *(const bf16x8*)&xall[tx][q8];
      if ((kt & 1) == 0) {
        aR0 = __builtin_amdgcn_mfma_f32_16x16x32_bf16(af, bw[0][kt], aR0, 0, 0, 0);
        aZ0 = __builtin_amdgcn_mfma_f32_16x16x32_bf16(af, bw[1][kt], aZ0, 0, 0, 0);
        aN0 = __builtin_amdgcn_mfma_f32_16x16x32_bf16(af, bw[2][kt], aN0, 0, 0, 0);
      } else if (kt < 5) {
        aR1 = __builtin_amdgcn_mfma_f32_16x16x32_bf16(af, bw[0][kt], aR1, 0, 0, 0);
        aZ1 = __builtin_amdgcn_mfma_f32_16x16x32_bf16(af, bw[1][kt], aZ1, 0, 0, 0);
        aN1 = __builtin_amdgcn_mfma_f32_16x16x32_bf16(af, bw[2][kt], aN1, 0, 0, 0);
      } else {
        aR1 = __builtin_amdgcn_mfma_f32_16x16x32_bf16(af, bw[0][5], aR1, 0, 0, 0);
        aZ1 = __builtin_amdgcn_mfma_f32_16x16x32_bf16(af, bw[1][5], aZ1, 0, 0, 0);
        aX  = __builtin_amdgcn_mfma_f32_16x16x32_bf16(af, bw[2][5], aX, 0, 0, 0);
      }
    }
    if (actv) {
      const float r = sigm(aR0[0] + aR1[0] + br);
      const float z = sigm(aZ0[0] + aZ1[0] + bz);
      const float n = tanh_fast(aX[0] + bnx + r * (aN0[0] + aN1[0] + bnh));
      h_old = (1.f - z) * n + z * h_old;
      const unsigned short us = f2bf(h_old);
      hx[buf ^ 1][j] = us;
      hist[(t >> 4) & 1][t & 15][j] = us;
    }
    __syncthreads();
    if ((t & 15) == 15) {   // flush last 16 steps' h to global (bf16)
      const int hb = (t >> 4) & 1;
      const int toff = tid / 40, ch = tid - toff * 40;  // 16 x 40 ushort4 chunks
      const int tg = t - 15 + toff;
      const int txg = d ? (kT - 1 - tg) : tg;
      *(ushort4*)&rnn16[((size_t)txg * kB + b) * 320 + d * 160 + ch * 4] =
          *(const ushort4*)&hist[hb][toff][ch * 4];
    }
  }
}

// ---------------------------------------------------------------------------
// Hier bi-GRU via bf16 MFMA (validated r2); now reads bf16 rnn16 (no f2bf),
// writes bf16 hv16, fast activations.
__global__ __launch_bounds__(256) void k_hier_mfma(
    const unsigned short* __restrict__ rnn16,  // [1024][64][320]
    const unsigned short* __restrict__ bpack,  // [2][24][14][64][8]
    const float* __restrict__ bihf, const float* __restrict__ bhhf,
    const float* __restrict__ bihb, const float* __restrict__ bhhb,
    unsigned short* __restrict__ hv16)         // [4096][16][256]
{
  const int d = blockIdx.x & 1;
  const int bn0 = (blockIdx.x >> 1) * 16;
  const int tid = threadIdx.x;
  const int w = tid >> 6;
  const int lane = tid & 63;
  const int q = lane >> 4, col = lane & 15;

  __shared__ __align__(16) unsigned short x_s[2][16][328];
  __shared__ __align__(16) unsigned short h_s[16][136];
  __shared__ __align__(16) float h32[16][136];

  for (int i = tid; i < 16 * 136; i += 256) { ((unsigned short*)h_s)[i] = 0; ((float*)h32)[i] = 0.f; }
  for (int i = tid; i < 2 * 16 * 28; i += 256) {
    const int bb2 = i / (16 * 28), rr2 = (i / 28) & 15, cc2 = 300 + (i % 28);
    x_s[bb2][rr2][cc2] = 0;
  }
  const float* bih = d ? bihb : bihf;
  const float* bhh = d ? bhhb : bhhf;
  const int j0 = w * 16 + col, j1 = 64 + w * 16 + col;
  const float biR0 = bih[j0] + bhh[j0],             biR1 = bih[j1] + bhh[j1];
  const float biZ0 = bih[128 + j0] + bhh[128 + j0], biZ1 = bih[128 + j1] + bhh[128 + j1];
  const float biNX0 = bih[256 + j0], biNX1 = bih[256 + j1];
  const float biNH0 = bhh[256 + j0], biNH1 = bhh[256 + j1];

  {
    const int mx0 = d ? 15 : 0;
    for (int i = tid; i < 16 * 150; i += 256) {
      const int r = i / 150, p = i - r * 150;
      const int c = 2 * p;
      const int bn = bn0 + r, bb = bn >> 6, nn = bn & 63;
      const size_t base = ((size_t)(nn * 16 + mx0) * 64 + bb) * 320;
      const int src = (c < 150) ? c : c + 10;
      *(ushort2*)&x_s[0][r][c] = *(const ushort2*)&rnn16[base + src];
    }
  }
  __syncthreads();

  const unsigned short* bpd = bpack + (size_t)d * 24 * 14 * 64 * 8;

  for (int m = 0; m < kM; m++) {
    const int mx = d ? (15 - m) : m;
    const int buf = m & 1;
    f32x4 aR[2], aZ[2], aNX[2], aNH[2];
#pragma unroll
    for (int t = 0; t < 2; t++) {
      aR[t] = (f32x4)(0.f); aZ[t] = (f32x4)(0.f);
      aNX[t] = (f32x4)(0.f); aNH[t] = (f32x4)(0.f);
    }
#pragma unroll
    for (int kt = 0; kt < 14; kt++) {
      bf16x8 af;
      if (kt < 10) af = *(const bf16x8*)&x_s[buf][col][kt * 32 + q * 8];
      else         af = *(const bf16x8*)&h_s[col][(kt - 10) * 32 + q * 8];
#pragma unroll
      for (int t = 0; t < 6; t++) {
        const int nt = w + 4 * t;
        const bf16x8 bfr = *(const bf16x8*)&bpd[(((size_t)nt * 14 + kt) * 64 + lane) * 8];
        if (t < 2)        aR[t]      = __builtin_amdgcn_mfma_f32_16x16x32_bf16(af, bfr, aR[t], 0, 0, 0);
        else if (t < 4)   aZ[t - 2]  = __builtin_amdgcn_mfma_f32_16x16x32_bf16(af, bfr, aZ[t - 2], 0, 0, 0);
        else if (kt < 10) aNX[t - 4] = __builtin_amdgcn_mfma_f32_16x16x32_bf16(af, bfr, aNX[t - 4], 0, 0, 0);
        else              aNH[t - 4] = __builtin_amdgcn_mfma_f32_16x16x32_bf16(af, bfr, aNH[t - 4], 0, 0, 0);
      }
    }
    __syncthreads();
#pragma unroll
    for (int jt = 0; jt < 2; jt++) {
      const int j = jt ? j1 : j0;
      const float bR = jt ? biR1 : biR0, bZ = jt ? biZ1 : biZ0;
      const float bNX = jt ? biNX1 : biNX0, bNH = jt ? biNH1 : biNH0;
#pragma unroll
      for (int i = 0; i < 4; i++) {
        const int row = q * 4 + i;
        const float rr = sigm(aR[jt][i] + bR);
        const float zz = sigm(aZ[jt][i] + bZ);
        const float hn = aNH[jt][i] + bNH;
        const float nn2 = tanh_fast(aNX[jt][i] + bNX + rr * hn);
        const float ho = h32[row][j];
        const float hnew = (1.f - zz) * nn2 + zz * ho;
        h32[row][j] = hnew;
        const unsigned short us = f2bf(hnew);
        h_s[row][j] = us;
        hv16[((size_t)(bn0 + row) * kM + mx) * kDH2 + d * kHH + j] = us;
      }
    }
    if (m + 1 < kM) {
      const int mxn = d ? (15 - (m + 1)) : (m + 1);
      for (int i = tid; i < 16 * 150; i += 256) {
        const int r = i / 150, p = i - r * 150;
        const int c = 2 * p;
        const int bn = bn0 + r, bb = bn >> 6, nn = bn & 63;
        const size_t base = ((size_t)(nn * 16 + mxn) * 64 + bb) * 320;
        const int src = (c < 150) ? c : c + 10;
        *(ushort2*)&x_s[buf ^ 1][r][c] = *(const ushort2*)&rnn16[base + src];
      }
    }
    __syncthreads();
  }
}

// ---------------------------------------------------------------------------
// Attention, fused MFMA: Ts = hv . PT via 32 MFMA/wave, then scores/softmax/ctx.
__global__ __launch_bounds__(256) void k_attn2(
    const unsigned short* __restrict__ hv16, const unsigned short* __restrict__ ptpack,
    const float* __restrict__ u, const float* __restrict__ w,
    const float* __restrict__ c0p, float* __restrict__ ctx) {
  const int tid = threadIdx.x, n = blockIdx.x;
  const int wv = tid >> 6, lane = tid & 63, col = lane & 15, q = lane >> 4, q8 = q * 8;
  __shared__ __align__(16) unsigned short hv16s[16][264];
  __shared__ __align__(16) float hvs32[16][256];
  __shared__ __align__(16) float Ts[16][260];
  __shared__ float pu[16][17], pw[16][17];
  __shared__ float uh[16], wh[16], SM[16];
  __shared__ float As[16][17];
  const float c0 = c0p[0];
  {
    const unsigned short* src = hv16 + (size_t)n * 4096;
    const int row = tid >> 4, ci = (tid & 15) * 16;
#pragma unroll
    for (int k = 0; k < 16; k += 4) {
      const ushort4 v = *(const ushort4*)&src[row * 256 + ci + k];
      *(ushort4*)&hv16s[row][ci + k] = v;
      hvs32[row][ci + k + 0] = bf2f(v.x);
      hvs32[row][ci + k + 1] = bf2f(v.y);
      hvs32[row][ci + k + 2] = bf2f(v.z);
      hvs32[row][ci + k + 3] = bf2f(v.w);
    }
  }
  __syncthreads();
  // MFMA: wave wv -> n-tiles {4wv..4wv+3}
  f32x4 acc[4];
#pragma unroll
  for (int i2 = 0; i2 < 4; i2++) acc[i2] = (f32x4)(0.f);
#pragma unroll
  for (int kt = 0; kt < 8; kt++) {
    const bf16x8 af = *(const bf16x8*)&hv16s[col][kt * 32 + q8];
#pragma unroll
    for (int i2 = 0; i2 < 4; i2++) {
      const int nt = wv * 4 + i2;
      const bf16x8 bfr = *(const bf16x8*)&ptpack[(((size_t)nt * 8 + kt) * 64 + lane) * 8];
      acc[i2] = __builtin_amdgcn_mfma_f32_16x16x32_bf16(af, bfr, acc[i2], 0, 0, 0);
    }
  }
#pragma unroll
  for (int i2 = 0; i2 < 4; i2++) {
    const int nt = wv * 4 + i2;
#pragma unroll
    for (int i = 0; i < 4; i++) Ts[q * 4 + i][nt * 16 + col] = acc[i2][i];
  }
  {
    const int l = tid >> 4, s = tid & 15;
    float su = 0.f, sw = 0.f;
#pragma unroll
    for (int a0 = 0; a0 < 16; a0 += 4) {
      const int a = s * 16 + a0;
      const float4 hq = *(const float4*)&hvs32[l][a];
      const float4 uq = *(const float4*)&u[a];
      const float4 wq = *(const float4*)&w[a];
      su += hq.x * uq.x + hq.y * uq.y + hq.z * uq.z + hq.w * uq.w;
      sw += hq.x * wq.x + hq.y * wq.y + hq.z * wq.z + hq.w * wq.w;
    }
    pu[l][s] = su; pw[l][s] = sw;
  }
  __syncthreads();
  if (tid < 16) { float s2 = 0.f; for (int s = 0; s < 16; s++) s2 += pu[tid][s]; uh[tid] = s2; }
  else if (tid < 32) { float s2 = 0.f; for (int s = 0; s < 16; s++) s2 += pw[tid - 16][s]; wh[tid - 16] = s2; }
  __syncthreads();
  const int l = tid >> 4, mm = tid & 15;
  float sc = c0 + uh[l] + wh[mm];
  for (int a = 0; a < 256; a += 4) {
    const float4 hq = *(const float4*)&hvs32[l][a];
    const float4 tq = *(const float4*)&Ts[mm][a];
    sc += hq.x * tq.x + hq.y * tq.y + hq.z * tq.z + hq.w * tq.w;
  }
  float mxv = sc;
#pragma unroll
  for (int o = 8; o >= 1; o >>= 1) mxv = fmaxf(mxv, __shfl_xor(mxv, o, 16));
  const float e = __expf(sc - mxv);
  float se = e;
#pragma unroll
  for (int o = 8; o >= 1; o >>= 1) se += __shfl_xor(se, o, 16);
  As[l][mm] = e / se;
  __syncthreads();
  if (tid < 16) {
    float s = 0.f;
    for (int l2 = 0; l2 < 16; l2++) s += As[l2][tid];
    SM[tid] = s;
  }
  __syncthreads();
  float cv = 0.f;
#pragma unroll
  for (int m2 = 0; m2 < 16; m2++) cv += SM[m2] * hvs32[m2][tid];
  ctx[(size_t)n * 256 + tid] = cv;
}

// ---------------------------------------------------------------------------
// ctx-dependent logits: 256 blocks x 16 bn, weights staged once per block.
__global__ __launch_bounds__(256) void k_ctxlog2(
    const float* __restrict__ ctx, const float* __restrict__ Wp, const float* __restrict__ bp,
    const float* __restrict__ Wk, const float* __restrict__ bk,
    float* __restrict__ clog, float* __restrict__ kslogp) {
  const int tid = threadIdx.x;
  __shared__ __align__(16) float W2[50][260];  // 0..34 pitch(ctx part), 35..49 ks
  __shared__ __align__(16) float cs[256];
  __shared__ float arr[64];
  __shared__ float bps[35], bks[15];
  for (int i = tid; i < 35 * 256; i += 256) { const int r = i >> 8, c = i & 255; W2[r][c] = Wp[r * 556 + 300 + c]; }
  for (int i = tid; i < 15 * 256; i += 256) { const int r = i >> 8, c = i & 255; W2[35 + r][c] = Wk[r * 256 + c]; }
  if (tid < 35) bps[tid] = bp[tid];
  else if (tid < 50) bks[tid - 35] = bk[tid - 35];
  __syncthreads();
  const int o = tid >> 2, s = tid & 3;
  for (int it = 0; it < 16; it++) {
    const int bn = blockIdx.x * 16 + it;
    cs[tid] = ctx[(size_t)bn * 256 + tid];
    __syncthreads();
    float v = 0.f;
    if (o < 50) {
      for (int k0 = 0; k0 < 64; k0 += 4) {
        const int k = s * 64 + k0;
        const float4 wq = *(const float4*)&W2[o][k];
        const float4 cq = *(const float4*)&cs[k];
        v += wq.x * cq.x + wq.y * cq.y + wq.z * cq.z + wq.w * cq.w;
      }
    }
    v += __shfl_xor(v, 1);
    v += __shfl_xor(v, 2);
    if (o < 50 && s == 0) arr[o] = v;
    __syncthreads();
    if (tid < 35) clog[bn * kNP + tid] = arr[tid] + bps[tid];
    if (tid >= 64 && tid < 80) {
      const int t2 = tid - 64;
      float kk = (t2 < 15) ? arr[35 + t2] + bks[t2] : -1e30f;
      float mxv = kk;
#pragma unroll
      for (int off = 8; off >= 1; off >>= 1) mxv = fmaxf(mxv, __shfl_xor(mxv, off, 16));
      const float e = (t2 < 15) ? __expf(kk - mxv) : 0.f;
      float se = e;
#pragma unroll
      for (int off = 8; off >= 1; off >>= 1) se += __shfl_xor(se, off, 16);
      if (t2 < 15) kslogp[bn * kNK + t2] = kk - mxv - __logf(se);
    }
    __syncthreads();
  }
}

// ---------------------------------------------------------------------------
__global__ __launch_bounds__(256) void k_loss(
    const unsigned short* __restrict__ rnn16, const float* __restrict__ Wp,
    const float* __restrict__ ctx_logits, const float* __restrict__ ks_logp,
    const int* __restrict__ pitches, const int* __restrict__ kss,
    float* __restrict__ acc) {
  __shared__ __align__(16) float W1[35][308];
  __shared__ __align__(16) float xrs[4][304];
  __shared__ float red[4][4];
  const int tid = threadIdx.x, w = tid >> 6, lane = tid & 63;
  for (int i = tid; i < 35 * 300; i += 256) {
    const int j = i / 300, k = i - j * 300;
    W1[j][k] = Wp[j * 556 + k];
  }
  __syncthreads();
  float sp = 0.f, cp = 0.f, sk = 0.f, ck = 0.f;
  for (int it = 0; it < 64; it++) {
    const int row = blockIdx.x * 256 + it * 4 + w; // row = t*64 + b
    const int t = row >> 6, b = row & 63;
    const unsigned short* rp = rnn16 + (size_t)row * 320;
    for (int i = lane; i < kD2; i += 64) xrs[w][i] = bf2f(rp[i < 150 ? i : i + 10]);
    __syncthreads();
    const int bn = b * 64 + (t >> 4);
    float lg = -1e30f;
    if (lane < 35) {
      float a0 = 0.f, a1 = 0.f, a2 = 0.f, a3 = 0.f;
      for (int k = 0; k < kD2; k += 4) {
        const float4 wq = *(const float4*)&W1[lane][k];
        const float4 xq = *(const float4*)&xrs[w][k];
        a0 += wq.x * xq.x; a1 += wq.y * xq.y; a2 += wq.z * xq.z; a3 += wq.w * xq.w;
      }
      lg = (a0 + a1) + (a2 + a3) + ctx_logits[bn * kNP + lane];
    }
    float mxv = lg;
#pragma unroll
    for (int o = 32; o >= 1; o >>= 1) mxv = fmaxf(mxv, __shfl_xor(mxv, o, 64));
    const float e = (lane < 35) ? __expf(lg - mxv) : 0.f;
    float se = e;
#pragma unroll
    for (int o = 32; o >= 1; o >>= 1) se += __shfl_xor(se, o, 64);
    const int tp2 = pitches[row];
    if (tp2 != 34) { sp += (mxv + __logf(se)) - __shfl(lg, tp2, 64); cp += 1.f; }
    const int tk = kss[row];
    if (tk != 14) { sk -= ks_logp[bn * kNK + tk]; ck += 1.f; }
    __syncthreads();
  }
  if (lane == 0) { red[w][0] = sp; red[w][1] = cp; red[w][2] = sk; red[w][3] = ck; }
  __syncthreads();
  if (tid == 0) {
    float a0 = 0.f, a1 = 0.f, a2 = 0.f, a3 = 0.f;
    for (int q = 0; q < 4; q++) { a0 += red[q][0]; a1 += red[q][1]; a2 += red[q][2]; a3 += red[q][3]; }
    atomicAdd(&acc[0], a0); atomicAdd(&acc[1], a1);
    atomicAdd(&acc[2], a2); atomicAdd(&acc[3], a3);
  }
}

__global__ void k_final(const float* __restrict__ acc, float* __restrict__ out) {
  out[0] = acc[0] / fmaxf(acc[1], 1.f) + acc[2] / fmaxf(acc[3], 1.f);
}

// ---------------------------------------------------------------------------
extern "C" void kernel_launch(void* const* d_in, const int* in_sizes, int n_in,
                              void* d_out, int out_size, void* d_ws, size_t ws_size,
                              hipStream_t stream) {
  (void)in_sizes; (void)n_in; (void)out_size; (void)ws_size;
  const float* sent    = (const float*)d_in[0];
  const int*   pitches = (const int*)d_in[1];
  const int*   kss     = (const int*)d_in[2];
  const float* mWih_f  = (const float*)d_in[5];
  const float* mWhh_f  = (const float*)d_in[6];
  const float* mbih_f  = (const float*)d_in[7];
  const float* mbhh_f  = (const float*)d_in[8];
  const float* mWih_b  = (const float*)d_in[9];
  const float* mWhh_b  = (const float*)d_in[10];
  const float* mbih_b  = (const float*)d_in[11];
  const float* mbhh_b  = (const float*)d_in[12];
  const float* hWih_f  = (const float*)d_in[13];
  const float* hWhh_f  = (const float*)d_in[14];
  const float* hbih_f  = (const float*)d_in[15];
  const float* hbhh_f  = (const float*)d_in[16];
  const float* hWih_b  = (const float*)d_in[17];
  const float* hWhh_b  = (const float*)d_in[18];
  const float* hbih_b  = (const float*)d_in[19];
  const float* hbhh_b  = (const float*)d_in[20];
  const float* Wq      = (const float*)d_in[21];
  const float* bq      = (const float*)d_in[22];
  const float* Wv      = (const float*)d_in[23];
  const float* bv      = (const float*)d_in[24];
  const float* Wp      = (const float*)d_in[25];
  const float* bp      = (const float*)d_in[26];
  const float* Wk      = (const float*)d_in[27];
  const float* bk      = (const float*)d_in[28];
  float* ws  = (float*)d_ws;
  float* out = (float*)d_out;
  unsigned short* rnn16  = (unsigned short*)(ws + OFF_RNN16);
  unsigned short* hv16   = (unsigned short*)(ws + OFF_HV16);
  unsigned short* ptpack = (unsigned short*)(ws + OFF_PTPACK);

  k_repack_main<<<360, 64, 0, stream>>>(mWih_f, mWhh_f, mWih_b, mWhh_b,
                                        (unsigned short*)(ws + OFF_BPACKM));
  k_repack<<<672, 64, 0, stream>>>(hWih_f, hWhh_f, hWih_b, hWhh_b,
                                   (unsigned short*)(ws + OFF_BPACK));
  k_pt<<<256, 256, 0, stream>>>(Wq, Wv, ws + OFF_PT);
  k_ptpack<<<128, 64, 0, stream>>>(ws + OFF_PT, ptpack);
  k_small<<<1, 256, 0, stream>>>(Wq, bq, Wv, bv, ws + OFF_U, ws + OFF_W, ws + OFF_C0, ws + OFF_ACC);

  k_main_gru_mfma<<<128, 640, 0, stream>>>(sent, (const unsigned short*)(ws + OFF_BPACKM),
                                           mbih_f, mbhh_f, mbih_b, mbhh_b, rnn16);
  k_hier_mfma<<<512, 256, 0, stream>>>(rnn16, (const unsigned short*)(ws + OFF_BPACK),
                                       hbih_f, hbhh_f, hbih_b, hbhh_b, hv16);
  k_attn2<<<4096, 256, 0, stream>>>(hv16, ptpack, ws + OFF_U, ws + OFF_W,
                                    ws + OFF_C0, ws + OFF_CTX);
  k_ctxlog2<<<256, 256, 0, stream>>>(ws + OFF_CTX, Wp, bp, Wk, bk,
                                     ws + OFF_CLOG, ws + OFF_KSLOGP);
  k_loss<<<256, 256, 0, stream>>>(rnn16, Wp, ws + OFF_CLOG, ws + OFF_KSLOGP,
                                  pitches, kss, ws + OFF_ACC);
  k_final<<<1, 1, 0, stream>>>(ws + OFF_ACC, out);
}

// Round 6
// 1239.017 us; speedup vs baseline: 1.3841x; 1.0625x over previous
//
#include <hip/hip_runtime.h>
#include <cstddef>

// ---- problem constants ----
constexpr int kT   = 1024;
constexpr int kB   = 64;
constexpr int kDIN = 17;
constexpr int kHM  = 150;   // main hidden (per dir)
constexpr int kHH  = 128;   // hier hidden (per dir)
constexpr int kM   = 16;    // measure length
constexpr int kD2  = 300;   // 2*kHM
constexpr int kNP  = 35;
constexpr int kNK  = 15;

// ---- workspace layout (float offsets, 16-float aligned) ----
// rnn16: ushort [1024][64][320]  (cols 0..149 = d0, 160..309 = d1, pads 0)
constexpr size_t OFF_RNN16  = 0;          // 10,485,760 f
constexpr size_t OFF_HV16   = 10485760;   // ushort [4096][16][256] = 8,388,608 f
constexpr size_t OFF_CTX    = 18874368;   // f32 [4096][256] = 1,048,576
constexpr size_t OFF_PT     = 19922944;   // f32 [256][256] = 65,536
constexpr size_t OFF_PTPACK = 19988480;   // ushort [16][8][64][8] = 32,768 f
constexpr size_t OFF_U      = 20021248;   // [256]
constexpr size_t OFF_W      = 20021504;   // [256]
constexpr size_t OFF_C0     = 20021760;   // [16]
constexpr size_t OFF_ACC    = 20021776;   // [16]
constexpr size_t OFF_KSLOGP = 20021792;   // [4096][15]
constexpr size_t OFF_CLOG   = 20083232;   // [4096][35]
constexpr size_t OFF_BPACKM = 20226592;   // ushort [2][30][6][64][8] = 92,160 f
constexpr size_t OFF_BPACK  = 20318752;   // ushort [2][24][14][64][8] = 172,032 f
// total ~20.5M floats = 82 MB

typedef __bf16 bf16x8 __attribute__((ext_vector_type(8)));
typedef float f32x4 __attribute__((ext_vector_type(4)));

__device__ __forceinline__ unsigned short f2bf(float f) {
  unsigned u = __float_as_uint(f);
  u += 0x7FFFu + ((u >> 16) & 1u);
  return (unsigned short)(u >> 16);
}
__device__ __forceinline__ float bf2f(unsigned short v) {
  return __uint_as_float(((unsigned)v) << 16);
}
__device__ __forceinline__ float sigm(float x) {
  return __builtin_amdgcn_rcpf(1.f + __expf(-x));
}
__device__ __forceinline__ float tanh_fast(float x) {
  return 1.f - 2.f * __builtin_amdgcn_rcpf(__expf(2.f * x) + 1.f);
}

// PT[e][c] = sum_a Wq[a][c]*Wv[a][e]
__global__ void k_pt(const float* __restrict__ Wq, const float* __restrict__ Wv,
                     float* __restrict__ PT) {
  const int e = blockIdx.x, c = threadIdx.x;
  float acc = 0.f;
  for (int a = 0; a < 256; a++) acc += Wq[a * 256 + c] * Wv[a * 256 + e];
  PT[e * 256 + c] = acc;
}

// PTpack[nt(16)][kt(8)][lane(64)][8]: B[k=e][n=c] = PT[e][c], bf16
__global__ void k_ptpack(const float* __restrict__ PT, unsigned short* __restrict__ pp) {
  const int bid = blockIdx.x;           // 128 = nt*8+kt
  const int kt = bid & 7, nt = bid >> 3;
  const int lane = threadIdx.x;
  const int c = nt * 16 + (lane & 15);
  const int e0 = kt * 32 + (lane >> 4) * 8;
#pragma unroll
  for (int j = 0; j < 8; j++)
    pp[((size_t)bid * 64 + lane) * 8 + j] = f2bf(PT[(e0 + j) * 256 + c]);
}

__global__ void k_small(const float* __restrict__ Wq, const float* __restrict__ bq,
                        const float* __restrict__ Wv, const float* __restrict__ bv,
                        float* __restrict__ u, float* __restrict__ w,
                        float* __restrict__ c0, float* __restrict__ acc) {
  const int a = threadIdx.x; // 256
  float us = 0.f, ws = 0.f;
  for (int j = 0; j < 256; j++) {
    us += Wq[j * 256 + a] * bv[j];
    ws += bq[j] * Wv[j * 256 + a];
  }
  u[a] = us; w[a] = ws;
  if (a == 0) {
    float c = 0.f;
    for (int j = 0; j < 256; j++) c += bq[j] * bv[j];
    c0[0] = c;
    acc[0] = acc[1] = acc[2] = acc[3] = 0.f;
  }
}

// ---------------------------------------------------------------------------
// hier weights -> bf16 B-frags. NEW K-layout matches rnn16's 320-col padded
// rows: k<150 -> Wih[.][k]; 150..159 -> 0; 160..309 -> Wih[.][k-10];
// 310..319 -> 0; k>=320 -> Whh[.][k-320]. bpack[d][nt24][kt14][lane][8]
__global__ void k_repack(const float* __restrict__ hWih_f, const float* __restrict__ hWhh_f,
                         const float* __restrict__ hWih_b, const float* __restrict__ hWhh_b,
                         unsigned short* __restrict__ bpack) {
  const int bid = blockIdx.x;           // 672
  const int kt = bid % 14;
  const int nt = (bid / 14) % 24;
  const int d  = bid / (14 * 24);
  const float* Wih = d ? hWih_b : hWih_f;   // [384][300]
  const float* Whh = d ? hWhh_b : hWhh_f;   // [384][128]
  const int lane = threadIdx.x;
  const int n = nt * 16 + (lane & 15);
  const int kbase = kt * 32 + (lane >> 4) * 8;
  unsigned short* dst = bpack + ((((size_t)d * 24 + nt) * 14 + kt) * 64 + lane) * 8;
#pragma unroll
  for (int j = 0; j < 8; j++) {
    const int k = kbase + j;
    float f = 0.f;
    if (kt < 10) {
      if (k < 150) f = Wih[n * 300 + k];
      else if (k >= 160 && k < 310) f = Wih[n * 300 + (k - 10)];
    } else {
      f = Whh[n * 128 + (k - 320)];   // kt 10..13 -> 0..127, no overflow
    }
    dst[j] = f2bf(f);
  }
}

// main weights -> bf16 B-frags (validated r3): bpackM[d][gt30][kt6][lane][8]
__global__ void k_repack_main(const float* __restrict__ mWih_f, const float* __restrict__ mWhh_f,
                              const float* __restrict__ mWih_b, const float* __restrict__ mWhh_b,
                              unsigned short* __restrict__ bpackM) {
  const int bid = blockIdx.x;          // 360
  const int kt = bid % 6;
  const int gt = (bid / 6) % 30;
  const int d  = bid / 180;
  const float* Wih = d ? mWih_b : mWih_f;  // [450][17]
  const float* Whh = d ? mWhh_b : mWhh_f;  // [450][150]
  const int lane = threadIdx.x;
  const int slot = gt * 16 + (lane & 15);
  const int type = slot / 160, j = slot - type * 160;
  const int row = type * 150 + j;
  const bool valid = (j < 150);
  const int kbase = (lane >> 4) * 8;
  unsigned short* dst = bpackM + ((((size_t)d * 30 + gt) * 6 + kt) * 64 + lane) * 8;
#pragma unroll
  for (int jj = 0; jj < 8; jj++) {
    float f = 0.f;
    if (valid) {
      if (kt < 5) {
        const int k = kt * 32 + kbase + jj;
        if (k < 150) f = Whh[row * 150 + k];
      } else {
        const int k = kbase + jj;
        if (k < 17) f = Wih[row * 17 + k];
      }
    }
    dst[jj] = f2bf(f);
  }
}

// ---------------------------------------------------------------------------
// Main bi-GRU, M=1 MFMA, 10 waves (validated r5). Tweak: A-frags hoisted.
__global__ __launch_bounds__(640, 2) void k_main_gru_mfma(
    const float* __restrict__ x,               // [1024][64][17]
    const unsigned short* __restrict__ bpackM, // [2][30][6][64][8]
    const float* __restrict__ bihf, const float* __restrict__ bhhf,
    const float* __restrict__ bihb, const float* __restrict__ bhhb,
    unsigned short* __restrict__ rnn16)        // [1024][64][320]
{
  const int d = blockIdx.x & 1, b = blockIdx.x >> 1;
  const int tid = threadIdx.x, w = tid >> 6, lane = tid & 63;
  const int col = lane & 15, q8 = (lane >> 4) * 8;
  __shared__ __align__(16) unsigned short hx[2][160];
  __shared__ __align__(16) unsigned short hist[2][16][160];
  __shared__ __align__(16) unsigned short xall[kT][32];
  for (int i = tid; i < 2 * 160; i += 640) ((unsigned short*)hx)[i] = 0;
  for (int i = tid; i < 2 * 16 * 160; i += 640) ((unsigned short*)hist)[i] = 0;
  for (int i = tid; i < kT * 32; i += 640) {
    const int t = i >> 5, c = i & 31;
    xall[t][c] = (c < kDIN) ? f2bf(x[((size_t)t * kB + b) * kDIN + c]) : (unsigned short)0;
  }
  const float* bih = d ? bihb : bihf;
  const float* bhh = d ? bhhb : bhhf;
  const int j = w * 16 + col;
  const bool actv = (lane < 16) && (j < kHM);
  float br = 0.f, bz = 0.f, bnx = 0.f, bnh = 0.f;
  if (actv) {
    br  = bih[j] + bhh[j];
    bz  = bih[150 + j] + bhh[150 + j];
    bnx = bih[300 + j];
    bnh = bhh[300 + j];
  }
  bf16x8 bw[3][6];
  const unsigned short* bp = bpackM + (size_t)d * 30 * 6 * 64 * 8;
  const int gts[3] = { w, 10 + w, 20 + w };
#pragma unroll
  for (int gi = 0; gi < 3; gi++)
#pragma unroll
    for (int kt = 0; kt < 6; kt++)
      bw[gi][kt] = *(const bf16x8*)&bp[(((size_t)gts[gi] * 6 + kt) * 64 + lane) * 8];
  float h_old = 0.f;
  __syncthreads();

  for (int t = 0; t < kT; t++) {
    const int tx = d ? (kT - 1 - t) : t;
    const int buf = t & 1;
    bf16x8 afr[6];
#pragma unroll
    for (int kt = 0; kt < 5; kt++) afr[kt] = *(const bf16x8*)&hx[buf][kt * 32 + q8];
    afr[5] = *(const bf16x8*)&xall[tx][q8];
    f32x4 aR0 = (f32x4)(0.f), aR1 = (f32x4)(0.f);
    f32x4 aZ0 = (f32x4)(0.f), aZ1 = (f32x4)(0.f);
    f32x4 aN0 = (f32x4)(0.f), aN1 = (f32x4)(0.f);
    f32x4 aX  = (f32x4)(0.f);
#pragma unroll
    for (int kt = 0; kt < 6; kt++) {
      const bf16x8 af = afr[kt];
      if ((kt & 1) == 0) {
        aR0 = __builtin_amdgcn_mfma_f32_16x16x32_bf16(af, bw[0][kt], aR0, 0, 0, 0);
        aZ0 = __builtin_amdgcn_mfma_f32_16x16x32_bf16(af, bw[1][kt], aZ0, 0, 0, 0);
        aN0 = __builtin_amdgcn_mfma_f32_16x16x32_bf16(af, bw[2][kt], aN0, 0, 0, 0);
      } else if (kt < 5) {
        aR1 = __builtin_amdgcn_mfma_f32_16x16x32_bf16(af, bw[0][kt], aR1, 0, 0, 0);
        aZ1 = __builtin_amdgcn_mfma_f32_16x16x32_bf16(af, bw[1][kt], aZ1, 0, 0, 0);
        aN1 = __builtin_amdgcn_mfma_f32_16x16x32_bf16(af, bw[2][kt], aN1, 0, 0, 0);
      } else {
        aR1 = __builtin_amdgcn_mfma_f32_16x16x32_bf16(af, bw[0][5], aR1, 0, 0, 0);
        aZ1 = __builtin_amdgcn_mfma_f32_16x16x32_bf16(af, bw[1][5], aZ1, 0, 0, 0);
        aX  = __builtin_amdgcn_mfma_f32_16x16x32_bf16(af, bw[2][5], aX, 0, 0, 0);
      }
    }
    if (actv) {
      const float r = sigm(aR0[0] + aR1[0] + br);
      const float z = sigm(aZ0[0] + aZ1[0] + bz);
      const float n = tanh_fast(aX[0] + bnx + r * (aN0[0] + aN1[0] + bnh));
      h_old = (1.f - z) * n + z * h_old;
      const unsigned short us = f2bf(h_old);
      hx[buf ^ 1][j] = us;
      hist[(t >> 4) & 1][t & 15][j] = us;
    }
    __syncthreads();
    if ((t & 15) == 15) {
      const int hb = (t >> 4) & 1;
      const int toff = tid / 40, ch = tid - toff * 40;
      const int tg = t - 15 + toff;
      const int txg = d ? (kT - 1 - tg) : tg;
      *(ushort4*)&rnn16[((size_t)txg * kB + b) * 320 + d * 160 + ch * 4] =
          *(const ushort4*)&hist[hb][toff][ch * 4];
    }
  }
}

// ---------------------------------------------------------------------------
// Hier bi-GRU via bf16 MFMA. r6: K-layout = rnn16 320-layout (coalesced uint4
// staging), fp32 h state in registers (LDS ~25 KB -> ~6 blocks/CU), B-frag
// double-buffer across kt.
__global__ __launch_bounds__(256) void k_hier_mfma(
    const unsigned short* __restrict__ rnn16,  // [1024][64][320]
    const unsigned short* __restrict__ bpack,  // [2][24][14][64][8]
    const float* __restrict__ bihf, const float* __restrict__ bhhf,
    const float* __restrict__ bihb, const float* __restrict__ bhhb,
    unsigned short* __restrict__ hv16)         // [4096][16][256]
{
  const int d = blockIdx.x & 1;
  const int bn0 = (blockIdx.x >> 1) * 16;
  const int tid = threadIdx.x;
  const int w = tid >> 6;
  const int lane = tid & 63;
  const int q = lane >> 4, col = lane & 15, q8 = q * 8;

  __shared__ __align__(16) unsigned short x_s[2][16][328];
  __shared__ __align__(16) unsigned short h_s[16][136];

  for (int i = tid; i < 16 * 136; i += 256) ((unsigned short*)h_s)[i] = 0;
  const float* bih = d ? bihb : bihf;
  const float* bhh = d ? bhhb : bhhf;
  const int j0 = w * 16 + col, j1 = 64 + w * 16 + col;
  const float biR0 = bih[j0] + bhh[j0],             biR1 = bih[j1] + bhh[j1];
  const float biZ0 = bih[128 + j0] + bhh[128 + j0], biZ1 = bih[128 + j1] + bhh[128 + j1];
  const float biNX0 = bih[256 + j0], biNX1 = bih[256 + j1];
  const float biNH0 = bhh[256 + j0], biNH1 = bhh[256 + j1];
  float h32r[2][4];
#pragma unroll
  for (int a = 0; a < 2; a++)
#pragma unroll
    for (int i = 0; i < 4; i++) h32r[a][i] = 0.f;

  { // stage m=0 (pure coalesced uint4 row copies; pads already zero in rnn16)
    const int mx0 = d ? 15 : 0;
    for (int i = tid; i < 640; i += 256) {
      const int r = i / 40, c = i - r * 40;
      const int bn = bn0 + r, bb = bn >> 6, nn = bn & 63;
      *(uint4*)&x_s[0][r][c * 8] =
          *(const uint4*)&rnn16[((size_t)(nn * 16 + mx0) * 64 + bb) * 320 + c * 8];
    }
  }
  __syncthreads();

  const unsigned short* bpd = bpack + (size_t)d * 24 * 14 * 64 * 8;

  for (int m = 0; m < kM; m++) {
    const int mx = d ? (15 - m) : m;
    const int buf = m & 1;
    f32x4 aR[2], aZ[2], aNX[2], aNH[2];
#pragma unroll
    for (int t = 0; t < 2; t++) {
      aR[t] = (f32x4)(0.f); aZ[t] = (f32x4)(0.f);
      aNX[t] = (f32x4)(0.f); aNH[t] = (f32x4)(0.f);
    }
    // B double-buffer across kt
    bf16x8 bcur[6], bnxt[6];
#pragma unroll
    for (int t = 0; t < 6; t++) {
      const int nt = w + 4 * t;
      bcur[t] = *(const bf16x8*)&bpd[(((size_t)nt * 14 + 0) * 64 + lane) * 8];
    }
#pragma unroll
    for (int kt = 0; kt < 14; kt++) {
      if (kt < 13) {
#pragma unroll
        for (int t = 0; t < 6; t++) {
          const int nt = w + 4 * t;
          bnxt[t] = *(const bf16x8*)&bpd[(((size_t)nt * 14 + kt + 1) * 64 + lane) * 8];
        }
      }
      bf16x8 af;
      if (kt < 10) af = *(const bf16x8*)&x_s[buf][col][kt * 32 + q8];
      else         af = *(const bf16x8*)&h_s[col][(kt - 10) * 32 + q8];
#pragma unroll
      for (int t = 0; t < 6; t++) {
        if (t < 2)        aR[t]      = __builtin_amdgcn_mfma_f32_16x16x32_bf16(af, bcur[t], aR[t], 0, 0, 0);
        else if (t < 4)   aZ[t - 2]  = __builtin_amdgcn_mfma_f32_16x16x32_bf16(af, bcur[t], aZ[t - 2], 0, 0, 0);
        else if (kt < 10) aNX[t - 4] = __builtin_amdgcn_mfma_f32_16x16x32_bf16(af, bcur[t], aNX[t - 4], 0, 0, 0);
        else              aNH[t - 4] = __builtin_amdgcn_mfma_f32_16x16x32_bf16(af, bcur[t], aNH[t - 4], 0, 0, 0);
      }
#pragma unroll
      for (int t = 0; t < 6; t++) bcur[t] = bnxt[t];
    }
    __syncthreads();   // all MFMA ds_reads of h_s/x_s done
#pragma unroll
    for (int jt = 0; jt < 2; jt++) {
      const int j = jt ? j1 : j0;
      const float bR = jt ? biR1 : biR0, bZ = jt ? biZ1 : biZ0;
      const float bNX = jt ? biNX1 : biNX0, bNH = jt ? biNH1 : biNH0;
#pragma unroll
      for (int i = 0; i < 4; i++) {
        const int row = q * 4 + i;
        const float rr = sigm(aR[jt][i] + bR);
        const float zz = sigm(aZ[jt][i] + bZ);
        const float nn2 = tanh_fast(aNX[jt][i] + bNX + rr * (aNH[jt][i] + bNH));
        const float hnew = (1.f - zz) * nn2 + zz * h32r[jt][i];
        h32r[jt][i] = hnew;
        const unsigned short us = f2bf(hnew);
        h_s[row][j] = us;
        hv16[((size_t)(bn0 + row) * kM + mx) * 256 + d * kHH + j] = us;
      }
    }
    if (m + 1 < kM) {
      const int mxn = d ? (15 - (m + 1)) : (m + 1);
      for (int i = tid; i < 640; i += 256) {
        const int r = i / 40, c = i - r * 40;
        const int bn = bn0 + r, bb = bn >> 6, nn = bn & 63;
        *(uint4*)&x_s[buf ^ 1][r][c * 8] =
            *(const uint4*)&rnn16[((size_t)(nn * 16 + mxn) * 64 + bb) * 320 + c * 8];
      }
    }
    __syncthreads();
  }
}

// ---------------------------------------------------------------------------
// Attention: PT-GEMV via MFMA (all waves) + score matrix via a SECOND MFMA
// (wave 0, Ts in bf16) instead of per-thread 256-wide dots.
__global__ __launch_bounds__(256) void k_attn2(
    const unsigned short* __restrict__ hv16, const unsigned short* __restrict__ ptpack,
    const float* __restrict__ u, const float* __restrict__ w,
    const float* __restrict__ c0p, float* __restrict__ ctx) {
  const int tid = threadIdx.x, n = blockIdx.x;
  const int wv = tid >> 6, lane = tid & 63, col = lane & 15, q = lane >> 4, q8 = q * 8;
  __shared__ __align__(16) unsigned short hv16s[16][264];
  __shared__ __align__(16) float hvs32[16][256];
  __shared__ __align__(16) unsigned short Ts16[16][264];
  __shared__ float pu[16][17], pw[16][17];
  __shared__ float uh[16], wh[16], SM[16];
  __shared__ float As[16][17];
  const float c0 = c0p[0];
  {
    const unsigned short* src = hv16 + (size_t)n * 4096;
    const int row = tid >> 4, ci = (tid & 15) * 16;
#pragma unroll
    for (int k = 0; k < 16; k += 4) {
      const ushort4 v = *(const ushort4*)&src[row * 256 + ci + k];
      *(ushort4*)&hv16s[row][ci + k] = v;
      hvs32[row][ci + k + 0] = bf2f(v.x);
      hvs32[row][ci + k + 1] = bf2f(v.y);
      hvs32[row][ci + k + 2] = bf2f(v.z);
      hvs32[row][ci + k + 3] = bf2f(v.w);
    }
  }
  __syncthreads();
  // PT MFMA: wave wv -> n-tiles {4wv..4wv+3}
  {
    f32x4 acc[4];
#pragma unroll
    for (int i2 = 0; i2 < 4; i2++) acc[i2] = (f32x4)(0.f);
#pragma unroll
    for (int kt = 0; kt < 8; kt++) {
      const bf16x8 af = *(const bf16x8*)&hv16s[col][kt * 32 + q8];
#pragma unroll
      for (int i2 = 0; i2 < 4; i2++) {
        const int nt = wv * 4 + i2;
        const bf16x8 bfr = *(const bf16x8*)&ptpack[(((size_t)nt * 8 + kt) * 64 + lane) * 8];
        acc[i2] = __builtin_amdgcn_mfma_f32_16x16x32_bf16(af, bfr, acc[i2], 0, 0, 0);
      }
    }
#pragma unroll
    for (int i2 = 0; i2 < 4; i2++) {
      const int nt = wv * 4 + i2;
#pragma unroll
      for (int i = 0; i < 4; i++) Ts16[q * 4 + i][nt * 16 + col] = f2bf(acc[i2][i]);
    }
  }
  { // u/w partial dots
    const int l = tid >> 4, s = tid & 15;
    float su = 0.f, sw = 0.f;
#pragma unroll
    for (int a0 = 0; a0 < 16; a0 += 4) {
      const int a = s * 16 + a0;
      const float4 hq = *(const float4*)&hvs32[l][a];
      const float4 uq = *(const float4*)&u[a];
      const float4 wq = *(const float4*)&w[a];
      su += hq.x * uq.x + hq.y * uq.y + hq.z * uq.z + hq.w * uq.w;
      sw += hq.x * wq.x + hq.y * wq.y + hq.z * wq.z + hq.w * wq.w;
    }
    pu[l][s] = su; pw[l][s] = sw;
  }
  __syncthreads();
  if (tid < 16) { float s2 = 0.f; for (int s = 0; s < 16; s++) s2 += pu[tid][s]; uh[tid] = s2; }
  else if (tid < 32) { float s2 = 0.f; for (int s = 0; s < 16; s++) s2 += pw[tid - 16][s]; wh[tid - 16] = s2; }
  __syncthreads();
  if (tid < 64) {  // wave 0: scores S[l][mm] = hv . Ts^T via MFMA, then softmax
    f32x4 sa = (f32x4)(0.f);
#pragma unroll
    for (int kt = 0; kt < 8; kt++) {
      const bf16x8 af  = *(const bf16x8*)&hv16s[col][kt * 32 + q8];
      const bf16x8 bts = *(const bf16x8*)&Ts16[col][kt * 32 + q8];
      sa = __builtin_amdgcn_mfma_f32_16x16x32_bf16(af, bts, sa, 0, 0, 0);
    }
#pragma unroll
    for (int i = 0; i < 4; i++) {
      const int l = q * 4 + i;
      float sc = sa[i] + c0 + uh[l] + wh[col];
      float mxv = sc;
#pragma unroll
      for (int o = 8; o >= 1; o >>= 1) mxv = fmaxf(mxv, __shfl_xor(mxv, o, 16));
      const float e = __expf(sc - mxv);
      float se = e;
#pragma unroll
      for (int o = 8; o >= 1; o >>= 1) se += __shfl_xor(se, o, 16);
      As[l][col] = e / se;
    }
  }
  __syncthreads();
  if (tid < 16) {
    float s = 0.f;
    for (int l2 = 0; l2 < 16; l2++) s += As[l2][tid];
    SM[tid] = s;
  }
  __syncthreads();
  float cv = 0.f;
#pragma unroll
  for (int m2 = 0; m2 < 16; m2++) cv += SM[m2] * hvs32[m2][tid];
  ctx[(size_t)n * 256 + tid] = cv;
}

// ---------------------------------------------------------------------------
// ctx-dependent logits: 256 blocks x 16 bn, weights staged once per block.
__global__ __launch_bounds__(256) void k_ctxlog2(
    const float* __restrict__ ctx, const float* __restrict__ Wp, const float* __restrict__ bp,
    const float* __restrict__ Wk, const float* __restrict__ bk,
    float* __restrict__ clog, float* __restrict__ kslogp) {
  const int tid = threadIdx.x;
  __shared__ __align__(16) float W2[50][260];  // 0..34 pitch(ctx part), 35..49 ks
  __shared__ __align__(16) float cs[256];
  __shared__ float arr[64];
  __shared__ float bps[35], bks[15];
  for (int i = tid; i < 35 * 256; i += 256) { const int r = i >> 8, c = i & 255; W2[r][c] = Wp[r * 556 + 300 + c]; }
  for (int i = tid; i < 15 * 256; i += 256) { const int r = i >> 8, c = i & 255; W2[35 + r][c] = Wk[r * 256 + c]; }
  if (tid < 35) bps[tid] = bp[tid];
  else if (tid < 50) bks[tid - 35] = bk[tid - 35];
  __syncthreads();
  const int o = tid >> 2, s = tid & 3;
  for (int it = 0; it < 16; it++) {
    const int bn = blockIdx.x * 16 + it;
    cs[tid] = ctx[(size_t)bn * 256 + tid];
    __syncthreads();
    float v = 0.f;
    if (o < 50) {
      for (int k0 = 0; k0 < 64; k0 += 4) {
        const int k = s * 64 + k0;
        const float4 wq = *(const float4*)&W2[o][k];
        const float4 cq = *(const float4*)&cs[k];
        v += wq.x * cq.x + wq.y * cq.y + wq.z * cq.z + wq.w * cq.w;
      }
    }
    v += __shfl_xor(v, 1);
    v += __shfl_xor(v, 2);
    if (o < 50 && s == 0) arr[o] = v;
    __syncthreads();
    if (tid < 35) clog[bn * kNP + tid] = arr[tid] + bps[tid];
    if (tid >= 64 && tid < 80) {
      const int t2 = tid - 64;
      float kk = (t2 < 15) ? arr[35 + t2] + bks[t2] : -1e30f;
      float mxv = kk;
#pragma unroll
      for (int off = 8; off >= 1; off >>= 1) mxv = fmaxf(mxv, __shfl_xor(mxv, off, 16));
      const float e = (t2 < 15) ? __expf(kk - mxv) : 0.f;
      float se = e;
#pragma unroll
      for (int off = 8; off >= 1; off >>= 1) se += __shfl_xor(se, off, 16);
      if (t2 < 15) kslogp[bn * kNK + t2] = kk - mxv - __logf(se);
    }
    __syncthreads();
  }
}

// ---------------------------------------------------------------------------
__global__ __launch_bounds__(256) void k_loss(
    const unsigned short* __restrict__ rnn16, const float* __restrict__ Wp,
    const float* __restrict__ ctx_logits, const float* __restrict__ ks_logp,
    const int* __restrict__ pitches, const int* __restrict__ kss,
    float* __restrict__ acc) {
  __shared__ __align__(16) float W1[35][308];
  __shared__ __align__(16) float xrs[4][304];
  __shared__ float red[4][4];
  const int tid = threadIdx.x, w = tid >> 6, lane = tid & 63;
  for (int i = tid; i < 35 * 300; i += 256) {
    const int j = i / 300, k = i - j * 300;
    W1[j][k] = Wp[j * 556 + k];
  }
  __syncthreads();
  float sp = 0.f, cp = 0.f, sk = 0.f, ck = 0.f;
  for (int it = 0; it < 64; it++) {
    const int row = blockIdx.x * 256 + it * 4 + w; // row = t*64 + b
    const int t = row >> 6, b = row & 63;
    const unsigned short* rp = rnn16 + (size_t)row * 320;
    for (int i = lane; i < kD2; i += 64) xrs[w][i] = bf2f(rp[i < 150 ? i : i + 10]);
    __syncthreads();
    const int bn = b * 64 + (t >> 4);
    float lg = -1e30f;
    if (lane < 35) {
      float a0 = 0.f, a1 = 0.f, a2 = 0.f, a3 = 0.f;
      for (int k = 0; k < kD2; k += 4) {
        const float4 wq = *(const float4*)&W1[lane][k];
        const float4 xq = *(const float4*)&xrs[w][k];
        a0 += wq.x * xq.x; a1 += wq.y * xq.y; a2 += wq.z * xq.z; a3 += wq.w * xq.w;
      }
      lg = (a0 + a1) + (a2 + a3) + ctx_logits[bn * kNP + lane];
    }
    float mxv = lg;
#pragma unroll
    for (int o = 32; o >= 1; o >>= 1) mxv = fmaxf(mxv, __shfl_xor(mxv, o, 64));
    const float e = (lane < 35) ? __expf(lg - mxv) : 0.f;
    float se = e;
#pragma unroll
    for (int o = 32; o >= 1; o >>= 1) se += __shfl_xor(se, o, 64);
    const int tp2 = pitches[row];
    if (tp2 != 34) { sp += (mxv + __logf(se)) - __shfl(lg, tp2, 64); cp += 1.f; }
    const int tk = kss[row];
    if (tk != 14) { sk -= ks_logp[bn * kNK + tk]; ck += 1.f; }
    __syncthreads();
  }
  if (lane == 0) { red[w][0] = sp; red[w][1] = cp; red[w][2] = sk; red[w][3] = ck; }
  __syncthreads();
  if (tid == 0) {
    float a0 = 0.f, a1 = 0.f, a2 = 0.f, a3 = 0.f;
    for (int q = 0; q < 4; q++) { a0 += red[q][0]; a1 += red[q][1]; a2 += red[q][2]; a3 += red[q][3]; }
    atomicAdd(&acc[0], a0); atomicAdd(&acc[1], a1);
    atomicAdd(&acc[2], a2); atomicAdd(&acc[3], a3);
  }
}

__global__ void k_final(const float* __restrict__ acc, float* __restrict__ out) {
  out[0] = acc[0] / fmaxf(acc[1], 1.f) + acc[2] / fmaxf(acc[3], 1.f);
}

// ---------------------------------------------------------------------------
extern "C" void kernel_launch(void* const* d_in, const int* in_sizes, int n_in,
                              void* d_out, int out_size, void* d_ws, size_t ws_size,
                              hipStream_t stream) {
  (void)in_sizes; (void)n_in; (void)out_size; (void)ws_size;
  const float* sent    = (const float*)d_in[0];
  const int*   pitches = (const int*)d_in[1];
  const int*   kss     = (const int*)d_in[2];
  const float* mWih_f  = (const float*)d_in[5];
  const float* mWhh_f  = (const float*)d_in[6];
  const float* mbih_f  = (const float*)d_in[7];
  const float* mbhh_f  = (const float*)d_in[8];
  const float* mWih_b  = (const float*)d_in[9];
  const float* mWhh_b  = (const float*)d_in[10];
  const float* mbih_b  = (const float*)d_in[11];
  const float* mbhh_b  = (const float*)d_in[12];
  const float* hWih_f  = (const float*)d_in[13];
  const float* hWhh_f  = (const float*)d_in[14];
  const float* hbih_f  = (const float*)d_in[15];
  const float* hbhh_f  = (const float*)d_in[16];
  const float* hWih_b  = (const float*)d_in[17];
  const float* hWhh_b  = (const float*)d_in[18];
  const float* hbih_b  = (const float*)d_in[19];
  const float* hbhh_b  = (const float*)d_in[20];
  const float* Wq      = (const float*)d_in[21];
  const float* bq      = (const float*)d_in[22];
  const float* Wv      = (const float*)d_in[23];
  const float* bv      = (const float*)d_in[24];
  const float* Wp      = (const float*)d_in[25];
  const float* bp      = (const float*)d_in[26];
  const float* Wk      = (const float*)d_in[27];
  const float* bk      = (const float*)d_in[28];
  float* ws  = (float*)d_ws;
  float* out = (float*)d_out;
  unsigned short* rnn16  = (unsigned short*)(ws + OFF_RNN16);
  unsigned short* hv16   = (unsigned short*)(ws + OFF_HV16);
  unsigned short* ptpack = (unsigned short*)(ws + OFF_PTPACK);

  k_repack_main<<<360, 64, 0, stream>>>(mWih_f, mWhh_f, mWih_b, mWhh_b,
                                        (unsigned short*)(ws + OFF_BPACKM));
  k_repack<<<672, 64, 0, stream>>>(hWih_f, hWhh_f, hWih_b, hWhh_b,
                                   (unsigned short*)(ws + OFF_BPACK));
  k_pt<<<256, 256, 0, stream>>>(Wq, Wv, ws + OFF_PT);
  k_ptpack<<<128, 64, 0, stream>>>(ws + OFF_PT, ptpack);
  k_small<<<1, 256, 0, stream>>>(Wq, bq, Wv, bv, ws + OFF_U, ws + OFF_W, ws + OFF_C0, ws + OFF_ACC);

  k_main_gru_mfma<<<128, 640, 0, stream>>>(sent, (const unsigned short*)(ws + OFF_BPACKM),
                                           mbih_f, mbhh_f, mbih_b, mbhh_b, rnn16);
  k_hier_mfma<<<512, 256, 0, stream>>>(rnn16, (const unsigned short*)(ws + OFF_BPACK),
                                       hbih_f, hbhh_f, hbih_b, hbhh_b, hv16);
  k_attn2<<<4096, 256, 0, stream>>>(hv16, ptpack, ws + OFF_U, ws + OFF_W,
                                    ws + OFF_C0, ws + OFF_CTX);
  k_ctxlog2<<<256, 256, 0, stream>>>(ws + OFF_CTX, Wp, bp, Wk, bk,
                                     ws + OFF_CLOG, ws + OFF_KSLOGP);
  k_loss<<<256, 256, 0, stream>>>(rnn16, Wp, ws + OFF_CLOG, ws + OFF_KSLOGP,
                                  pitches, kss, ws + OFF_ACC);
  k_final<<<1, 1, 0, stream>>>(ws + OFF_ACC, out);
}

// Round 7
// 1204.573 us; speedup vs baseline: 1.4236x; 1.0286x over previous
//
#include <hip/hip_runtime.h>
#include <cstddef>

// ---- problem constants ----
constexpr int kT   = 1024;
constexpr int kB   = 64;
constexpr int kDIN = 17;
constexpr int kHM  = 150;   // main hidden (per dir)
constexpr int kHH  = 128;   // hier hidden (per dir)
constexpr int kM   = 16;    // measure length
constexpr int kD2  = 300;   // 2*kHM
constexpr int kNP  = 35;
constexpr int kNK  = 15;

// ---- workspace layout (float offsets, 16-float aligned) ----
constexpr size_t OFF_RNN16  = 0;          // ushort [1024][64][320] = 10,485,760 f
constexpr size_t OFF_HV16   = 10485760;   // ushort [4096][16][256] = 8,388,608 f
constexpr size_t OFF_CTX    = 18874368;   // f32 [4096][256] = 1,048,576
constexpr size_t OFF_PT     = 19922944;   // f32 [256][256] = 65,536
constexpr size_t OFF_PTPACK = 19988480;   // ushort [16][8][64][8] = 32,768 f
constexpr size_t OFF_U      = 20021248;   // [256]
constexpr size_t OFF_W      = 20021504;   // [256]
constexpr size_t OFF_C0     = 20021760;   // [16]
constexpr size_t OFF_ACC    = 20021776;   // [16]
constexpr size_t OFF_KSLOGP = 20021792;   // [4096][15]
constexpr size_t OFF_CLOG   = 20083232;   // [4096][35]
constexpr size_t OFF_BPACKM = 20226592;   // ushort [2][30][6][64][8] = 92,160 f
constexpr size_t OFF_BPACK  = 20318752;   // ushort [2][24][14][64][8] = 172,032 f

typedef __bf16 bf16x8 __attribute__((ext_vector_type(8)));
typedef float f32x4 __attribute__((ext_vector_type(4)));

__device__ __forceinline__ unsigned short f2bf(float f) {
  unsigned u = __float_as_uint(f);
  u += 0x7FFFu + ((u >> 16) & 1u);
  return (unsigned short)(u >> 16);
}
__device__ __forceinline__ float bf2f(unsigned short v) {
  return __uint_as_float(((unsigned)v) << 16);
}
__device__ __forceinline__ float sigm(float x) {
  return __builtin_amdgcn_rcpf(1.f + __expf(-x));
}
__device__ __forceinline__ float tanh_fast(float x) {
  return 1.f - 2.f * __builtin_amdgcn_rcpf(__expf(2.f * x) + 1.f);
}

// PT[e][c] = sum_a Wq[a][c]*Wv[a][e]
__global__ void k_pt(const float* __restrict__ Wq, const float* __restrict__ Wv,
                     float* __restrict__ PT) {
  const int e = blockIdx.x, c = threadIdx.x;
  float acc = 0.f;
  for (int a = 0; a < 256; a++) acc += Wq[a * 256 + c] * Wv[a * 256 + e];
  PT[e * 256 + c] = acc;
}

// PTpack[nt(16)][kt(8)][lane(64)][8]: B[k=e][n=c] = PT[e][c], bf16
__global__ void k_ptpack(const float* __restrict__ PT, unsigned short* __restrict__ pp) {
  const int bid = blockIdx.x;           // 128 = nt*8+kt
  const int kt = bid & 7, nt = bid >> 3;
  const int lane = threadIdx.x;
  const int c = nt * 16 + (lane & 15);
  const int e0 = kt * 32 + (lane >> 4) * 8;
#pragma unroll
  for (int j = 0; j < 8; j++)
    pp[((size_t)bid * 64 + lane) * 8 + j] = f2bf(PT[(e0 + j) * 256 + c]);
}

__global__ void k_small(const float* __restrict__ Wq, const float* __restrict__ bq,
                        const float* __restrict__ Wv, const float* __restrict__ bv,
                        float* __restrict__ u, float* __restrict__ w,
                        float* __restrict__ c0, float* __restrict__ acc) {
  const int a = threadIdx.x; // 256
  float us = 0.f, ws = 0.f;
  for (int j = 0; j < 256; j++) {
    us += Wq[j * 256 + a] * bv[j];
    ws += bq[j] * Wv[j * 256 + a];
  }
  u[a] = us; w[a] = ws;
  if (a == 0) {
    float c = 0.f;
    for (int j = 0; j < 256; j++) c += bq[j] * bv[j];
    c0[0] = c;
    acc[0] = acc[1] = acc[2] = acc[3] = 0.f;
  }
}

// ---------------------------------------------------------------------------
// hier weights -> bf16 B-frags; K-layout = rnn16 320-col padded layout (r6).
__global__ void k_repack(const float* __restrict__ hWih_f, const float* __restrict__ hWhh_f,
                         const float* __restrict__ hWih_b, const float* __restrict__ hWhh_b,
                         unsigned short* __restrict__ bpack) {
  const int bid = blockIdx.x;           // 672
  const int kt = bid % 14;
  const int nt = (bid / 14) % 24;
  const int d  = bid / (14 * 24);
  const float* Wih = d ? hWih_b : hWih_f;   // [384][300]
  const float* Whh = d ? hWhh_b : hWhh_f;   // [384][128]
  const int lane = threadIdx.x;
  const int n = nt * 16 + (lane & 15);
  const int kbase = kt * 32 + (lane >> 4) * 8;
  unsigned short* dst = bpack + ((((size_t)d * 24 + nt) * 14 + kt) * 64 + lane) * 8;
#pragma unroll
  for (int j = 0; j < 8; j++) {
    const int k = kbase + j;
    float f = 0.f;
    if (kt < 10) {
      if (k < 150) f = Wih[n * 300 + k];
      else if (k >= 160 && k < 310) f = Wih[n * 300 + (k - 10)];
    } else {
      f = Whh[n * 128 + (k - 320)];
    }
    dst[j] = f2bf(f);
  }
}

// main weights -> bf16 B-frags (validated r3)
__global__ void k_repack_main(const float* __restrict__ mWih_f, const float* __restrict__ mWhh_f,
                              const float* __restrict__ mWih_b, const float* __restrict__ mWhh_b,
                              unsigned short* __restrict__ bpackM) {
  const int bid = blockIdx.x;          // 360
  const int kt = bid % 6;
  const int gt = (bid / 6) % 30;
  const int d  = bid / 180;
  const float* Wih = d ? mWih_b : mWih_f;  // [450][17]
  const float* Whh = d ? mWhh_b : mWhh_f;  // [450][150]
  const int lane = threadIdx.x;
  const int slot = gt * 16 + (lane & 15);
  const int type = slot / 160, j = slot - type * 160;
  const int row = type * 150 + j;
  const bool valid = (j < 150);
  const int kbase = (lane >> 4) * 8;
  unsigned short* dst = bpackM + ((((size_t)d * 30 + gt) * 6 + kt) * 64 + lane) * 8;
#pragma unroll
  for (int jj = 0; jj < 8; jj++) {
    float f = 0.f;
    if (valid) {
      if (kt < 5) {
        const int k = kt * 32 + kbase + jj;
        if (k < 150) f = Whh[row * 150 + k];
      } else {
        const int k = kbase + jj;
        if (k < 17) f = Wih[row * 17 + k];
      }
    }
    dst[jj] = f2bf(f);
  }
}

// ---------------------------------------------------------------------------
// Main bi-GRU, M=1 MFMA, 10 waves (validated r5/r6 — structural floor).
__global__ __launch_bounds__(640, 2) void k_main_gru_mfma(
    const float* __restrict__ x,               // [1024][64][17]
    const unsigned short* __restrict__ bpackM, // [2][30][6][64][8]
    const float* __restrict__ bihf, const float* __restrict__ bhhf,
    const float* __restrict__ bihb, const float* __restrict__ bhhb,
    unsigned short* __restrict__ rnn16)        // [1024][64][320]
{
  const int d = blockIdx.x & 1, b = blockIdx.x >> 1;
  const int tid = threadIdx.x, w = tid >> 6, lane = tid & 63;
  const int col = lane & 15, q8 = (lane >> 4) * 8;
  __shared__ __align__(16) unsigned short hx[2][160];
  __shared__ __align__(16) unsigned short hist[2][16][160];
  __shared__ __align__(16) unsigned short xall[kT][32];
  for (int i = tid; i < 2 * 160; i += 640) ((unsigned short*)hx)[i] = 0;
  for (int i = tid; i < 2 * 16 * 160; i += 640) ((unsigned short*)hist)[i] = 0;
  for (int i = tid; i < kT * 32; i += 640) {
    const int t = i >> 5, c = i & 31;
    xall[t][c] = (c < kDIN) ? f2bf(x[((size_t)t * kB + b) * kDIN + c]) : (unsigned short)0;
  }
  const float* bih = d ? bihb : bihf;
  const float* bhh = d ? bhhb : bhhf;
  const int j = w * 16 + col;
  const bool actv = (lane < 16) && (j < kHM);
  float br = 0.f, bz = 0.f, bnx = 0.f, bnh = 0.f;
  if (actv) {
    br  = bih[j] + bhh[j];
    bz  = bih[150 + j] + bhh[150 + j];
    bnx = bih[300 + j];
    bnh = bhh[300 + j];
  }
  bf16x8 bw[3][6];
  const unsigned short* bp = bpackM + (size_t)d * 30 * 6 * 64 * 8;
  const int gts[3] = { w, 10 + w, 20 + w };
#pragma unroll
  for (int gi = 0; gi < 3; gi++)
#pragma unroll
    for (int kt = 0; kt < 6; kt++)
      bw[gi][kt] = *(const bf16x8*)&bp[(((size_t)gts[gi] * 6 + kt) * 64 + lane) * 8];
  float h_old = 0.f;
  __syncthreads();

  for (int t = 0; t < kT; t++) {
    const int tx = d ? (kT - 1 - t) : t;
    const int buf = t & 1;
    bf16x8 afr[6];
#pragma unroll
    for (int kt = 0; kt < 5; kt++) afr[kt] = *(const bf16x8*)&hx[buf][kt * 32 + q8];
    afr[5] = *(const bf16x8*)&xall[tx][q8];
    f32x4 aR0 = (f32x4)(0.f), aR1 = (f32x4)(0.f);
    f32x4 aZ0 = (f32x4)(0.f), aZ1 = (f32x4)(0.f);
    f32x4 aN0 = (f32x4)(0.f), aN1 = (f32x4)(0.f);
    f32x4 aX  = (f32x4)(0.f);
#pragma unroll
    for (int kt = 0; kt < 6; kt++) {
      const bf16x8 af = afr[kt];
      if ((kt & 1) == 0) {
        aR0 = __builtin_amdgcn_mfma_f32_16x16x32_bf16(af, bw[0][kt], aR0, 0, 0, 0);
        aZ0 = __builtin_amdgcn_mfma_f32_16x16x32_bf16(af, bw[1][kt], aZ0, 0, 0, 0);
        aN0 = __builtin_amdgcn_mfma_f32_16x16x32_bf16(af, bw[2][kt], aN0, 0, 0, 0);
      } else if (kt < 5) {
        aR1 = __builtin_amdgcn_mfma_f32_16x16x32_bf16(af, bw[0][kt], aR1, 0, 0, 0);
        aZ1 = __builtin_amdgcn_mfma_f32_16x16x32_bf16(af, bw[1][kt], aZ1, 0, 0, 0);
        aN1 = __builtin_amdgcn_mfma_f32_16x16x32_bf16(af, bw[2][kt], aN1, 0, 0, 0);
      } else {
        aR1 = __builtin_amdgcn_mfma_f32_16x16x32_bf16(af, bw[0][5], aR1, 0, 0, 0);
        aZ1 = __builtin_amdgcn_mfma_f32_16x16x32_bf16(af, bw[1][5], aZ1, 0, 0, 0);
        aX  = __builtin_amdgcn_mfma_f32_16x16x32_bf16(af, bw[2][5], aX, 0, 0, 0);
      }
    }
    if (actv) {
      const float r = sigm(aR0[0] + aR1[0] + br);
      const float z = sigm(aZ0[0] + aZ1[0] + bz);
      const float n = tanh_fast(aX[0] + bnx + r * (aN0[0] + aN1[0] + bnh));
      h_old = (1.f - z) * n + z * h_old;
      const unsigned short us = f2bf(h_old);
      hx[buf ^ 1][j] = us;
      hist[(t >> 4) & 1][t & 15][j] = us;
    }
    __syncthreads();
    if ((t & 15) == 15) {
      const int hb = (t >> 4) & 1;
      const int toff = tid / 40, ch = tid - toff * 40;
      const int tg = t - 15 + toff;
      const int txg = d ? (kT - 1 - tg) : tg;
      *(ushort4*)&rnn16[((size_t)txg * kB + b) * 320 + d * 160 + ch * 4] =
          *(const ushort4*)&hist[hb][toff][ch * 4];
    }
  }
}

// ---------------------------------------------------------------------------
// Hier bi-GRU. r7: 8 waves (512 thr), B-fragments REGISTER-RESIDENT across
// all 16 m-steps (42 frags/wave = 168 VGPR) -> B streamed once per block
// (was 16x). Wave w owns n-tiles {w, 8+w, 16+w} = (r,z,n) for hidden
// j = w*16+col; all 64 lanes do activation (4 rows each), h state in regs.
__global__ __launch_bounds__(512, 1) void k_hier_mfma(
    const unsigned short* __restrict__ rnn16,  // [1024][64][320]
    const unsigned short* __restrict__ bpack,  // [2][24][14][64][8]
    const float* __restrict__ bihf, const float* __restrict__ bhhf,
    const float* __restrict__ bihb, const float* __restrict__ bhhb,
    unsigned short* __restrict__ hv16)         // [4096][16][256]
{
  const int d = blockIdx.x & 1;
  const int bn0 = (blockIdx.x >> 1) * 16;
  const int tid = threadIdx.x;
  const int w = tid >> 6;          // 0..7
  const int lane = tid & 63;
  const int q = lane >> 4, col = lane & 15, q8 = q * 8;

  __shared__ __align__(16) unsigned short x_s[2][16][328];
  __shared__ __align__(16) unsigned short h_s[16][136];

  for (int i = tid; i < 16 * 136; i += 512) ((unsigned short*)h_s)[i] = 0;
  const float* bih = d ? bihb : bihf;
  const float* bhh = d ? bhhb : bhhf;
  const int j = w * 16 + col;      // 0..127
  const float biR  = bih[j] + bhh[j];
  const float biZ  = bih[128 + j] + bhh[128 + j];
  const float biNX = bih[256 + j];
  const float biNH = bhh[256 + j];
  float h32r[4] = {0.f, 0.f, 0.f, 0.f};

  // register-resident B: 3 gate-tiles x 14 kt
  bf16x8 bw[3][14];
  const unsigned short* bpd = bpack + (size_t)d * 24 * 14 * 64 * 8;
  const int nts[3] = { w, 8 + w, 16 + w };
#pragma unroll
  for (int gi = 0; gi < 3; gi++)
#pragma unroll
    for (int kt = 0; kt < 14; kt++)
      bw[gi][kt] = *(const bf16x8*)&bpd[(((size_t)nts[gi] * 14 + kt) * 64 + lane) * 8];

  { // stage m=0 x (coalesced uint4; pads already zero in rnn16)
    const int mx0 = d ? 15 : 0;
    for (int i = tid; i < 640; i += 512) {
      const int r = i / 40, c = i - r * 40;
      const int bn = bn0 + r, bb = bn >> 6, nn = bn & 63;
      *(uint4*)&x_s[0][r][c * 8] =
          *(const uint4*)&rnn16[((size_t)(nn * 16 + mx0) * 64 + bb) * 320 + c * 8];
    }
  }
  __syncthreads();

  for (int m = 0; m < kM; m++) {
    const int mx = d ? (15 - m) : m;
    const int buf = m & 1;
    f32x4 aR = (f32x4)(0.f), aZ = (f32x4)(0.f), aNX = (f32x4)(0.f), aNH = (f32x4)(0.f);
#pragma unroll
    for (int kt = 0; kt < 14; kt++) {
      const bf16x8 af = (kt < 10) ? *(const bf16x8*)&x_s[buf][col][kt * 32 + q8]
                                  : *(const bf16x8*)&h_s[col][(kt - 10) * 32 + q8];
      aR = __builtin_amdgcn_mfma_f32_16x16x32_bf16(af, bw[0][kt], aR, 0, 0, 0);
      aZ = __builtin_amdgcn_mfma_f32_16x16x32_bf16(af, bw[1][kt], aZ, 0, 0, 0);
      if (kt < 10) aNX = __builtin_amdgcn_mfma_f32_16x16x32_bf16(af, bw[2][kt], aNX, 0, 0, 0);
      else         aNH = __builtin_amdgcn_mfma_f32_16x16x32_bf16(af, bw[2][kt], aNH, 0, 0, 0);
    }
    __syncthreads();   // MFMA ds_reads of h_s/x_s done before rewrite
#pragma unroll
    for (int i = 0; i < 4; i++) {
      const int row = q * 4 + i;
      const float rr = sigm(aR[i] + biR);
      const float zz = sigm(aZ[i] + biZ);
      const float nn2 = tanh_fast(aNX[i] + biNX + rr * (aNH[i] + biNH));
      const float hnew = (1.f - zz) * nn2 + zz * h32r[i];
      h32r[i] = hnew;
      const unsigned short us = f2bf(hnew);
      h_s[row][j] = us;
      hv16[((size_t)(bn0 + row) * kM + mx) * 256 + d * kHH + j] = us;
    }
    if (m + 1 < kM) {
      const int mxn = d ? (15 - (m + 1)) : (m + 1);
      for (int i = tid; i < 640; i += 512) {
        const int r = i / 40, c = i - r * 40;
        const int bn = bn0 + r, bb = bn >> 6, nn = bn & 63;
        *(uint4*)&x_s[buf ^ 1][r][c * 8] =
            *(const uint4*)&rnn16[((size_t)(nn * 16 + mxn) * 64 + bb) * 320 + c * 8];
      }
    }
    __syncthreads();
  }
}

// ---------------------------------------------------------------------------
// Attention r7: 4 measure-groups per block (1024 blocks), ptpack B-frags
// register-resident across the 4 (32 frags = 128 VGPR).
__global__ __launch_bounds__(256) void k_attn2(
    const unsigned short* __restrict__ hv16, const unsigned short* __restrict__ ptpack,
    const float* __restrict__ u, const float* __restrict__ w,
    const float* __restrict__ c0p, float* __restrict__ ctx) {
  const int tid = threadIdx.x;
  const int wv = tid >> 6, lane = tid & 63, col = lane & 15, q = lane >> 4, q8 = q * 8;
  __shared__ __align__(16) unsigned short hv16s[16][264];
  __shared__ __align__(16) unsigned short Ts16[16][264];
  __shared__ float pu[16][17], pw[16][17];
  __shared__ float uh[16], wh[16], SM[16];
  __shared__ float As[16][17];
  const float c0 = c0p[0];
  // resident PT B-frags: 4 nt x 8 kt
  bf16x8 bpt[4][8];
#pragma unroll
  for (int i2 = 0; i2 < 4; i2++)
#pragma unroll
    for (int kt = 0; kt < 8; kt++)
      bpt[i2][kt] = *(const bf16x8*)&ptpack[((((size_t)(wv * 4 + i2)) * 8 + kt) * 64 + lane) * 8];

  for (int ni = 0; ni < 4; ni++) {
    const int n = blockIdx.x * 4 + ni;
    {
      const unsigned short* src = hv16 + (size_t)n * 4096;
      const int row = tid >> 4, ci = (tid & 15) * 16;
#pragma unroll
      for (int k = 0; k < 16; k += 4)
        *(ushort4*)&hv16s[row][ci + k] = *(const ushort4*)&src[row * 256 + ci + k];
    }
    __syncthreads();
    // PT GEMM via MFMA
    {
      f32x4 acc[4];
#pragma unroll
      for (int i2 = 0; i2 < 4; i2++) acc[i2] = (f32x4)(0.f);
#pragma unroll
      for (int kt = 0; kt < 8; kt++) {
        const bf16x8 af = *(const bf16x8*)&hv16s[col][kt * 32 + q8];
#pragma unroll
        for (int i2 = 0; i2 < 4; i2++)
          acc[i2] = __builtin_amdgcn_mfma_f32_16x16x32_bf16(af, bpt[i2][kt], acc[i2], 0, 0, 0);
      }
#pragma unroll
      for (int i2 = 0; i2 < 4; i2++) {
        const int nt = wv * 4 + i2;
#pragma unroll
        for (int i = 0; i < 4; i++) Ts16[q * 4 + i][nt * 16 + col] = f2bf(acc[i2][i]);
      }
    }
    { // u/w partial dots (bf16 source)
      const int l = tid >> 4, s = tid & 15;
      float su = 0.f, sw = 0.f;
#pragma unroll
      for (int a0 = 0; a0 < 16; a0++) {
        const int a = s * 16 + a0;
        const float hvv = bf2f(hv16s[l][a]);
        su += hvv * u[a];
        sw += hvv * w[a];
      }
      pu[l][s] = su; pw[l][s] = sw;
    }
    __syncthreads();
    if (tid < 16) { float s2 = 0.f; for (int s = 0; s < 16; s++) s2 += pu[tid][s]; uh[tid] = s2; }
    else if (tid < 32) { float s2 = 0.f; for (int s = 0; s < 16; s++) s2 += pw[tid - 16][s]; wh[tid - 16] = s2; }
    __syncthreads();
    if (tid < 64) {  // wave 0: score MFMA + softmax
      f32x4 sa = (f32x4)(0.f);
#pragma unroll
      for (int kt = 0; kt < 8; kt++) {
        const bf16x8 af  = *(const bf16x8*)&hv16s[col][kt * 32 + q8];
        const bf16x8 bts = *(const bf16x8*)&Ts16[col][kt * 32 + q8];
        sa = __builtin_amdgcn_mfma_f32_16x16x32_bf16(af, bts, sa, 0, 0, 0);
      }
#pragma unroll
      for (int i = 0; i < 4; i++) {
        const int l = q * 4 + i;
        float sc = sa[i] + c0 + uh[l] + wh[col];
        float mxv = sc;
#pragma unroll
        for (int o = 8; o >= 1; o >>= 1) mxv = fmaxf(mxv, __shfl_xor(mxv, o, 16));
        const float e = __expf(sc - mxv);
        float se = e;
#pragma unroll
        for (int o = 8; o >= 1; o >>= 1) se += __shfl_xor(se, o, 16);
        As[l][col] = e / se;
      }
    }
    __syncthreads();
    if (tid < 16) {
      float s = 0.f;
      for (int l2 = 0; l2 < 16; l2++) s += As[l2][tid];
      SM[tid] = s;
    }
    __syncthreads();
    float cv = 0.f;
#pragma unroll
    for (int m2 = 0; m2 < 16; m2++) cv += SM[m2] * bf2f(hv16s[m2][tid]);
    ctx[(size_t)n * 256 + tid] = cv;
    __syncthreads();
  }
}

// ---------------------------------------------------------------------------
// ctx-dependent logits: 256 blocks x 16 bn, weights staged once per block.
__global__ __launch_bounds__(256) void k_ctxlog2(
    const float* __restrict__ ctx, const float* __restrict__ Wp, const float* __restrict__ bp,
    const float* __restrict__ Wk, const float* __restrict__ bk,
    float* __restrict__ clog, float* __restrict__ kslogp) {
  const int tid = threadIdx.x;
  __shared__ __align__(16) float W2[50][260];
  __shared__ __align__(16) float cs[256];
  __shared__ float arr[64];
  __shared__ float bps[35], bks[15];
  for (int i = tid; i < 35 * 256; i += 256) { const int r = i >> 8, c = i & 255; W2[r][c] = Wp[r * 556 + 300 + c]; }
  for (int i = tid; i < 15 * 256; i += 256) { const int r = i >> 8, c = i & 255; W2[35 + r][c] = Wk[r * 256 + c]; }
  if (tid < 35) bps[tid] = bp[tid];
  else if (tid < 50) bks[tid - 35] = bk[tid - 35];
  __syncthreads();
  const int o = tid >> 2, s = tid & 3;
  for (int it = 0; it < 16; it++) {
    const int bn = blockIdx.x * 16 + it;
    cs[tid] = ctx[(size_t)bn * 256 + tid];
    __syncthreads();
    float v = 0.f;
    if (o < 50) {
      for (int k0 = 0; k0 < 64; k0 += 4) {
        const int k = s * 64 + k0;
        const float4 wq = *(const float4*)&W2[o][k];
        const float4 cq = *(const float4*)&cs[k];
        v += wq.x * cq.x + wq.y * cq.y + wq.z * cq.z + wq.w * cq.w;
      }
    }
    v += __shfl_xor(v, 1);
    v += __shfl_xor(v, 2);
    if (o < 50 && s == 0) arr[o] = v;
    __syncthreads();
    if (tid < 35) clog[bn * kNP + tid] = arr[tid] + bps[tid];
    if (tid >= 64 && tid < 80) {
      const int t2 = tid - 64;
      float kk = (t2 < 15) ? arr[35 + t2] + bks[t2] : -1e30f;
      float mxv = kk;
#pragma unroll
      for (int off = 8; off >= 1; off >>= 1) mxv = fmaxf(mxv, __shfl_xor(mxv, off, 16));
      const float e = (t2 < 15) ? __expf(kk - mxv) : 0.f;
      float se = e;
#pragma unroll
      for (int off = 8; off >= 1; off >>= 1) se += __shfl_xor(se, off, 16);
      if (t2 < 15) kslogp[bn * kNK + t2] = kk - mxv - __logf(se);
    }
    __syncthreads();
  }
}

// ---------------------------------------------------------------------------
__global__ __launch_bounds__(256) void k_loss(
    const unsigned short* __restrict__ rnn16, const float* __restrict__ Wp,
    const float* __restrict__ ctx_logits, const float* __restrict__ ks_logp,
    const int* __restrict__ pitches, const int* __restrict__ kss,
    float* __restrict__ acc) {
  __shared__ __align__(16) float W1[35][308];
  __shared__ __align__(16) float xrs[4][304];
  __shared__ float red[4][4];
  const int tid = threadIdx.x, w = tid >> 6, lane = tid & 63;
  for (int i = tid; i < 35 * 300; i += 256) {
    const int j = i / 300, k = i - j * 300;
    W1[j][k] = Wp[j * 556 + k];
  }
  __syncthreads();
  float sp = 0.f, cp = 0.f, sk = 0.f, ck = 0.f;
  for (int it = 0; it < 64; it++) {
    const int row = blockIdx.x * 256 + it * 4 + w; // row = t*64 + b
    const int t = row >> 6, b = row & 63;
    const unsigned short* rp = rnn16 + (size_t)row * 320;
    for (int i = lane; i < kD2; i += 64) xrs[w][i] = bf2f(rp[i < 150 ? i : i + 10]);
    __syncthreads();
    const int bn = b * 64 + (t >> 4);
    float lg = -1e30f;
    if (lane < 35) {
      float a0 = 0.f, a1 = 0.f, a2 = 0.f, a3 = 0.f;
      for (int k = 0; k < kD2; k += 4) {
        const float4 wq = *(const float4*)&W1[lane][k];
        const float4 xq = *(const float4*)&xrs[w][k];
        a0 += wq.x * xq.x; a1 += wq.y * xq.y; a2 += wq.z * xq.z; a3 += wq.w * xq.w;
      }
      lg = (a0 + a1) + (a2 + a3) + ctx_logits[bn * kNP + lane];
    }
    float mxv = lg;
#pragma unroll
    for (int o = 32; o >= 1; o >>= 1) mxv = fmaxf(mxv, __shfl_xor(mxv, o, 64));
    const float e = (lane < 35) ? __expf(lg - mxv) : 0.f;
    float se = e;
#pragma unroll
    for (int o = 32; o >= 1; o >>= 1) se += __shfl_xor(se, o, 64);
    const int tp2 = pitches[row];
    if (tp2 != 34) { sp += (mxv + __logf(se)) - __shfl(lg, tp2, 64); cp += 1.f; }
    const int tk = kss[row];
    if (tk != 14) { sk -= ks_logp[bn * kNK + tk]; ck += 1.f; }
    __syncthreads();
  }
  if (lane == 0) { red[w][0] = sp; red[w][1] = cp; red[w][2] = sk; red[w][3] = ck; }
  __syncthreads();
  if (tid == 0) {
    float a0 = 0.f, a1 = 0.f, a2 = 0.f, a3 = 0.f;
    for (int q = 0; q < 4; q++) { a0 += red[q][0]; a1 += red[q][1]; a2 += red[q][2]; a3 += red[q][3]; }
    atomicAdd(&acc[0], a0); atomicAdd(&acc[1], a1);
    atomicAdd(&acc[2], a2); atomicAdd(&acc[3], a3);
  }
}

__global__ void k_final(const float* __restrict__ acc, float* __restrict__ out) {
  out[0] = acc[0] / fmaxf(acc[1], 1.f) + acc[2] / fmaxf(acc[3], 1.f);
}

// ---------------------------------------------------------------------------
extern "C" void kernel_launch(void* const* d_in, const int* in_sizes, int n_in,
                              void* d_out, int out_size, void* d_ws, size_t ws_size,
                              hipStream_t stream) {
  (void)in_sizes; (void)n_in; (void)out_size; (void)ws_size;
  const float* sent    = (const float*)d_in[0];
  const int*   pitches = (const int*)d_in[1];
  const int*   kss     = (const int*)d_in[2];
  const float* mWih_f  = (const float*)d_in[5];
  const float* mWhh_f  = (const float*)d_in[6];
  const float* mbih_f  = (const float*)d_in[7];
  const float* mbhh_f  = (const float*)d_in[8];
  const float* mWih_b  = (const float*)d_in[9];
  const float* mWhh_b  = (const float*)d_in[10];
  const float* mbih_b  = (const float*)d_in[11];
  const float* mbhh_b  = (const float*)d_in[12];
  const float* hWih_f  = (const float*)d_in[13];
  const float* hWhh_f  = (const float*)d_in[14];
  const float* hbih_f  = (const float*)d_in[15];
  const float* hbhh_f  = (const float*)d_in[16];
  const float* hWih_b  = (const float*)d_in[17];
  const float* hWhh_b  = (const float*)d_in[18];
  const float* hbih_b  = (const float*)d_in[19];
  const float* hbhh_b  = (const float*)d_in[20];
  const float* Wq      = (const float*)d_in[21];
  const float* bq      = (const float*)d_in[22];
  const float* Wv      = (const float*)d_in[23];
  const float* bv      = (const float*)d_in[24];
  const float* Wp      = (const float*)d_in[25];
  const float* bp      = (const float*)d_in[26];
  const float* Wk      = (const float*)d_in[27];
  const float* bk      = (const float*)d_in[28];
  float* ws  = (float*)d_ws;
  float* out = (float*)d_out;
  unsigned short* rnn16  = (unsigned short*)(ws + OFF_RNN16);
  unsigned short* hv16   = (unsigned short*)(ws + OFF_HV16);
  unsigned short* ptpack = (unsigned short*)(ws + OFF_PTPACK);

  k_repack_main<<<360, 64, 0, stream>>>(mWih_f, mWhh_f, mWih_b, mWhh_b,
                                        (unsigned short*)(ws + OFF_BPACKM));
  k_repack<<<672, 64, 0, stream>>>(hWih_f, hWhh_f, hWih_b, hWhh_b,
                                   (unsigned short*)(ws + OFF_BPACK));
  k_pt<<<256, 256, 0, stream>>>(Wq, Wv, ws + OFF_PT);
  k_ptpack<<<128, 64, 0, stream>>>(ws + OFF_PT, ptpack);
  k_small<<<1, 256, 0, stream>>>(Wq, bq, Wv, bv, ws + OFF_U, ws + OFF_W, ws + OFF_C0, ws + OFF_ACC);

  k_main_gru_mfma<<<128, 640, 0, stream>>>(sent, (const unsigned short*)(ws + OFF_BPACKM),
                                           mbih_f, mbhh_f, mbih_b, mbhh_b, rnn16);
  k_hier_mfma<<<512, 512, 0, stream>>>(rnn16, (const unsigned short*)(ws + OFF_BPACK),
                                       hbih_f, hbhh_f, hbih_b, hbhh_b, hv16);
  k_attn2<<<1024, 256, 0, stream>>>(hv16, ptpack, ws + OFF_U, ws + OFF_W,
                                    ws + OFF_C0, ws + OFF_CTX);
  k_ctxlog2<<<256, 256, 0, stream>>>(ws + OFF_CTX, Wp, bp, Wk, bk,
                                     ws + OFF_CLOG, ws + OFF_KSLOGP);
  k_loss<<<256, 256, 0, stream>>>(rnn16, Wp, ws + OFF_CLOG, ws + OFF_KSLOGP,
                                  pitches, kss, ws + OFF_ACC);
  k_final<<<1, 1, 0, stream>>>(ws + OFF_ACC, out);
}

// Round 8
// 1047.067 us; speedup vs baseline: 1.6378x; 1.1504x over previous
//
#include <hip/hip_runtime.h>
#include <cstddef>

// ---- problem constants ----
constexpr int kT   = 1024;
constexpr int kB   = 64;
constexpr int kDIN = 17;
constexpr int kHM  = 150;   // main hidden (per dir)
constexpr int kHH  = 128;   // hier hidden (per dir)
constexpr int kM   = 16;    // measure length
constexpr int kD2  = 300;   // 2*kHM
constexpr int kNP  = 35;
constexpr int kNK  = 15;

// ---- workspace layout (float offsets, 16-float aligned) ----
constexpr size_t OFF_RNN16  = 0;          // ushort [1024][64][320] = 10,485,760 f
constexpr size_t OFF_HV16   = 10485760;   // ushort [4096][16][256] = 8,388,608 f
constexpr size_t OFF_CTX    = 18874368;   // f32 [4096][256] = 1,048,576
constexpr size_t OFF_PT     = 19922944;   // f32 [256][256] = 65,536
constexpr size_t OFF_PTPACK = 19988480;   // ushort [16][8][64][8] = 32,768 f
constexpr size_t OFF_U      = 20021248;   // [256]
constexpr size_t OFF_W      = 20021504;   // [256]
constexpr size_t OFF_C0     = 20021760;   // [16]
constexpr size_t OFF_ACC    = 20021776;   // [16]
constexpr size_t OFF_KSLOGP = 20021792;   // [4096][15]
constexpr size_t OFF_CLOG   = 20083232;   // [4096][35]
constexpr size_t OFF_BPACKM = 20226592;   // ushort [2][30][6][64][8] = 92,160 f
constexpr size_t OFF_BPACK  = 20318752;   // ushort [2][24][14][64][8] = 172,032 f
constexpr size_t OFF_BPACKL = 20490784;   // ushort [3][10][64][8] = 7,680 f
// total ~20.5M floats = 82 MB

typedef __bf16 bf16x8 __attribute__((ext_vector_type(8)));
typedef float f32x4 __attribute__((ext_vector_type(4)));

__device__ __forceinline__ unsigned short f2bf(float f) {
  unsigned u = __float_as_uint(f);
  u += 0x7FFFu + ((u >> 16) & 1u);
  return (unsigned short)(u >> 16);
}
__device__ __forceinline__ float bf2f(unsigned short v) {
  return __uint_as_float(((unsigned)v) << 16);
}
__device__ __forceinline__ float sigm(float x) {
  return __builtin_amdgcn_rcpf(1.f + __expf(-x));
}
__device__ __forceinline__ float tanh_fast(float x) {
  return 1.f - 2.f * __builtin_amdgcn_rcpf(__expf(2.f * x) + 1.f);
}

// PT[e][c] = sum_a Wq[a][c]*Wv[a][e]
__global__ void k_pt(const float* __restrict__ Wq, const float* __restrict__ Wv,
                     float* __restrict__ PT) {
  const int e = blockIdx.x, c = threadIdx.x;
  float acc = 0.f;
  for (int a = 0; a < 256; a++) acc += Wq[a * 256 + c] * Wv[a * 256 + e];
  PT[e * 256 + c] = acc;
}

// merged: bid<128 -> ptpack (64 thr used); bid==128 -> small (u,w,c0,acc)
__global__ void k_ptsmall(const float* __restrict__ PT,
                          const float* __restrict__ Wq, const float* __restrict__ bq,
                          const float* __restrict__ Wv, const float* __restrict__ bv,
                          unsigned short* __restrict__ pp,
                          float* __restrict__ u, float* __restrict__ w,
                          float* __restrict__ c0, float* __restrict__ acc) {
  const int bid = blockIdx.x;
  if (bid < 128) {
    if (threadIdx.x >= 64) return;
    const int kt = bid & 7, nt = bid >> 3;
    const int lane = threadIdx.x;
    const int c = nt * 16 + (lane & 15);
    const int e0 = kt * 32 + (lane >> 4) * 8;
#pragma unroll
    for (int j = 0; j < 8; j++)
      pp[((size_t)bid * 64 + lane) * 8 + j] = f2bf(PT[(e0 + j) * 256 + c]);
  } else {
    const int a = threadIdx.x; // 256
    float us = 0.f, ws = 0.f;
    for (int j = 0; j < 256; j++) {
      us += Wq[j * 256 + a] * bv[j];
      ws += bq[j] * Wv[j * 256 + a];
    }
    u[a] = us; w[a] = ws;
    if (a == 0) {
      float c = 0.f;
      for (int j = 0; j < 256; j++) c += bq[j] * bv[j];
      c0[0] = c;
      acc[0] = acc[1] = acc[2] = acc[3] = 0.f;
    }
  }
}

// ---------------------------------------------------------------------------
// Merged repack: bid<360 -> main GRU B-frags; <1032 -> hier B-frags;
// else (30) -> loss W1 B-frags (K = rnn16 320-col layout).
__global__ void k_repack_all(
    const float* __restrict__ mWih_f, const float* __restrict__ mWhh_f,
    const float* __restrict__ mWih_b, const float* __restrict__ mWhh_b,
    const float* __restrict__ hWih_f, const float* __restrict__ hWhh_f,
    const float* __restrict__ hWih_b, const float* __restrict__ hWhh_b,
    const float* __restrict__ Wp,
    unsigned short* __restrict__ bpackM, unsigned short* __restrict__ bpack,
    unsigned short* __restrict__ bpackL) {
  const int lane = threadIdx.x;
  int bid = blockIdx.x;
  if (bid < 360) {
    const int kt = bid % 6;
    const int gt = (bid / 6) % 30;
    const int d  = bid / 180;
    const float* Wih = d ? mWih_b : mWih_f;  // [450][17]
    const float* Whh = d ? mWhh_b : mWhh_f;  // [450][150]
    const int slot = gt * 16 + (lane & 15);
    const int type = slot / 160, j = slot - type * 160;
    const int row = type * 150 + j;
    const bool valid = (j < 150);
    const int kbase = (lane >> 4) * 8;
    unsigned short* dst = bpackM + ((((size_t)d * 30 + gt) * 6 + kt) * 64 + lane) * 8;
#pragma unroll
    for (int jj = 0; jj < 8; jj++) {
      float f = 0.f;
      if (valid) {
        if (kt < 5) {
          const int k = kt * 32 + kbase + jj;
          if (k < 150) f = Whh[row * 150 + k];
        } else {
          const int k = kbase + jj;
          if (k < 17) f = Wih[row * 17 + k];
        }
      }
      dst[jj] = f2bf(f);
    }
  } else if (bid < 1032) {
    bid -= 360;
    const int kt = bid % 14;
    const int nt = (bid / 14) % 24;
    const int d  = bid / (14 * 24);
    const float* Wih = d ? hWih_b : hWih_f;   // [384][300]
    const float* Whh = d ? hWhh_b : hWhh_f;   // [384][128]
    const int n = nt * 16 + (lane & 15);
    const int kbase = kt * 32 + (lane >> 4) * 8;
    unsigned short* dst = bpack + ((((size_t)d * 24 + nt) * 14 + kt) * 64 + lane) * 8;
#pragma unroll
    for (int j = 0; j < 8; j++) {
      const int k = kbase + j;
      float f = 0.f;
      if (kt < 10) {
        if (k < 150) f = Wih[n * 300 + k];
        else if (k >= 160 && k < 310) f = Wih[n * 300 + (k - 10)];
      } else {
        f = Whh[n * 128 + (k - 320)];
      }
      dst[j] = f2bf(f);
    }
  } else {
    bid -= 1032;                       // 0..29 = nt*10+kt
    const int kt = bid % 10, nt = bid / 10;
    const int n = nt * 16 + (lane & 15);   // logit index, valid < 35
    const int kbase = kt * 32 + (lane >> 4) * 8;
    unsigned short* dst = bpackL + (((size_t)bid) * 64 + lane) * 8;
#pragma unroll
    for (int j = 0; j < 8; j++) {
      const int k = kbase + j;
      float f = 0.f;
      if (n < kNP) {
        if (k < 150) f = Wp[n * 556 + k];
        else if (k >= 160 && k < 310) f = Wp[n * 556 + (k - 10)];
      }
      dst[j] = f2bf(f);
    }
  }
}

// ---------------------------------------------------------------------------
// Main bi-GRU, M=1 MFMA, 10 waves (validated r5/r6 — structural floor).
__global__ __launch_bounds__(640, 2) void k_main_gru_mfma(
    const float* __restrict__ x,               // [1024][64][17]
    const unsigned short* __restrict__ bpackM, // [2][30][6][64][8]
    const float* __restrict__ bihf, const float* __restrict__ bhhf,
    const float* __restrict__ bihb, const float* __restrict__ bhhb,
    unsigned short* __restrict__ rnn16)        // [1024][64][320]
{
  const int d = blockIdx.x & 1, b = blockIdx.x >> 1;
  const int tid = threadIdx.x, w = tid >> 6, lane = tid & 63;
  const int col = lane & 15, q8 = (lane >> 4) * 8;
  __shared__ __align__(16) unsigned short hx[2][160];
  __shared__ __align__(16) unsigned short hist[2][16][160];
  __shared__ __align__(16) unsigned short xall[kT][32];
  for (int i = tid; i < 2 * 160; i += 640) ((unsigned short*)hx)[i] = 0;
  for (int i = tid; i < 2 * 16 * 160; i += 640) ((unsigned short*)hist)[i] = 0;
  for (int i = tid; i < kT * 32; i += 640) {
    const int t = i >> 5, c = i & 31;
    xall[t][c] = (c < kDIN) ? f2bf(x[((size_t)t * kB + b) * kDIN + c]) : (unsigned short)0;
  }
  const float* bih = d ? bihb : bihf;
  const float* bhh = d ? bhhb : bhhf;
  const int j = w * 16 + col;
  const bool actv = (lane < 16) && (j < kHM);
  float br = 0.f, bz = 0.f, bnx = 0.f, bnh = 0.f;
  if (actv) {
    br  = bih[j] + bhh[j];
    bz  = bih[150 + j] + bhh[150 + j];
    bnx = bih[300 + j];
    bnh = bhh[300 + j];
  }
  bf16x8 bw[3][6];
  const unsigned short* bp = bpackM + (size_t)d * 30 * 6 * 64 * 8;
  const int gts[3] = { w, 10 + w, 20 + w };
#pragma unroll
  for (int gi = 0; gi < 3; gi++)
#pragma unroll
    for (int kt = 0; kt < 6; kt++)
      bw[gi][kt] = *(const bf16x8*)&bp[(((size_t)gts[gi] * 6 + kt) * 64 + lane) * 8];
  float h_old = 0.f;
  __syncthreads();

  for (int t = 0; t < kT; t++) {
    const int tx = d ? (kT - 1 - t) : t;
    const int buf = t & 1;
    bf16x8 afr[6];
#pragma unroll
    for (int kt = 0; kt < 5; kt++) afr[kt] = *(const bf16x8*)&hx[buf][kt * 32 + q8];
    afr[5] = *(const bf16x8*)&xall[tx][q8];
    f32x4 aR0 = (f32x4)(0.f), aR1 = (f32x4)(0.f);
    f32x4 aZ0 = (f32x4)(0.f), aZ1 = (f32x4)(0.f);
    f32x4 aN0 = (f32x4)(0.f), aN1 = (f32x4)(0.f);
    f32x4 aX  = (f32x4)(0.f);
#pragma unroll
    for (int kt = 0; kt < 6; kt++) {
      const bf16x8 af = afr[kt];
      if ((kt & 1) == 0) {
        aR0 = __builtin_amdgcn_mfma_f32_16x16x32_bf16(af, bw[0][kt], aR0, 0, 0, 0);
        aZ0 = __builtin_amdgcn_mfma_f32_16x16x32_bf16(af, bw[1][kt], aZ0, 0, 0, 0);
        aN0 = __builtin_amdgcn_mfma_f32_16x16x32_bf16(af, bw[2][kt], aN0, 0, 0, 0);
      } else if (kt < 5) {
        aR1 = __builtin_amdgcn_mfma_f32_16x16x32_bf16(af, bw[0][kt], aR1, 0, 0, 0);
        aZ1 = __builtin_amdgcn_mfma_f32_16x16x32_bf16(af, bw[1][kt], aZ1, 0, 0, 0);
        aN1 = __builtin_amdgcn_mfma_f32_16x16x32_bf16(af, bw[2][kt], aN1, 0, 0, 0);
      } else {
        aR1 = __builtin_amdgcn_mfma_f32_16x16x32_bf16(af, bw[0][5], aR1, 0, 0, 0);
        aZ1 = __builtin_amdgcn_mfma_f32_16x16x32_bf16(af, bw[1][5], aZ1, 0, 0, 0);
        aX  = __builtin_amdgcn_mfma_f32_16x16x32_bf16(af, bw[2][5], aX, 0, 0, 0);
      }
    }
    if (actv) {
      const float r = sigm(aR0[0] + aR1[0] + br);
      const float z = sigm(aZ0[0] + aZ1[0] + bz);
      const float n = tanh_fast(aX[0] + bnx + r * (aN0[0] + aN1[0] + bnh));
      h_old = (1.f - z) * n + z * h_old;
      const unsigned short us = f2bf(h_old);
      hx[buf ^ 1][j] = us;
      hist[(t >> 4) & 1][t & 15][j] = us;
    }
    __syncthreads();
    if ((t & 15) == 15) {
      const int hb = (t >> 4) & 1;
      const int toff = tid / 40, ch = tid - toff * 40;
      const int tg = t - 15 + toff;
      const int txg = d ? (kT - 1 - tg) : tg;
      *(ushort4*)&rnn16[((size_t)txg * kB + b) * 320 + d * 160 + ch * 4] =
          *(const ushort4*)&hist[hb][toff][ch * 4];
    }
  }
}

// ---------------------------------------------------------------------------
// Hier bi-GRU (validated r7): 8 waves, register-resident B (42 frags).
__global__ __launch_bounds__(512, 1) void k_hier_mfma(
    const unsigned short* __restrict__ rnn16,  // [1024][64][320]
    const unsigned short* __restrict__ bpack,  // [2][24][14][64][8]
    const float* __restrict__ bihf, const float* __restrict__ bhhf,
    const float* __restrict__ bihb, const float* __restrict__ bhhb,
    unsigned short* __restrict__ hv16)         // [4096][16][256]
{
  const int d = blockIdx.x & 1;
  const int bn0 = (blockIdx.x >> 1) * 16;
  const int tid = threadIdx.x;
  const int w = tid >> 6;          // 0..7
  const int lane = tid & 63;
  const int q = lane >> 4, col = lane & 15, q8 = q * 8;

  __shared__ __align__(16) unsigned short x_s[2][16][328];
  __shared__ __align__(16) unsigned short h_s[16][136];

  for (int i = tid; i < 16 * 136; i += 512) ((unsigned short*)h_s)[i] = 0;
  const float* bih = d ? bihb : bihf;
  const float* bhh = d ? bhhb : bhhf;
  const int j = w * 16 + col;      // 0..127
  const float biR  = bih[j] + bhh[j];
  const float biZ  = bih[128 + j] + bhh[128 + j];
  const float biNX = bih[256 + j];
  const float biNH = bhh[256 + j];
  float h32r[4] = {0.f, 0.f, 0.f, 0.f};

  bf16x8 bw[3][14];
  const unsigned short* bpd = bpack + (size_t)d * 24 * 14 * 64 * 8;
  const int nts[3] = { w, 8 + w, 16 + w };
#pragma unroll
  for (int gi = 0; gi < 3; gi++)
#pragma unroll
    for (int kt = 0; kt < 14; kt++)
      bw[gi][kt] = *(const bf16x8*)&bpd[(((size_t)nts[gi] * 14 + kt) * 64 + lane) * 8];

  {
    const int mx0 = d ? 15 : 0;
    for (int i = tid; i < 640; i += 512) {
      const int r = i / 40, c = i - r * 40;
      const int bn = bn0 + r, bb = bn >> 6, nn = bn & 63;
      *(uint4*)&x_s[0][r][c * 8] =
          *(const uint4*)&rnn16[((size_t)(nn * 16 + mx0) * 64 + bb) * 320 + c * 8];
    }
  }
  __syncthreads();

  for (int m = 0; m < kM; m++) {
    const int mx = d ? (15 - m) : m;
    const int buf = m & 1;
    f32x4 aR = (f32x4)(0.f), aZ = (f32x4)(0.f), aNX = (f32x4)(0.f), aNH = (f32x4)(0.f);
#pragma unroll
    for (int kt = 0; kt < 14; kt++) {
      const bf16x8 af = (kt < 10) ? *(const bf16x8*)&x_s[buf][col][kt * 32 + q8]
                                  : *(const bf16x8*)&h_s[col][(kt - 10) * 32 + q8];
      aR = __builtin_amdgcn_mfma_f32_16x16x32_bf16(af, bw[0][kt], aR, 0, 0, 0);
      aZ = __builtin_amdgcn_mfma_f32_16x16x32_bf16(af, bw[1][kt], aZ, 0, 0, 0);
      if (kt < 10) aNX = __builtin_amdgcn_mfma_f32_16x16x32_bf16(af, bw[2][kt], aNX, 0, 0, 0);
      else         aNH = __builtin_amdgcn_mfma_f32_16x16x32_bf16(af, bw[2][kt], aNH, 0, 0, 0);
    }
    __syncthreads();
#pragma unroll
    for (int i = 0; i < 4; i++) {
      const int row = q * 4 + i;
      const float rr = sigm(aR[i] + biR);
      const float zz = sigm(aZ[i] + biZ);
      const float nn2 = tanh_fast(aNX[i] + biNX + rr * (aNH[i] + biNH));
      const float hnew = (1.f - zz) * nn2 + zz * h32r[i];
      h32r[i] = hnew;
      const unsigned short us = f2bf(hnew);
      h_s[row][j] = us;
      hv16[((size_t)(bn0 + row) * kM + mx) * 256 + d * kHH + j] = us;
    }
    if (m + 1 < kM) {
      const int mxn = d ? (15 - (m + 1)) : (m + 1);
      for (int i = tid; i < 640; i += 512) {
        const int r = i / 40, c = i - r * 40;
        const int bn = bn0 + r, bb = bn >> 6, nn = bn & 63;
        *(uint4*)&x_s[buf ^ 1][r][c * 8] =
            *(const uint4*)&rnn16[((size_t)(nn * 16 + mxn) * 64 + bb) * 320 + c * 8];
      }
    }
    __syncthreads();
  }
}

// ---------------------------------------------------------------------------
// Attention (validated r7): 4 n per block, ptpack register-resident.
__global__ __launch_bounds__(256) void k_attn2(
    const unsigned short* __restrict__ hv16, const unsigned short* __restrict__ ptpack,
    const float* __restrict__ u, const float* __restrict__ w,
    const float* __restrict__ c0p, float* __restrict__ ctx) {
  const int tid = threadIdx.x;
  const int wv = tid >> 6, lane = tid & 63, col = lane & 15, q = lane >> 4, q8 = q * 8;
  __shared__ __align__(16) unsigned short hv16s[16][264];
  __shared__ __align__(16) unsigned short Ts16[16][264];
  __shared__ float pu[16][17], pw[16][17];
  __shared__ float uh[16], wh[16], SM[16];
  __shared__ float As[16][17];
  const float c0 = c0p[0];
  bf16x8 bpt[4][8];
#pragma unroll
  for (int i2 = 0; i2 < 4; i2++)
#pragma unroll
    for (int kt = 0; kt < 8; kt++)
      bpt[i2][kt] = *(const bf16x8*)&ptpack[((((size_t)(wv * 4 + i2)) * 8 + kt) * 64 + lane) * 8];

  for (int ni = 0; ni < 4; ni++) {
    const int n = blockIdx.x * 4 + ni;
    {
      const unsigned short* src = hv16 + (size_t)n * 4096;
      const int row = tid >> 4, ci = (tid & 15) * 16;
#pragma unroll
      for (int k = 0; k < 16; k += 4)
        *(ushort4*)&hv16s[row][ci + k] = *(const ushort4*)&src[row * 256 + ci + k];
    }
    __syncthreads();
    {
      f32x4 acc[4];
#pragma unroll
      for (int i2 = 0; i2 < 4; i2++) acc[i2] = (f32x4)(0.f);
#pragma unroll
      for (int kt = 0; kt < 8; kt++) {
        const bf16x8 af = *(const bf16x8*)&hv16s[col][kt * 32 + q8];
#pragma unroll
        for (int i2 = 0; i2 < 4; i2++)
          acc[i2] = __builtin_amdgcn_mfma_f32_16x16x32_bf16(af, bpt[i2][kt], acc[i2], 0, 0, 0);
      }
#pragma unroll
      for (int i2 = 0; i2 < 4; i2++) {
        const int nt = wv * 4 + i2;
#pragma unroll
        for (int i = 0; i < 4; i++) Ts16[q * 4 + i][nt * 16 + col] = f2bf(acc[i2][i]);
      }
    }
    {
      const int l = tid >> 4, s = tid & 15;
      float su = 0.f, sw = 0.f;
#pragma unroll
      for (int a0 = 0; a0 < 16; a0++) {
        const int a = s * 16 + a0;
        const float hvv = bf2f(hv16s[l][a]);
        su += hvv * u[a];
        sw += hvv * w[a];
      }
      pu[l][s] = su; pw[l][s] = sw;
    }
    __syncthreads();
    if (tid < 16) { float s2 = 0.f; for (int s = 0; s < 16; s++) s2 += pu[tid][s]; uh[tid] = s2; }
    else if (tid < 32) { float s2 = 0.f; for (int s = 0; s < 16; s++) s2 += pw[tid - 16][s]; wh[tid - 16] = s2; }
    __syncthreads();
    if (tid < 64) {
      f32x4 sa = (f32x4)(0.f);
#pragma unroll
      for (int kt = 0; kt < 8; kt++) {
        const bf16x8 af  = *(const bf16x8*)&hv16s[col][kt * 32 + q8];
        const bf16x8 bts = *(const bf16x8*)&Ts16[col][kt * 32 + q8];
        sa = __builtin_amdgcn_mfma_f32_16x16x32_bf16(af, bts, sa, 0, 0, 0);
      }
#pragma unroll
      for (int i = 0; i < 4; i++) {
        const int l = q * 4 + i;
        float sc = sa[i] + c0 + uh[l] + wh[col];
        float mxv = sc;
#pragma unroll
        for (int o = 8; o >= 1; o >>= 1) mxv = fmaxf(mxv, __shfl_xor(mxv, o, 16));
        const float e = __expf(sc - mxv);
        float se = e;
#pragma unroll
        for (int o = 8; o >= 1; o >>= 1) se += __shfl_xor(se, o, 16);
        As[l][col] = e / se;
      }
    }
    __syncthreads();
    if (tid < 16) {
      float s = 0.f;
      for (int l2 = 0; l2 < 16; l2++) s += As[l2][tid];
      SM[tid] = s;
    }
    __syncthreads();
    float cv = 0.f;
#pragma unroll
    for (int m2 = 0; m2 < 16; m2++) cv += SM[m2] * bf2f(hv16s[m2][tid]);
    ctx[(size_t)n * 256 + tid] = cv;
    __syncthreads();
  }
}

// ---------------------------------------------------------------------------
// ctx-dependent logits (validated r5).
__global__ __launch_bounds__(256) void k_ctxlog2(
    const float* __restrict__ ctx, const float* __restrict__ Wp, const float* __restrict__ bp,
    const float* __restrict__ Wk, const float* __restrict__ bk,
    float* __restrict__ clog, float* __restrict__ kslogp) {
  const int tid = threadIdx.x;
  __shared__ __align__(16) float W2[50][260];
  __shared__ __align__(16) float cs[256];
  __shared__ float arr[64];
  __shared__ float bps[35], bks[15];
  for (int i = tid; i < 35 * 256; i += 256) { const int r = i >> 8, c = i & 255; W2[r][c] = Wp[r * 556 + 300 + c]; }
  for (int i = tid; i < 15 * 256; i += 256) { const int r = i >> 8, c = i & 255; W2[35 + r][c] = Wk[r * 256 + c]; }
  if (tid < 35) bps[tid] = bp[tid];
  else if (tid < 50) bks[tid - 35] = bk[tid - 35];
  __syncthreads();
  const int o = tid >> 2, s = tid & 3;
  for (int it = 0; it < 16; it++) {
    const int bn = blockIdx.x * 16 + it;
    cs[tid] = ctx[(size_t)bn * 256 + tid];
    __syncthreads();
    float v = 0.f;
    if (o < 50) {
      for (int k0 = 0; k0 < 64; k0 += 4) {
        const int k = s * 64 + k0;
        const float4 wq = *(const float4*)&W2[o][k];
        const float4 cq = *(const float4*)&cs[k];
        v += wq.x * cq.x + wq.y * cq.y + wq.z * cq.z + wq.w * cq.w;
      }
    }
    v += __shfl_xor(v, 1);
    v += __shfl_xor(v, 2);
    if (o < 50 && s == 0) arr[o] = v;
    __syncthreads();
    if (tid < 35) clog[bn * kNP + tid] = arr[tid] + bps[tid];
    if (tid >= 64 && tid < 80) {
      const int t2 = tid - 64;
      float kk = (t2 < 15) ? arr[35 + t2] + bks[t2] : -1e30f;
      float mxv = kk;
#pragma unroll
      for (int off = 8; off >= 1; off >>= 1) mxv = fmaxf(mxv, __shfl_xor(mxv, off, 16));
      const float e = (t2 < 15) ? __expf(kk - mxv) : 0.f;
      float se = e;
#pragma unroll
      for (int off = 8; off >= 1; off >>= 1) se += __shfl_xor(se, off, 16);
      if (t2 < 15) kslogp[bn * kNK + t2] = kk - mxv - __logf(se);
    }
    __syncthreads();
  }
}

// ---------------------------------------------------------------------------
// Loss via MFMA: logits = rnn16 @ W1^T (B-frags register-resident), softmax
// per 16-lane group, no LDS, no barriers. 512 blocks x 4 waves; wave handles
// 32 rows (2 M-tiles of 16).
__global__ __launch_bounds__(256, 2) void k_loss_mfma(
    const unsigned short* __restrict__ rnn16,  // [65536][320]
    const unsigned short* __restrict__ bpackL, // [3][10][64][8]
    const float* __restrict__ clog,            // [4096][35]
    const float* __restrict__ ks_logp,         // [4096][15]
    const int* __restrict__ pitches, const int* __restrict__ kss,
    float* __restrict__ acc) {
  const int tid = threadIdx.x, w = tid >> 6, lane = tid & 63;
  const int col = lane & 15, q = lane >> 4, q8 = q * 8;
  bf16x8 bl[3][10];
#pragma unroll
  for (int nt = 0; nt < 3; nt++)
#pragma unroll
    for (int kt = 0; kt < 10; kt++)
      bl[nt][kt] = *(const bf16x8*)&bpackL[(((size_t)nt * 10 + kt) * 64 + lane) * 8];

  float sp = 0.f, cp = 0.f, sk = 0.f, ck = 0.f;
#pragma unroll
  for (int mt = 0; mt < 2; mt++) {
    const int rowbase = blockIdx.x * 128 + w * 32 + mt * 16;
    f32x4 a0 = (f32x4)(0.f), a1 = (f32x4)(0.f), a2 = (f32x4)(0.f);
#pragma unroll
    for (int kt = 0; kt < 10; kt++) {
      const bf16x8 af = *(const bf16x8*)&rnn16[(size_t)(rowbase + col) * 320 + kt * 32 + q8];
      a0 = __builtin_amdgcn_mfma_f32_16x16x32_bf16(af, bl[0][kt], a0, 0, 0, 0);
      a1 = __builtin_amdgcn_mfma_f32_16x16x32_bf16(af, bl[1][kt], a1, 0, 0, 0);
      a2 = __builtin_amdgcn_mfma_f32_16x16x32_bf16(af, bl[2][kt], a2, 0, 0, 0);
    }
#pragma unroll
    for (int i = 0; i < 4; i++) {
      const int row = rowbase + q * 4 + i;
      const int t = row >> 6, b = row & 63;
      const int bn = b * 64 + (t >> 4);
      const float lg0 = a0[i] + clog[bn * kNP + col];
      const float lg1 = a1[i] + clog[bn * kNP + 16 + col];
      const float lg2 = (col < 3) ? (a2[i] + clog[bn * kNP + 32 + col]) : -1e30f;
      float mx = fmaxf(fmaxf(lg0, lg1), lg2);
#pragma unroll
      for (int o = 8; o >= 1; o >>= 1) mx = fmaxf(mx, __shfl_xor(mx, o, 16));
      float se = __expf(lg0 - mx) + __expf(lg1 - mx) + __expf(lg2 - mx);
#pragma unroll
      for (int o = 8; o >= 1; o >>= 1) se += __shfl_xor(se, o, 16);
      const int tp = pitches[row];
      const float cand = (tp < 16) ? a0[i] : (tp < 32) ? a1[i] : a2[i];
      const float tva = __shfl(cand, (lane & 48) | (tp & 15), 64);
      if (col == 0 && tp != 34) {
        sp += (mx + __logf(se)) - (tva + clog[bn * kNP + tp]);
        cp += 1.f;
      }
      if (col == 1) {
        const int tk = kss[row];
        if (tk != 14) { sk -= ks_logp[bn * kNK + tk]; ck += 1.f; }
      }
    }
  }
#pragma unroll
  for (int o = 32; o >= 1; o >>= 1) {
    sp += __shfl_xor(sp, o, 64);
    cp += __shfl_xor(cp, o, 64);
    sk += __shfl_xor(sk, o, 64);
    ck += __shfl_xor(ck, o, 64);
  }
  if (lane == 0) {
    atomicAdd(&acc[0], sp); atomicAdd(&acc[1], cp);
    atomicAdd(&acc[2], sk); atomicAdd(&acc[3], ck);
  }
}

__global__ void k_final(const float* __restrict__ acc, float* __restrict__ out) {
  out[0] = acc[0] / fmaxf(acc[1], 1.f) + acc[2] / fmaxf(acc[3], 1.f);
}

// ---------------------------------------------------------------------------
extern "C" void kernel_launch(void* const* d_in, const int* in_sizes, int n_in,
                              void* d_out, int out_size, void* d_ws, size_t ws_size,
                              hipStream_t stream) {
  (void)in_sizes; (void)n_in; (void)out_size; (void)ws_size;
  const float* sent    = (const float*)d_in[0];
  const int*   pitches = (const int*)d_in[1];
  const int*   kss     = (const int*)d_in[2];
  const float* mWih_f  = (const float*)d_in[5];
  const float* mWhh_f  = (const float*)d_in[6];
  const float* mbih_f  = (const float*)d_in[7];
  const float* mbhh_f  = (const float*)d_in[8];
  const float* mWih_b  = (const float*)d_in[9];
  const float* mWhh_b  = (const float*)d_in[10];
  const float* mbih_b  = (const float*)d_in[11];
  const float* mbhh_b  = (const float*)d_in[12];
  const float* hWih_f  = (const float*)d_in[13];
  const float* hWhh_f  = (const float*)d_in[14];
  const float* hbih_f  = (const float*)d_in[15];
  const float* hbhh_f  = (const float*)d_in[16];
  const float* hWih_b  = (const float*)d_in[17];
  const float* hWhh_b  = (const float*)d_in[18];
  const float* hbih_b  = (const float*)d_in[19];
  const float* hbhh_b  = (const float*)d_in[20];
  const float* Wq      = (const float*)d_in[21];
  const float* bq      = (const float*)d_in[22];
  const float* Wv      = (const float*)d_in[23];
  const float* bv      = (const float*)d_in[24];
  const float* Wp      = (const float*)d_in[25];
  const float* bp      = (const float*)d_in[26];
  const float* Wk      = (const float*)d_in[27];
  const float* bk      = (const float*)d_in[28];
  float* ws  = (float*)d_ws;
  float* out = (float*)d_out;
  unsigned short* rnn16  = (unsigned short*)(ws + OFF_RNN16);
  unsigned short* hv16   = (unsigned short*)(ws + OFF_HV16);
  unsigned short* ptpack = (unsigned short*)(ws + OFF_PTPACK);
  unsigned short* bpackL = (unsigned short*)(ws + OFF_BPACKL);

  k_repack_all<<<1062, 64, 0, stream>>>(mWih_f, mWhh_f, mWih_b, mWhh_b,
                                        hWih_f, hWhh_f, hWih_b, hWhh_b, Wp,
                                        (unsigned short*)(ws + OFF_BPACKM),
                                        (unsigned short*)(ws + OFF_BPACK), bpackL);
  k_pt<<<256, 256, 0, stream>>>(Wq, Wv, ws + OFF_PT);
  k_ptsmall<<<129, 256, 0, stream>>>(ws + OFF_PT, Wq, bq, Wv, bv, ptpack,
                                     ws + OFF_U, ws + OFF_W, ws + OFF_C0, ws + OFF_ACC);

  k_main_gru_mfma<<<128, 640, 0, stream>>>(sent, (const unsigned short*)(ws + OFF_BPACKM),
                                           mbih_f, mbhh_f, mbih_b, mbhh_b, rnn16);
  k_hier_mfma<<<512, 512, 0, stream>>>(rnn16, (const unsigned short*)(ws + OFF_BPACK),
                                       hbih_f, hbhh_f, hbih_b, hbhh_b, hv16);
  k_attn2<<<1024, 256, 0, stream>>>(hv16, ptpack, ws + OFF_U, ws + OFF_W,
                                    ws + OFF_C0, ws + OFF_CTX);
  k_ctxlog2<<<256, 256, 0, stream>>>(ws + OFF_CTX, Wp, bp, Wk, bk,
                                     ws + OFF_CLOG, ws + OFF_KSLOGP);
  k_loss_mfma<<<512, 256, 0, stream>>>(rnn16, bpackL, ws + OFF_CLOG, ws + OFF_KSLOGP,
                                       pitches, kss, ws + OFF_ACC);
  k_final<<<1, 1, 0, stream>>>(ws + OFF_ACC, out);
}

// Round 9
// 1041.724 us; speedup vs baseline: 1.6462x; 1.0051x over previous
//
#include <hip/hip_runtime.h>
#include <cstddef>

// ---- problem constants ----
constexpr int kT   = 1024;
constexpr int kB   = 64;
constexpr int kDIN = 17;
constexpr int kHM  = 150;   // main hidden (per dir)
constexpr int kHH  = 128;   // hier hidden (per dir)
constexpr int kM   = 16;    // measure length
constexpr int kD2  = 300;   // 2*kHM
constexpr int kNP  = 35;
constexpr int kNK  = 15;

// ---- workspace layout (float offsets, 16-float aligned) ----
constexpr size_t OFF_RNN16  = 0;          // ushort [1024][64][320] = 10,485,760 f
constexpr size_t OFF_HV16   = 10485760;   // ushort [4096][16][256] = 8,388,608 f
constexpr size_t OFF_PTPACK = 19988480;   // ushort [16][8][64][8] = 32,768 f
constexpr size_t OFF_U      = 20021248;   // [256]
constexpr size_t OFF_W      = 20021504;   // [256]
constexpr size_t OFF_C0     = 20021760;   // [16]
constexpr size_t OFF_ACC    = 20021776;   // [16]
constexpr size_t OFF_KSLOGP = 20021792;   // [4096][15]
constexpr size_t OFF_CLOG   = 20083232;   // [4096][35]
constexpr size_t OFF_BPACK  = 20318752;   // ushort [2][24][14][64][8] = 172,032 f
constexpr size_t OFF_BPACKL = 20490784;   // ushort [3][10][64][8] = 7,680 f

typedef __bf16 bf16x8 __attribute__((ext_vector_type(8)));
typedef float f32x4 __attribute__((ext_vector_type(4)));

__device__ __forceinline__ unsigned short f2bf(float f) {
  unsigned u = __float_as_uint(f);
  u += 0x7FFFu + ((u >> 16) & 1u);
  return (unsigned short)(u >> 16);
}
__device__ __forceinline__ float bf2f(unsigned short v) {
  return __uint_as_float(((unsigned)v) << 16);
}
__device__ __forceinline__ float sigm(float x) {
  return __builtin_amdgcn_rcpf(1.f + __expf(-x));
}
__device__ __forceinline__ float tanh_fast(float x) {
  return 1.f - 2.f * __builtin_amdgcn_rcpf(__expf(2.f * x) + 1.f);
}

// ---------------------------------------------------------------------------
// MEGA kernel: blocks 0..127 = main bi-GRU (validated r5-r8 structure; B-frags
// now gathered directly from mWhh/mWih at startup). Blocks 128..198 = hier +
// loss weight repack (10 sub-bids each). Blocks 199..211 = ptpack computed
// directly from Wq.Wv (no PT intermediate). Block 212 = u/w/c0/acc.
// The extra blocks run on CUs idle during the 128-block GRU -> preprocessing
// is hidden under the GRU's 690 us.
__global__ __launch_bounds__(640, 2) void k_mega(
    const float* __restrict__ x,               // [1024][64][17]
    const float* __restrict__ mWih_f, const float* __restrict__ mWhh_f,
    const float* __restrict__ mWih_b, const float* __restrict__ mWhh_b,
    const float* __restrict__ mbih_f, const float* __restrict__ mbhh_f,
    const float* __restrict__ mbih_b, const float* __restrict__ mbhh_b,
    const float* __restrict__ hWih_f, const float* __restrict__ hWhh_f,
    const float* __restrict__ hWih_b, const float* __restrict__ hWhh_b,
    const float* __restrict__ Wp,
    const float* __restrict__ Wq, const float* __restrict__ bq,
    const float* __restrict__ Wv, const float* __restrict__ bv,
    unsigned short* __restrict__ rnn16,        // [1024][64][320]
    unsigned short* __restrict__ bpack,        // [2][24][14][64][8]
    unsigned short* __restrict__ bpackL,       // [3][10][64][8]
    unsigned short* __restrict__ pp,           // ptpack [16][8][64][8]
    float* __restrict__ u, float* __restrict__ w,
    float* __restrict__ c0, float* __restrict__ acc)
{
  __shared__ __align__(16) unsigned short hx[2][160];
  __shared__ __align__(16) unsigned short hist[2][16][160];
  __shared__ __align__(16) unsigned short xall[kT][32];
  const int blk = blockIdx.x;
  if (blk < 128) {
    // ---------------- main bi-GRU ----------------
    const int d = blk & 1, b = blk >> 1;
    const int tid = threadIdx.x, wv = tid >> 6, lane = tid & 63;
    const int col = lane & 15, q8 = (lane >> 4) * 8;
    for (int i = tid; i < 2 * 160; i += 640) ((unsigned short*)hx)[i] = 0;
    for (int i = tid; i < 2 * 16 * 160; i += 640) ((unsigned short*)hist)[i] = 0;
    for (int i = tid; i < kT * 32; i += 640) {
      const int t = i >> 5, c = i & 31;
      xall[t][c] = (c < kDIN) ? f2bf(x[((size_t)t * kB + b) * kDIN + c]) : (unsigned short)0;
    }
    const float* bih = d ? mbih_b : mbih_f;
    const float* bhh = d ? mbhh_b : mbhh_f;
    const float* Wihd = d ? mWih_b : mWih_f;   // [450][17]
    const float* Whhd = d ? mWhh_b : mWhh_f;   // [450][150]
    const int j = wv * 16 + col;
    const bool actv = (lane < 16) && (j < kHM);
    float br = 0.f, bz = 0.f, bnx = 0.f, bnh = 0.f;
    if (actv) {
      br  = bih[j] + bhh[j];
      bz  = bih[150 + j] + bhh[150 + j];
      bnx = bih[300 + j];
      bnh = bhh[300 + j];
    }
    // gather B-frags directly (once; amortized over 1024 steps)
    bf16x8 bw[3][6];
    const int gts[3] = { wv, 10 + wv, 20 + wv };
#pragma unroll
    for (int gi = 0; gi < 3; gi++) {
      const int slot = gts[gi] * 16 + col;
      const int type = slot / 160, jh = slot - type * 160;
      const int row = type * 150 + jh;
      const bool valid = (jh < 150);
#pragma unroll
      for (int kt = 0; kt < 6; kt++) {
        union { bf16x8 v; unsigned short us[8]; } tmp;
#pragma unroll
        for (int jj = 0; jj < 8; jj++) {
          float f = 0.f;
          if (valid) {
            if (kt < 5) {
              const int k = kt * 32 + (lane >> 4) * 8 + jj;
              if (k < 150) f = Whhd[row * 150 + k];
            } else {
              const int k = (lane >> 4) * 8 + jj;
              if (k < 17) f = Wihd[row * 17 + k];
            }
          }
          tmp.us[jj] = f2bf(f);
        }
        bw[gi][kt] = tmp.v;
      }
    }
    float h_old = 0.f;
    __syncthreads();

    for (int t = 0; t < kT; t++) {
      const int tx = d ? (kT - 1 - t) : t;
      const int buf = t & 1;
      bf16x8 afr[6];
#pragma unroll
      for (int kt = 0; kt < 5; kt++) afr[kt] = *(const bf16x8*)&hx[buf][kt * 32 + q8];
      afr[5] = *(const bf16x8*)&xall[tx][q8];
      f32x4 aR0 = (f32x4)(0.f), aR1 = (f32x4)(0.f);
      f32x4 aZ0 = (f32x4)(0.f), aZ1 = (f32x4)(0.f);
      f32x4 aN0 = (f32x4)(0.f), aN1 = (f32x4)(0.f);
      f32x4 aX  = (f32x4)(0.f);
#pragma unroll
      for (int kt = 0; kt < 6; kt++) {
        const bf16x8 af = afr[kt];
        if ((kt & 1) == 0) {
          aR0 = __builtin_amdgcn_mfma_f32_16x16x32_bf16(af, bw[0][kt], aR0, 0, 0, 0);
          aZ0 = __builtin_amdgcn_mfma_f32_16x16x32_bf16(af, bw[1][kt], aZ0, 0, 0, 0);
          aN0 = __builtin_amdgcn_mfma_f32_16x16x32_bf16(af, bw[2][kt], aN0, 0, 0, 0);
        } else if (kt < 5) {
          aR1 = __builtin_amdgcn_mfma_f32_16x16x32_bf16(af, bw[0][kt], aR1, 0, 0, 0);
          aZ1 = __builtin_amdgcn_mfma_f32_16x16x32_bf16(af, bw[1][kt], aZ1, 0, 0, 0);
          aN1 = __builtin_amdgcn_mfma_f32_16x16x32_bf16(af, bw[2][kt], aN1, 0, 0, 0);
        } else {
          aR1 = __builtin_amdgcn_mfma_f32_16x16x32_bf16(af, bw[0][5], aR1, 0, 0, 0);
          aZ1 = __builtin_amdgcn_mfma_f32_16x16x32_bf16(af, bw[1][5], aZ1, 0, 0, 0);
          aX  = __builtin_amdgcn_mfma_f32_16x16x32_bf16(af, bw[2][5], aX, 0, 0, 0);
        }
      }
      if (actv) {
        const float r = sigm(aR0[0] + aR1[0] + br);
        const float z = sigm(aZ0[0] + aZ1[0] + bz);
        const float n = tanh_fast(aX[0] + bnx + r * (aN0[0] + aN1[0] + bnh));
        h_old = (1.f - z) * n + z * h_old;
        const unsigned short us = f2bf(h_old);
        hx[buf ^ 1][j] = us;
        hist[(t >> 4) & 1][t & 15][j] = us;
      }
      __syncthreads();
      if ((t & 15) == 15) {
        const int hb = (t >> 4) & 1;
        const int toff = tid / 40, ch = tid - toff * 40;
        const int tg = t - 15 + toff;
        const int txg = d ? (kT - 1 - tg) : tg;
        *(ushort4*)&rnn16[((size_t)txg * kB + b) * 320 + d * 160 + ch * 4] =
            *(const ushort4*)&hist[hb][toff][ch * 4];
      }
    }
  } else if (blk < 199) {
    // ---------------- hier + loss weight repack ----------------
    const int sub = threadIdx.x >> 6, lane = threadIdx.x & 63;
    int bid = (blk - 128) * 10 + sub;
    if (bid >= 702) return;
    if (bid < 672) {
      const int kt = bid % 14;
      const int nt = (bid / 14) % 24;
      const int d  = bid / (14 * 24);
      const float* Wih = d ? hWih_b : hWih_f;   // [384][300]
      const float* Whh = d ? hWhh_b : hWhh_f;   // [384][128]
      const int n = nt * 16 + (lane & 15);
      const int kbase = kt * 32 + (lane >> 4) * 8;
      unsigned short* dst = bpack + ((((size_t)d * 24 + nt) * 14 + kt) * 64 + lane) * 8;
#pragma unroll
      for (int jj = 0; jj < 8; jj++) {
        const int k = kbase + jj;
        float f = 0.f;
        if (kt < 10) {
          if (k < 150) f = Wih[n * 300 + k];
          else if (k >= 160 && k < 310) f = Wih[n * 300 + (k - 10)];
        } else {
          f = Whh[n * 128 + (k - 320)];
        }
        dst[jj] = f2bf(f);
      }
    } else {
      bid -= 672;                       // 0..29 = nt*10+kt
      const int kt = bid % 10, nt = bid / 10;
      const int n = nt * 16 + (lane & 15);
      const int kbase = kt * 32 + (lane >> 4) * 8;
      unsigned short* dst = bpackL + (((size_t)bid) * 64 + lane) * 8;
#pragma unroll
      for (int jj = 0; jj < 8; jj++) {
        const int k = kbase + jj;
        float f = 0.f;
        if (n < kNP) {
          if (k < 150) f = Wp[n * 556 + k];
          else if (k >= 160 && k < 310) f = Wp[n * 556 + (k - 10)];
        }
        dst[jj] = f2bf(f);
      }
    }
  } else if (blk < 212) {
    // ---------------- ptpack direct from Wq.Wv ----------------
    const int sub = threadIdx.x >> 6, lane = threadIdx.x & 63;
    const int bid = (blk - 199) * 10 + sub;
    if (bid >= 128) return;
    const int kt = bid & 7, nt = bid >> 3;
    const int c = nt * 16 + (lane & 15);
    const int e0 = kt * 32 + (lane >> 4) * 8;
    float av[8];
#pragma unroll
    for (int jj = 0; jj < 8; jj++) av[jj] = 0.f;
    for (int a = 0; a < 256; a++) {
      const float wq = Wq[a * 256 + c];
#pragma unroll
      for (int jj = 0; jj < 8; jj++) av[jj] += wq * Wv[a * 256 + e0 + jj];
    }
    unsigned short* dst = pp + ((size_t)bid * 64 + lane) * 8;
#pragma unroll
    for (int jj = 0; jj < 8; jj++) dst[jj] = f2bf(av[jj]);
  } else {
    // ---------------- u, w, c0, acc ----------------
    const int a = threadIdx.x;
    if (a >= 256) return;
    float us = 0.f, ws = 0.f;
    for (int jj = 0; jj < 256; jj++) {
      us += Wq[jj * 256 + a] * bv[jj];
      ws += bq[jj] * Wv[jj * 256 + a];
    }
    u[a] = us; w[a] = ws;
    if (a == 0) {
      float cc = 0.f;
      for (int jj = 0; jj < 256; jj++) cc += bq[jj] * bv[jj];
      c0[0] = cc;
      acc[0] = acc[1] = acc[2] = acc[3] = 0.f;
    }
  }
}

// ---------------------------------------------------------------------------
// Hier bi-GRU (validated r7): 8 waves, register-resident B (42 frags).
__global__ __launch_bounds__(512, 1) void k_hier_mfma(
    const unsigned short* __restrict__ rnn16,  // [1024][64][320]
    const unsigned short* __restrict__ bpack,  // [2][24][14][64][8]
    const float* __restrict__ bihf, const float* __restrict__ bhhf,
    const float* __restrict__ bihb, const float* __restrict__ bhhb,
    unsigned short* __restrict__ hv16)         // [4096][16][256]
{
  const int d = blockIdx.x & 1;
  const int bn0 = (blockIdx.x >> 1) * 16;
  const int tid = threadIdx.x;
  const int w = tid >> 6;          // 0..7
  const int lane = tid & 63;
  const int q = lane >> 4, col = lane & 15, q8 = q * 8;

  __shared__ __align__(16) unsigned short x_s[2][16][328];
  __shared__ __align__(16) unsigned short h_s[16][136];

  for (int i = tid; i < 16 * 136; i += 512) ((unsigned short*)h_s)[i] = 0;
  const float* bih = d ? bihb : bihf;
  const float* bhh = d ? bhhb : bhhf;
  const int j = w * 16 + col;      // 0..127
  const float biR  = bih[j] + bhh[j];
  const float biZ  = bih[128 + j] + bhh[128 + j];
  const float biNX = bih[256 + j];
  const float biNH = bhh[256 + j];
  float h32r[4] = {0.f, 0.f, 0.f, 0.f};

  bf16x8 bw[3][14];
  const unsigned short* bpd = bpack + (size_t)d * 24 * 14 * 64 * 8;
  const int nts[3] = { w, 8 + w, 16 + w };
#pragma unroll
  for (int gi = 0; gi < 3; gi++)
#pragma unroll
    for (int kt = 0; kt < 14; kt++)
      bw[gi][kt] = *(const bf16x8*)&bpd[(((size_t)nts[gi] * 14 + kt) * 64 + lane) * 8];

  {
    const int mx0 = d ? 15 : 0;
    for (int i = tid; i < 640; i += 512) {
      const int r = i / 40, c = i - r * 40;
      const int bn = bn0 + r, bb = bn >> 6, nn = bn & 63;
      *(uint4*)&x_s[0][r][c * 8] =
          *(const uint4*)&rnn16[((size_t)(nn * 16 + mx0) * 64 + bb) * 320 + c * 8];
    }
  }
  __syncthreads();

  for (int m = 0; m < kM; m++) {
    const int mx = d ? (15 - m) : m;
    const int buf = m & 1;
    f32x4 aR = (f32x4)(0.f), aZ = (f32x4)(0.f), aNX = (f32x4)(0.f), aNH = (f32x4)(0.f);
#pragma unroll
    for (int kt = 0; kt < 14; kt++) {
      const bf16x8 af = (kt < 10) ? *(const bf16x8*)&x_s[buf][col][kt * 32 + q8]
                                  : *(const bf16x8*)&h_s[col][(kt - 10) * 32 + q8];
      aR = __builtin_amdgcn_mfma_f32_16x16x32_bf16(af, bw[0][kt], aR, 0, 0, 0);
      aZ = __builtin_amdgcn_mfma_f32_16x16x32_bf16(af, bw[1][kt], aZ, 0, 0, 0);
      if (kt < 10) aNX = __builtin_amdgcn_mfma_f32_16x16x32_bf16(af, bw[2][kt], aNX, 0, 0, 0);
      else         aNH = __builtin_amdgcn_mfma_f32_16x16x32_bf16(af, bw[2][kt], aNH, 0, 0, 0);
    }
    __syncthreads();
#pragma unroll
    for (int i = 0; i < 4; i++) {
      const int row = q * 4 + i;
      const float rr = sigm(aR[i] + biR);
      const float zz = sigm(aZ[i] + biZ);
      const float nn2 = tanh_fast(aNX[i] + biNX + rr * (aNH[i] + biNH));
      const float hnew = (1.f - zz) * nn2 + zz * h32r[i];
      h32r[i] = hnew;
      const unsigned short us = f2bf(hnew);
      h_s[row][j] = us;
      hv16[((size_t)(bn0 + row) * kM + mx) * 256 + d * kHH + j] = us;
    }
    if (m + 1 < kM) {
      const int mxn = d ? (15 - (m + 1)) : (m + 1);
      for (int i = tid; i < 640; i += 512) {
        const int r = i / 40, c = i - r * 40;
        const int bn = bn0 + r, bb = bn >> 6, nn = bn & 63;
        *(uint4*)&x_s[buf ^ 1][r][c * 8] =
            *(const uint4*)&rnn16[((size_t)(nn * 16 + mxn) * 64 + bb) * 320 + c * 8];
      }
    }
    __syncthreads();
  }
}

// ---------------------------------------------------------------------------
// Fused attention + ctx-logits: 256 blocks x 16 n. ctx stays in LDS;
// writes clog [4096][35] and kslogp [4096][15] directly.
__global__ __launch_bounds__(256) void k_attn_ctx(
    const unsigned short* __restrict__ hv16, const unsigned short* __restrict__ ptpack,
    const float* __restrict__ u, const float* __restrict__ w,
    const float* __restrict__ c0p,
    const float* __restrict__ Wp, const float* __restrict__ bp,
    const float* __restrict__ Wk, const float* __restrict__ bk,
    float* __restrict__ clog, float* __restrict__ kslogp) {
  const int tid = threadIdx.x;
  const int wv = tid >> 6, lane = tid & 63, col = lane & 15, q = lane >> 4, q8 = q * 8;
  __shared__ __align__(16) unsigned short hv16s[16][264];
  __shared__ __align__(16) unsigned short Ts16[16][264];
  __shared__ __align__(16) float W2[50][260];
  __shared__ __align__(16) float cs[256];
  __shared__ float pu[16][17], pw[16][17];
  __shared__ float uh[16], wh[16], SM[16];
  __shared__ float As[16][17];
  __shared__ float arr[64];
  __shared__ float bps[35], bks[15];
  const float c0 = c0p[0];
  for (int i = tid; i < 35 * 256; i += 256) { const int r = i >> 8, c = i & 255; W2[r][c] = Wp[r * 556 + 300 + c]; }
  for (int i = tid; i < 15 * 256; i += 256) { const int r = i >> 8, c = i & 255; W2[35 + r][c] = Wk[r * 256 + c]; }
  if (tid < 35) bps[tid] = bp[tid];
  else if (tid < 50) bks[tid - 35] = bk[tid - 35];
  bf16x8 bpt[4][8];
#pragma unroll
  for (int i2 = 0; i2 < 4; i2++)
#pragma unroll
    for (int kt = 0; kt < 8; kt++)
      bpt[i2][kt] = *(const bf16x8*)&ptpack[((((size_t)(wv * 4 + i2)) * 8 + kt) * 64 + lane) * 8];

  for (int ni = 0; ni < 16; ni++) {
    const int n = blockIdx.x * 16 + ni;
    {
      const unsigned short* src = hv16 + (size_t)n * 4096;
      const int row = tid >> 4, ci = (tid & 15) * 16;
#pragma unroll
      for (int k = 0; k < 16; k += 4)
        *(ushort4*)&hv16s[row][ci + k] = *(const ushort4*)&src[row * 256 + ci + k];
    }
    __syncthreads();
    {  // PT GEMM via MFMA
      f32x4 acc4[4];
#pragma unroll
      for (int i2 = 0; i2 < 4; i2++) acc4[i2] = (f32x4)(0.f);
#pragma unroll
      for (int kt = 0; kt < 8; kt++) {
        const bf16x8 af = *(const bf16x8*)&hv16s[col][kt * 32 + q8];
#pragma unroll
        for (int i2 = 0; i2 < 4; i2++)
          acc4[i2] = __builtin_amdgcn_mfma_f32_16x16x32_bf16(af, bpt[i2][kt], acc4[i2], 0, 0, 0);
      }
#pragma unroll
      for (int i2 = 0; i2 < 4; i2++) {
        const int nt = wv * 4 + i2;
#pragma unroll
        for (int i = 0; i < 4; i++) Ts16[q * 4 + i][nt * 16 + col] = f2bf(acc4[i2][i]);
      }
    }
    {  // u/w partial dots
      const int l = tid >> 4, s = tid & 15;
      float su = 0.f, sw = 0.f;
#pragma unroll
      for (int a0 = 0; a0 < 16; a0++) {
        const int a = s * 16 + a0;
        const float hvv = bf2f(hv16s[l][a]);
        su += hvv * u[a];
        sw += hvv * w[a];
      }
      pu[l][s] = su; pw[l][s] = sw;
    }
    __syncthreads();
    if (tid < 16) { float s2 = 0.f; for (int s = 0; s < 16; s++) s2 += pu[tid][s]; uh[tid] = s2; }
    else if (tid < 32) { float s2 = 0.f; for (int s = 0; s < 16; s++) s2 += pw[tid - 16][s]; wh[tid - 16] = s2; }
    __syncthreads();
    if (tid < 64) {  // wave 0: score MFMA + softmax
      f32x4 sa = (f32x4)(0.f);
#pragma unroll
      for (int kt = 0; kt < 8; kt++) {
        const bf16x8 af  = *(const bf16x8*)&hv16s[col][kt * 32 + q8];
        const bf16x8 bts = *(const bf16x8*)&Ts16[col][kt * 32 + q8];
        sa = __builtin_amdgcn_mfma_f32_16x16x32_bf16(af, bts, sa, 0, 0, 0);
      }
#pragma unroll
      for (int i = 0; i < 4; i++) {
        const int l = q * 4 + i;
        float sc = sa[i] + c0 + uh[l] + wh[col];
        float mxv = sc;
#pragma unroll
        for (int o = 8; o >= 1; o >>= 1) mxv = fmaxf(mxv, __shfl_xor(mxv, o, 16));
        const float e = __expf(sc - mxv);
        float se = e;
#pragma unroll
        for (int o = 8; o >= 1; o >>= 1) se += __shfl_xor(se, o, 16);
        As[l][col] = e / se;
      }
    }
    __syncthreads();
    if (tid < 16) {
      float s = 0.f;
      for (int l2 = 0; l2 < 16; l2++) s += As[l2][tid];
      SM[tid] = s;
    }
    __syncthreads();
    {  // ctx into LDS
      float cv = 0.f;
#pragma unroll
      for (int m2 = 0; m2 < 16; m2++) cv += SM[m2] * bf2f(hv16s[m2][tid]);
      cs[tid] = cv;
    }
    __syncthreads();
    {  // ctx-logits
      const int o = tid >> 2, s = tid & 3;
      float v = 0.f;
      if (o < 50) {
        for (int k0 = 0; k0 < 64; k0 += 4) {
          const int k = s * 64 + k0;
          const float4 wq = *(const float4*)&W2[o][k];
          const float4 cq = *(const float4*)&cs[k];
          v += wq.x * cq.x + wq.y * cq.y + wq.z * cq.z + wq.w * cq.w;
        }
      }
      v += __shfl_xor(v, 1);
      v += __shfl_xor(v, 2);
      if (o < 50 && s == 0) arr[o] = v;
    }
    __syncthreads();
    if (tid < 35) clog[n * kNP + tid] = arr[tid] + bps[tid];
    if (tid >= 64 && tid < 80) {
      const int t2 = tid - 64;
      float kk = (t2 < 15) ? arr[35 + t2] + bks[t2] : -1e30f;
      float mxv = kk;
#pragma unroll
      for (int off = 8; off >= 1; off >>= 1) mxv = fmaxf(mxv, __shfl_xor(mxv, off, 16));
      const float e = (t2 < 15) ? __expf(kk - mxv) : 0.f;
      float se = e;
#pragma unroll
      for (int off = 8; off >= 1; off >>= 1) se += __shfl_xor(se, off, 16);
      if (t2 < 15) kslogp[n * kNK + t2] = kk - mxv - __logf(se);
    }
    __syncthreads();
  }
}

// ---------------------------------------------------------------------------
// Loss via MFMA (validated r8).
__global__ __launch_bounds__(256, 2) void k_loss_mfma(
    const unsigned short* __restrict__ rnn16,  // [65536][320]
    const unsigned short* __restrict__ bpackL, // [3][10][64][8]
    const float* __restrict__ clog,            // [4096][35]
    const float* __restrict__ ks_logp,         // [4096][15]
    const int* __restrict__ pitches, const int* __restrict__ kss,
    float* __restrict__ acc) {
  const int tid = threadIdx.x, w = tid >> 6, lane = tid & 63;
  const int col = lane & 15, q = lane >> 4, q8 = q * 8;
  bf16x8 bl[3][10];
#pragma unroll
  for (int nt = 0; nt < 3; nt++)
#pragma unroll
    for (int kt = 0; kt < 10; kt++)
      bl[nt][kt] = *(const bf16x8*)&bpackL[(((size_t)nt * 10 + kt) * 64 + lane) * 8];

  float sp = 0.f, cp = 0.f, sk = 0.f, ck = 0.f;
#pragma unroll
  for (int mt = 0; mt < 2; mt++) {
    const int rowbase = blockIdx.x * 128 + w * 32 + mt * 16;
    f32x4 a0 = (f32x4)(0.f), a1 = (f32x4)(0.f), a2 = (f32x4)(0.f);
#pragma unroll
    for (int kt = 0; kt < 10; kt++) {
      const bf16x8 af = *(const bf16x8*)&rnn16[(size_t)(rowbase + col) * 320 + kt * 32 + q8];
      a0 = __builtin_amdgcn_mfma_f32_16x16x32_bf16(af, bl[0][kt], a0, 0, 0, 0);
      a1 = __builtin_amdgcn_mfma_f32_16x16x32_bf16(af, bl[1][kt], a1, 0, 0, 0);
      a2 = __builtin_amdgcn_mfma_f32_16x16x32_bf16(af, bl[2][kt], a2, 0, 0, 0);
    }
#pragma unroll
    for (int i = 0; i < 4; i++) {
      const int row = rowbase + q * 4 + i;
      const int t = row >> 6, b = row & 63;
      const int bn = b * 64 + (t >> 4);
      const float lg0 = a0[i] + clog[bn * kNP + col];
      const float lg1 = a1[i] + clog[bn * kNP + 16 + col];
      const float lg2 = (col < 3) ? (a2[i] + clog[bn * kNP + 32 + col]) : -1e30f;
      float mx = fmaxf(fmaxf(lg0, lg1), lg2);
#pragma unroll
      for (int o = 8; o >= 1; o >>= 1) mx = fmaxf(mx, __shfl_xor(mx, o, 16));
      float se = __expf(lg0 - mx) + __expf(lg1 - mx) + __expf(lg2 - mx);
#pragma unroll
      for (int o = 8; o >= 1; o >>= 1) se += __shfl_xor(se, o, 16);
      const int tp = pitches[row];
      const float cand = (tp < 16) ? a0[i] : (tp < 32) ? a1[i] : a2[i];
      const float tva = __shfl(cand, (lane & 48) | (tp & 15), 64);
      if (col == 0 && tp != 34) {
        sp += (mx + __logf(se)) - (tva + clog[bn * kNP + tp]);
        cp += 1.f;
      }
      if (col == 1) {
        const int tk = kss[row];
        if (tk != 14) { sk -= ks_logp[bn * kNK + tk]; ck += 1.f; }
      }
    }
  }
#pragma unroll
  for (int o = 32; o >= 1; o >>= 1) {
    sp += __shfl_xor(sp, o, 64);
    cp += __shfl_xor(cp, o, 64);
    sk += __shfl_xor(sk, o, 64);
    ck += __shfl_xor(ck, o, 64);
  }
  if (lane == 0) {
    atomicAdd(&acc[0], sp); atomicAdd(&acc[1], cp);
    atomicAdd(&acc[2], sk); atomicAdd(&acc[3], ck);
  }
}

__global__ void k_final(const float* __restrict__ acc, float* __restrict__ out) {
  out[0] = acc[0] / fmaxf(acc[1], 1.f) + acc[2] / fmaxf(acc[3], 1.f);
}

// ---------------------------------------------------------------------------
extern "C" void kernel_launch(void* const* d_in, const int* in_sizes, int n_in,
                              void* d_out, int out_size, void* d_ws, size_t ws_size,
                              hipStream_t stream) {
  (void)in_sizes; (void)n_in; (void)out_size; (void)ws_size;
  const float* sent    = (const float*)d_in[0];
  const int*   pitches = (const int*)d_in[1];
  const int*   kss     = (const int*)d_in[2];
  const float* mWih_f  = (const float*)d_in[5];
  const float* mWhh_f  = (const float*)d_in[6];
  const float* mbih_f  = (const float*)d_in[7];
  const float* mbhh_f  = (const float*)d_in[8];
  const float* mWih_b  = (const float*)d_in[9];
  const float* mWhh_b  = (const float*)d_in[10];
  const float* mbih_b  = (const float*)d_in[11];
  const float* mbhh_b  = (const float*)d_in[12];
  const float* hWih_f  = (const float*)d_in[13];
  const float* hWhh_f  = (const float*)d_in[14];
  const float* hbih_f  = (const float*)d_in[15];
  const float* hbhh_f  = (const float*)d_in[16];
  const float* hWih_b  = (const float*)d_in[17];
  const float* hWhh_b  = (const float*)d_in[18];
  const float* hbih_b  = (const float*)d_in[19];
  const float* hbhh_b  = (const float*)d_in[20];
  const float* Wq      = (const float*)d_in[21];
  const float* bq      = (const float*)d_in[22];
  const float* Wv      = (const float*)d_in[23];
  const float* bv      = (const float*)d_in[24];
  const float* Wp      = (const float*)d_in[25];
  const float* bp      = (const float*)d_in[26];
  const float* Wk      = (const float*)d_in[27];
  const float* bk      = (const float*)d_in[28];
  float* ws  = (float*)d_ws;
  float* out = (float*)d_out;
  unsigned short* rnn16  = (unsigned short*)(ws + OFF_RNN16);
  unsigned short* hv16   = (unsigned short*)(ws + OFF_HV16);
  unsigned short* ptpack = (unsigned short*)(ws + OFF_PTPACK);
  unsigned short* bpackL = (unsigned short*)(ws + OFF_BPACKL);
  unsigned short* bpack  = (unsigned short*)(ws + OFF_BPACK);

  k_mega<<<213, 640, 0, stream>>>(sent,
                                  mWih_f, mWhh_f, mWih_b, mWhh_b,
                                  mbih_f, mbhh_f, mbih_b, mbhh_b,
                                  hWih_f, hWhh_f, hWih_b, hWhh_b, Wp,
                                  Wq, bq, Wv, bv,
                                  rnn16, bpack, bpackL, ptpack,
                                  ws + OFF_U, ws + OFF_W, ws + OFF_C0, ws + OFF_ACC);
  k_hier_mfma<<<512, 512, 0, stream>>>(rnn16, bpack,
                                       hbih_f, hbhh_f, hbih_b, hbhh_b, hv16);
  k_attn_ctx<<<256, 256, 0, stream>>>(hv16, ptpack, ws + OFF_U, ws + OFF_W,
                                      ws + OFF_C0, Wp, bp, Wk, bk,
                                      ws + OFF_CLOG, ws + OFF_KSLOGP);
  k_loss_mfma<<<512, 256, 0, stream>>>(rnn16, bpackL, ws + OFF_CLOG, ws + OFF_KSLOGP,
                                       pitches, kss, ws + OFF_ACC);
  k_final<<<1, 1, 0, stream>>>(ws + OFF_ACC, out);
}

// Round 10
// 1024.975 us; speedup vs baseline: 1.6731x; 1.0163x over previous
//
#include <hip/hip_runtime.h>
#include <cstddef>

// ---- problem constants ----
constexpr int kT   = 1024;
constexpr int kB   = 64;
constexpr int kDIN = 17;
constexpr int kHM  = 150;   // main hidden (per dir)
constexpr int kHH  = 128;   // hier hidden (per dir)
constexpr int kM   = 16;    // measure length
constexpr int kD2  = 300;   // 2*kHM
constexpr int kNP  = 35;
constexpr int kNK  = 15;

// ---- workspace layout (float offsets, 16-float aligned) ----
constexpr size_t OFF_RNN16  = 0;          // ushort [1024][64][320] = 10,485,760 f
constexpr size_t OFF_HV16   = 10485760;   // ushort [4096][16][256] = 8,388,608 f
constexpr size_t OFF_PTPACK = 19988480;   // ushort [16][8][64][8] = 32,768 f
constexpr size_t OFF_U      = 20021248;   // [256]
constexpr size_t OFF_W      = 20021504;   // [256]
constexpr size_t OFF_C0     = 20021760;   // [16]
constexpr size_t OFF_ACC    = 20021776;   // [16] (sp,cp,sk,ck,counter)
constexpr size_t OFF_KSLOGP = 20021792;   // [4096][15]
constexpr size_t OFF_CLOG   = 20083232;   // [4096][35]
constexpr size_t OFF_BPACK  = 20318752;   // ushort [2][24][14][64][8] = 172,032 f
constexpr size_t OFF_BPACKL = 20490784;   // ushort [3][10][64][8] = 7,680 f

typedef __bf16 bf16x8 __attribute__((ext_vector_type(8)));
typedef float f32x4 __attribute__((ext_vector_type(4)));

__device__ __forceinline__ unsigned short f2bf(float f) {
  unsigned u = __float_as_uint(f);
  u += 0x7FFFu + ((u >> 16) & 1u);
  return (unsigned short)(u >> 16);
}
__device__ __forceinline__ float bf2f(unsigned short v) {
  return __uint_as_float(((unsigned)v) << 16);
}
__device__ __forceinline__ float sigm(float x) {
  return __builtin_amdgcn_rcpf(1.f + __expf(-x));
}
__device__ __forceinline__ float tanh_fast(float x) {
  return 1.f - 2.f * __builtin_amdgcn_rcpf(__expf(2.f * x) + 1.f);
}

// ---------------------------------------------------------------------------
// MEGA kernel (validated r9): blocks 0..127 main bi-GRU; 128..198 repack;
// 199..211 ptpack; 212 u/w/c0/acc.
__global__ __launch_bounds__(640, 2) void k_mega(
    const float* __restrict__ x,               // [1024][64][17]
    const float* __restrict__ mWih_f, const float* __restrict__ mWhh_f,
    const float* __restrict__ mWih_b, const float* __restrict__ mWhh_b,
    const float* __restrict__ mbih_f, const float* __restrict__ mbhh_f,
    const float* __restrict__ mbih_b, const float* __restrict__ mbhh_b,
    const float* __restrict__ hWih_f, const float* __restrict__ hWhh_f,
    const float* __restrict__ hWih_b, const float* __restrict__ hWhh_b,
    const float* __restrict__ Wp,
    const float* __restrict__ Wq, const float* __restrict__ bq,
    const float* __restrict__ Wv, const float* __restrict__ bv,
    unsigned short* __restrict__ rnn16,        // [1024][64][320]
    unsigned short* __restrict__ bpack,        // [2][24][14][64][8]
    unsigned short* __restrict__ bpackL,       // [3][10][64][8]
    unsigned short* __restrict__ pp,           // ptpack [16][8][64][8]
    float* __restrict__ u, float* __restrict__ w,
    float* __restrict__ c0, float* __restrict__ acc)
{
  __shared__ __align__(16) unsigned short hx[2][160];
  __shared__ __align__(16) unsigned short hist[2][16][160];
  __shared__ __align__(16) unsigned short xall[kT][32];
  const int blk = blockIdx.x;
  if (blk < 128) {
    // ---------------- main bi-GRU ----------------
    const int d = blk & 1, b = blk >> 1;
    const int tid = threadIdx.x, wv = tid >> 6, lane = tid & 63;
    const int col = lane & 15, q8 = (lane >> 4) * 8;
    for (int i = tid; i < 2 * 160; i += 640) ((unsigned short*)hx)[i] = 0;
    for (int i = tid; i < 2 * 16 * 160; i += 640) ((unsigned short*)hist)[i] = 0;
    for (int i = tid; i < kT * 32; i += 640) {
      const int t = i >> 5, c = i & 31;
      xall[t][c] = (c < kDIN) ? f2bf(x[((size_t)t * kB + b) * kDIN + c]) : (unsigned short)0;
    }
    const float* bih = d ? mbih_b : mbih_f;
    const float* bhh = d ? mbhh_b : mbhh_f;
    const float* Wihd = d ? mWih_b : mWih_f;   // [450][17]
    const float* Whhd = d ? mWhh_b : mWhh_f;   // [450][150]
    const int j = wv * 16 + col;
    const bool actv = (lane < 16) && (j < kHM);
    float br = 0.f, bz = 0.f, bnx = 0.f, bnh = 0.f;
    if (actv) {
      br  = bih[j] + bhh[j];
      bz  = bih[150 + j] + bhh[150 + j];
      bnx = bih[300 + j];
      bnh = bhh[300 + j];
    }
    bf16x8 bw[3][6];
    const int gts[3] = { wv, 10 + wv, 20 + wv };
#pragma unroll
    for (int gi = 0; gi < 3; gi++) {
      const int slot = gts[gi] * 16 + col;
      const int type = slot / 160, jh = slot - type * 160;
      const int row = type * 150 + jh;
      const bool valid = (jh < 150);
#pragma unroll
      for (int kt = 0; kt < 6; kt++) {
        union { bf16x8 v; unsigned short us[8]; } tmp;
#pragma unroll
        for (int jj = 0; jj < 8; jj++) {
          float f = 0.f;
          if (valid) {
            if (kt < 5) {
              const int k = kt * 32 + (lane >> 4) * 8 + jj;
              if (k < 150) f = Whhd[row * 150 + k];
            } else {
              const int k = (lane >> 4) * 8 + jj;
              if (k < 17) f = Wihd[row * 17 + k];
            }
          }
          tmp.us[jj] = f2bf(f);
        }
        bw[gi][kt] = tmp.v;
      }
    }
    float h_old = 0.f;
    __syncthreads();

    for (int t = 0; t < kT; t++) {
      const int tx = d ? (kT - 1 - t) : t;
      const int buf = t & 1;
      bf16x8 afr[6];
#pragma unroll
      for (int kt = 0; kt < 5; kt++) afr[kt] = *(const bf16x8*)&hx[buf][kt * 32 + q8];
      afr[5] = *(const bf16x8*)&xall[tx][q8];
      f32x4 aR0 = (f32x4)(0.f), aR1 = (f32x4)(0.f);
      f32x4 aZ0 = (f32x4)(0.f), aZ1 = (f32x4)(0.f);
      f32x4 aN0 = (f32x4)(0.f), aN1 = (f32x4)(0.f);
      f32x4 aX  = (f32x4)(0.f);
#pragma unroll
      for (int kt = 0; kt < 6; kt++) {
        const bf16x8 af = afr[kt];
        if ((kt & 1) == 0) {
          aR0 = __builtin_amdgcn_mfma_f32_16x16x32_bf16(af, bw[0][kt], aR0, 0, 0, 0);
          aZ0 = __builtin_amdgcn_mfma_f32_16x16x32_bf16(af, bw[1][kt], aZ0, 0, 0, 0);
          aN0 = __builtin_amdgcn_mfma_f32_16x16x32_bf16(af, bw[2][kt], aN0, 0, 0, 0);
        } else if (kt < 5) {
          aR1 = __builtin_amdgcn_mfma_f32_16x16x32_bf16(af, bw[0][kt], aR1, 0, 0, 0);
          aZ1 = __builtin_amdgcn_mfma_f32_16x16x32_bf16(af, bw[1][kt], aZ1, 0, 0, 0);
          aN1 = __builtin_amdgcn_mfma_f32_16x16x32_bf16(af, bw[2][kt], aN1, 0, 0, 0);
        } else {
          aR1 = __builtin_amdgcn_mfma_f32_16x16x32_bf16(af, bw[0][5], aR1, 0, 0, 0);
          aZ1 = __builtin_amdgcn_mfma_f32_16x16x32_bf16(af, bw[1][5], aZ1, 0, 0, 0);
          aX  = __builtin_amdgcn_mfma_f32_16x16x32_bf16(af, bw[2][5], aX, 0, 0, 0);
        }
      }
      if (actv) {
        const float r = sigm(aR0[0] + aR1[0] + br);
        const float z = sigm(aZ0[0] + aZ1[0] + bz);
        const float n = tanh_fast(aX[0] + bnx + r * (aN0[0] + aN1[0] + bnh));
        h_old = (1.f - z) * n + z * h_old;
        const unsigned short us = f2bf(h_old);
        hx[buf ^ 1][j] = us;
        hist[(t >> 4) & 1][t & 15][j] = us;
      }
      __syncthreads();
      if ((t & 15) == 15) {
        const int hb = (t >> 4) & 1;
        const int toff = tid / 40, ch = tid - toff * 40;
        const int tg = t - 15 + toff;
        const int txg = d ? (kT - 1 - tg) : tg;
        *(ushort4*)&rnn16[((size_t)txg * kB + b) * 320 + d * 160 + ch * 4] =
            *(const ushort4*)&hist[hb][toff][ch * 4];
      }
    }
  } else if (blk < 199) {
    // ---------------- hier + loss weight repack ----------------
    const int sub = threadIdx.x >> 6, lane = threadIdx.x & 63;
    int bid = (blk - 128) * 10 + sub;
    if (bid >= 702) return;
    if (bid < 672) {
      const int kt = bid % 14;
      const int nt = (bid / 14) % 24;
      const int d  = bid / (14 * 24);
      const float* Wih = d ? hWih_b : hWih_f;   // [384][300]
      const float* Whh = d ? hWhh_b : hWhh_f;   // [384][128]
      const int n = nt * 16 + (lane & 15);
      const int kbase = kt * 32 + (lane >> 4) * 8;
      unsigned short* dst = bpack + ((((size_t)d * 24 + nt) * 14 + kt) * 64 + lane) * 8;
#pragma unroll
      for (int jj = 0; jj < 8; jj++) {
        const int k = kbase + jj;
        float f = 0.f;
        if (kt < 10) {
          if (k < 150) f = Wih[n * 300 + k];
          else if (k >= 160 && k < 310) f = Wih[n * 300 + (k - 10)];
        } else {
          f = Whh[n * 128 + (k - 320)];
        }
        dst[jj] = f2bf(f);
      }
    } else {
      bid -= 672;                       // 0..29 = nt*10+kt
      const int kt = bid % 10, nt = bid / 10;
      const int n = nt * 16 + (lane & 15);
      const int kbase = kt * 32 + (lane >> 4) * 8;
      unsigned short* dst = bpackL + (((size_t)bid) * 64 + lane) * 8;
#pragma unroll
      for (int jj = 0; jj < 8; jj++) {
        const int k = kbase + jj;
        float f = 0.f;
        if (n < kNP) {
          if (k < 150) f = Wp[n * 556 + k];
          else if (k >= 160 && k < 310) f = Wp[n * 556 + (k - 10)];
        }
        dst[jj] = f2bf(f);
      }
    }
  } else if (blk < 212) {
    // ---------------- ptpack direct from Wq.Wv ----------------
    const int sub = threadIdx.x >> 6, lane = threadIdx.x & 63;
    const int bid = (blk - 199) * 10 + sub;
    if (bid >= 128) return;
    const int kt = bid & 7, nt = bid >> 3;
    const int c = nt * 16 + (lane & 15);
    const int e0 = kt * 32 + (lane >> 4) * 8;
    float av[8];
#pragma unroll
    for (int jj = 0; jj < 8; jj++) av[jj] = 0.f;
    for (int a = 0; a < 256; a++) {
      const float wq = Wq[a * 256 + c];
#pragma unroll
      for (int jj = 0; jj < 8; jj++) av[jj] += wq * Wv[a * 256 + e0 + jj];
    }
    unsigned short* dst = pp + ((size_t)bid * 64 + lane) * 8;
#pragma unroll
    for (int jj = 0; jj < 8; jj++) dst[jj] = f2bf(av[jj]);
  } else {
    // ---------------- u, w, c0, acc ----------------
    const int a = threadIdx.x;
    if (a >= 256) return;
    float us = 0.f, ws = 0.f;
    for (int jj = 0; jj < 256; jj++) {
      us += Wq[jj * 256 + a] * bv[jj];
      ws += bq[jj] * Wv[jj * 256 + a];
    }
    u[a] = us; w[a] = ws;
    if (a == 0) {
      float cc = 0.f;
      for (int jj = 0; jj < 256; jj++) cc += bq[jj] * bv[jj];
      c0[0] = cc;
      acc[0] = acc[1] = acc[2] = acc[3] = acc[4] = 0.f;
    }
  }
}

// ---------------------------------------------------------------------------
// Hier bi-GRU (validated r7-r9): 8 waves, register-resident B (42 frags).
__global__ __launch_bounds__(512, 1) void k_hier_mfma(
    const unsigned short* __restrict__ rnn16,  // [1024][64][320]
    const unsigned short* __restrict__ bpack,  // [2][24][14][64][8]
    const float* __restrict__ bihf, const float* __restrict__ bhhf,
    const float* __restrict__ bihb, const float* __restrict__ bhhb,
    unsigned short* __restrict__ hv16)         // [4096][16][256]
{
  const int d = blockIdx.x & 1;
  const int bn0 = (blockIdx.x >> 1) * 16;
  const int tid = threadIdx.x;
  const int w = tid >> 6;          // 0..7
  const int lane = tid & 63;
  const int q = lane >> 4, col = lane & 15, q8 = q * 8;

  __shared__ __align__(16) unsigned short x_s[2][16][328];
  __shared__ __align__(16) unsigned short h_s[16][136];

  for (int i = tid; i < 16 * 136; i += 512) ((unsigned short*)h_s)[i] = 0;
  const float* bih = d ? bihb : bihf;
  const float* bhh = d ? bhhb : bhhf;
  const int j = w * 16 + col;      // 0..127
  const float biR  = bih[j] + bhh[j];
  const float biZ  = bih[128 + j] + bhh[128 + j];
  const float biNX = bih[256 + j];
  const float biNH = bhh[256 + j];
  float h32r[4] = {0.f, 0.f, 0.f, 0.f};

  bf16x8 bw[3][14];
  const unsigned short* bpd = bpack + (size_t)d * 24 * 14 * 64 * 8;
  const int nts[3] = { w, 8 + w, 16 + w };
#pragma unroll
  for (int gi = 0; gi < 3; gi++)
#pragma unroll
    for (int kt = 0; kt < 14; kt++)
      bw[gi][kt] = *(const bf16x8*)&bpd[(((size_t)nts[gi] * 14 + kt) * 64 + lane) * 8];

  {
    const int mx0 = d ? 15 : 0;
    for (int i = tid; i < 640; i += 512) {
      const int r = i / 40, c = i - r * 40;
      const int bn = bn0 + r, bb = bn >> 6, nn = bn & 63;
      *(uint4*)&x_s[0][r][c * 8] =
          *(const uint4*)&rnn16[((size_t)(nn * 16 + mx0) * 64 + bb) * 320 + c * 8];
    }
  }
  __syncthreads();

  for (int m = 0; m < kM; m++) {
    const int mx = d ? (15 - m) : m;
    const int buf = m & 1;
    f32x4 aR = (f32x4)(0.f), aZ = (f32x4)(0.f), aNX = (f32x4)(0.f), aNH = (f32x4)(0.f);
#pragma unroll
    for (int kt = 0; kt < 14; kt++) {
      const bf16x8 af = (kt < 10) ? *(const bf16x8*)&x_s[buf][col][kt * 32 + q8]
                                  : *(const bf16x8*)&h_s[col][(kt - 10) * 32 + q8];
      aR = __builtin_amdgcn_mfma_f32_16x16x32_bf16(af, bw[0][kt], aR, 0, 0, 0);
      aZ = __builtin_amdgcn_mfma_f32_16x16x32_bf16(af, bw[1][kt], aZ, 0, 0, 0);
      if (kt < 10) aNX = __builtin_amdgcn_mfma_f32_16x16x32_bf16(af, bw[2][kt], aNX, 0, 0, 0);
      else         aNH = __builtin_amdgcn_mfma_f32_16x16x32_bf16(af, bw[2][kt], aNH, 0, 0, 0);
    }
    __syncthreads();
#pragma unroll
    for (int i = 0; i < 4; i++) {
      const int row = q * 4 + i;
      const float rr = sigm(aR[i] + biR);
      const float zz = sigm(aZ[i] + biZ);
      const float nn2 = tanh_fast(aNX[i] + biNX + rr * (aNH[i] + biNH));
      const float hnew = (1.f - zz) * nn2 + zz * h32r[i];
      h32r[i] = hnew;
      const unsigned short us = f2bf(hnew);
      h_s[row][j] = us;
      hv16[((size_t)(bn0 + row) * kM + mx) * 256 + d * kHH + j] = us;
    }
    if (m + 1 < kM) {
      const int mxn = d ? (15 - (m + 1)) : (m + 1);
      for (int i = tid; i < 640; i += 512) {
        const int r = i / 40, c = i - r * 40;
        const int bn = bn0 + r, bb = bn >> 6, nn = bn & 63;
        *(uint4*)&x_s[buf ^ 1][r][c * 8] =
            *(const uint4*)&rnn16[((size_t)(nn * 16 + mxn) * 64 + bb) * 320 + c * 8];
      }
    }
    __syncthreads();
  }
}

// ---------------------------------------------------------------------------
// Fused attention + ctx-logits, r10: 512 blocks x 8 n (2 blocks/CU co-res
// -> 2x wave-parallelism, half the serial depth), u/w in LDS, register
// prefetch of next n's hv hidden under the ctx-logits phase.
__global__ __launch_bounds__(256) void k_attn_ctx(
    const unsigned short* __restrict__ hv16, const unsigned short* __restrict__ ptpack,
    const float* __restrict__ u, const float* __restrict__ w,
    const float* __restrict__ c0p,
    const float* __restrict__ Wp, const float* __restrict__ bp,
    const float* __restrict__ Wk, const float* __restrict__ bk,
    float* __restrict__ clog, float* __restrict__ kslogp) {
  const int tid = threadIdx.x;
  const int wv = tid >> 6, lane = tid & 63, col = lane & 15, q = lane >> 4, q8 = q * 8;
  __shared__ __align__(16) unsigned short hv16s[16][264];
  __shared__ __align__(16) unsigned short Ts16[16][264];
  __shared__ __align__(16) float W2[50][260];
  __shared__ __align__(16) float cs[256];
  __shared__ __align__(16) float us[256], wss[256];
  __shared__ float pu[16][17], pw[16][17];
  __shared__ float uh[16], wh[16], SM[16];
  __shared__ float As[16][17];
  __shared__ float arr[64];
  __shared__ float bps[35], bks[15];
  const float c0 = c0p[0];
  for (int i = tid; i < 35 * 256; i += 256) { const int r = i >> 8, c = i & 255; W2[r][c] = Wp[r * 556 + 300 + c]; }
  for (int i = tid; i < 15 * 256; i += 256) { const int r = i >> 8, c = i & 255; W2[35 + r][c] = Wk[r * 256 + c]; }
  us[tid] = u[tid];
  wss[tid] = w[tid];
  if (tid < 35) bps[tid] = bp[tid];
  else if (tid < 50) bks[tid - 35] = bk[tid - 35];
  bf16x8 bpt[4][8];
#pragma unroll
  for (int i2 = 0; i2 < 4; i2++)
#pragma unroll
    for (int kt = 0; kt < 8; kt++)
      bpt[i2][kt] = *(const bf16x8*)&ptpack[((((size_t)(wv * 4 + i2)) * 8 + kt) * 64 + lane) * 8];

  const int srow = tid >> 4, sci = (tid & 15) * 16;
  { // stage n0
    const unsigned short* src = hv16 + (size_t)(blockIdx.x * 8) * 4096;
#pragma unroll
    for (int k = 0; k < 16; k += 4)
      *(ushort4*)&hv16s[srow][sci + k] = *(const ushort4*)&src[srow * 256 + sci + k];
  }
  __syncthreads();

  for (int ni = 0; ni < 8; ni++) {
    const int n = blockIdx.x * 8 + ni;
    // prefetch next n's hv into registers (written to LDS after last hv16s read)
    ushort4 pf[4];
    if (ni + 1 < 8) {
      const unsigned short* src = hv16 + (size_t)(n + 1) * 4096;
#pragma unroll
      for (int k2 = 0; k2 < 4; k2++) pf[k2] = *(const ushort4*)&src[srow * 256 + sci + k2 * 4];
    }
    {  // PT GEMM via MFMA
      f32x4 acc4[4];
#pragma unroll
      for (int i2 = 0; i2 < 4; i2++) acc4[i2] = (f32x4)(0.f);
#pragma unroll
      for (int kt = 0; kt < 8; kt++) {
        const bf16x8 af = *(const bf16x8*)&hv16s[col][kt * 32 + q8];
#pragma unroll
        for (int i2 = 0; i2 < 4; i2++)
          acc4[i2] = __builtin_amdgcn_mfma_f32_16x16x32_bf16(af, bpt[i2][kt], acc4[i2], 0, 0, 0);
      }
#pragma unroll
      for (int i2 = 0; i2 < 4; i2++) {
        const int nt = wv * 4 + i2;
#pragma unroll
        for (int i = 0; i < 4; i++) Ts16[q * 4 + i][nt * 16 + col] = f2bf(acc4[i2][i]);
      }
    }
    {  // u/w partial dots (LDS sources)
      const int l = tid >> 4, s = tid & 15;
      float su = 0.f, sw = 0.f;
#pragma unroll
      for (int a0 = 0; a0 < 16; a0++) {
        const int a = s * 16 + a0;
        const float hvv = bf2f(hv16s[l][a]);
        su += hvv * us[a];
        sw += hvv * wss[a];
      }
      pu[l][s] = su; pw[l][s] = sw;
    }
    __syncthreads();
    if (tid < 16) { float s2 = 0.f; for (int s = 0; s < 16; s++) s2 += pu[tid][s]; uh[tid] = s2; }
    else if (tid < 32) { float s2 = 0.f; for (int s = 0; s < 16; s++) s2 += pw[tid - 16][s]; wh[tid - 16] = s2; }
    __syncthreads();
    if (tid < 64) {  // wave 0: score MFMA + softmax
      f32x4 sa = (f32x4)(0.f);
#pragma unroll
      for (int kt = 0; kt < 8; kt++) {
        const bf16x8 af  = *(const bf16x8*)&hv16s[col][kt * 32 + q8];
        const bf16x8 bts = *(const bf16x8*)&Ts16[col][kt * 32 + q8];
        sa = __builtin_amdgcn_mfma_f32_16x16x32_bf16(af, bts, sa, 0, 0, 0);
      }
#pragma unroll
      for (int i = 0; i < 4; i++) {
        const int l = q * 4 + i;
        float sc = sa[i] + c0 + uh[l] + wh[col];
        float mxv = sc;
#pragma unroll
        for (int o = 8; o >= 1; o >>= 1) mxv = fmaxf(mxv, __shfl_xor(mxv, o, 16));
        const float e = __expf(sc - mxv);
        float se = e;
#pragma unroll
        for (int o = 8; o >= 1; o >>= 1) se += __shfl_xor(se, o, 16);
        As[l][col] = e / se;
      }
    }
    __syncthreads();
    if (tid < 16) {
      float s = 0.f;
      for (int l2 = 0; l2 < 16; l2++) s += As[l2][tid];
      SM[tid] = s;
    }
    __syncthreads();
    {  // ctx into LDS (last read of hv16s this iteration)
      float cv = 0.f;
#pragma unroll
      for (int m2 = 0; m2 < 16; m2++) cv += SM[m2] * bf2f(hv16s[m2][tid]);
      cs[tid] = cv;
    }
    __syncthreads();
    // hv16s now free: write the prefetched next-n hv
    if (ni + 1 < 8) {
#pragma unroll
      for (int k2 = 0; k2 < 4; k2++) *(ushort4*)&hv16s[srow][sci + k2 * 4] = pf[k2];
    }
    {  // ctx-logits
      const int o = tid >> 2, s = tid & 3;
      float v = 0.f;
      if (o < 50) {
        for (int k0 = 0; k0 < 64; k0 += 4) {
          const int k = s * 64 + k0;
          const float4 wq = *(const float4*)&W2[o][k];
          const float4 cq = *(const float4*)&cs[k];
          v += wq.x * cq.x + wq.y * cq.y + wq.z * cq.z + wq.w * cq.w;
        }
      }
      v += __shfl_xor(v, 1);
      v += __shfl_xor(v, 2);
      if (o < 50 && s == 0) arr[o] = v;
    }
    __syncthreads();
    if (tid < 35) clog[n * kNP + tid] = arr[tid] + bps[tid];
    if (tid >= 64 && tid < 80) {
      const int t2 = tid - 64;
      float kk = (t2 < 15) ? arr[35 + t2] + bks[t2] : -1e30f;
      float mxv = kk;
#pragma unroll
      for (int off = 8; off >= 1; off >>= 1) mxv = fmaxf(mxv, __shfl_xor(mxv, off, 16));
      const float e = (t2 < 15) ? __expf(kk - mxv) : 0.f;
      float se = e;
#pragma unroll
      for (int off = 8; off >= 1; off >>= 1) se += __shfl_xor(se, off, 16);
      if (t2 < 15) kslogp[n * kNK + t2] = kk - mxv - __logf(se);
    }
    __syncthreads();
  }
}

// ---------------------------------------------------------------------------
// Loss via MFMA (validated r8) + fused final reduction via completion counter.
__global__ __launch_bounds__(256, 2) void k_loss_mfma(
    const unsigned short* __restrict__ rnn16,  // [65536][320]
    const unsigned short* __restrict__ bpackL, // [3][10][64][8]
    const float* __restrict__ clog,            // [4096][35]
    const float* __restrict__ ks_logp,         // [4096][15]
    const int* __restrict__ pitches, const int* __restrict__ kss,
    float* __restrict__ acc, float* __restrict__ out) {
  const int tid = threadIdx.x, w = tid >> 6, lane = tid & 63;
  const int col = lane & 15, q = lane >> 4, q8 = q * 8;
  bf16x8 bl[3][10];
#pragma unroll
  for (int nt = 0; nt < 3; nt++)
#pragma unroll
    for (int kt = 0; kt < 10; kt++)
      bl[nt][kt] = *(const bf16x8*)&bpackL[(((size_t)nt * 10 + kt) * 64 + lane) * 8];

  float sp = 0.f, cp = 0.f, sk = 0.f, ck = 0.f;
#pragma unroll
  for (int mt = 0; mt < 2; mt++) {
    const int rowbase = blockIdx.x * 128 + w * 32 + mt * 16;
    f32x4 a0 = (f32x4)(0.f), a1 = (f32x4)(0.f), a2 = (f32x4)(0.f);
#pragma unroll
    for (int kt = 0; kt < 10; kt++) {
      const bf16x8 af = *(const bf16x8*)&rnn16[(size_t)(rowbase + col) * 320 + kt * 32 + q8];
      a0 = __builtin_amdgcn_mfma_f32_16x16x32_bf16(af, bl[0][kt], a0, 0, 0, 0);
      a1 = __builtin_amdgcn_mfma_f32_16x16x32_bf16(af, bl[1][kt], a1, 0, 0, 0);
      a2 = __builtin_amdgcn_mfma_f32_16x16x32_bf16(af, bl[2][kt], a2, 0, 0, 0);
    }
#pragma unroll
    for (int i = 0; i < 4; i++) {
      const int row = rowbase + q * 4 + i;
      const int t = row >> 6, b = row & 63;
      const int bn = b * 64 + (t >> 4);
      const float lg0 = a0[i] + clog[bn * kNP + col];
      const float lg1 = a1[i] + clog[bn * kNP + 16 + col];
      const float lg2 = (col < 3) ? (a2[i] + clog[bn * kNP + 32 + col]) : -1e30f;
      float mx = fmaxf(fmaxf(lg0, lg1), lg2);
#pragma unroll
      for (int o = 8; o >= 1; o >>= 1) mx = fmaxf(mx, __shfl_xor(mx, o, 16));
      float se = __expf(lg0 - mx) + __expf(lg1 - mx) + __expf(lg2 - mx);
#pragma unroll
      for (int o = 8; o >= 1; o >>= 1) se += __shfl_xor(se, o, 16);
      const int tp = pitches[row];
      const float cand = (tp < 16) ? a0[i] : (tp < 32) ? a1[i] : a2[i];
      const float tva = __shfl(cand, (lane & 48) | (tp & 15), 64);
      if (col == 0 && tp != 34) {
        sp += (mx + __logf(se)) - (tva + clog[bn * kNP + tp]);
        cp += 1.f;
      }
      if (col == 1) {
        const int tk = kss[row];
        if (tk != 14) { sk -= ks_logp[bn * kNK + tk]; ck += 1.f; }
      }
    }
  }
#pragma unroll
  for (int o = 32; o >= 1; o >>= 1) {
    sp += __shfl_xor(sp, o, 64);
    cp += __shfl_xor(cp, o, 64);
    sk += __shfl_xor(sk, o, 64);
    ck += __shfl_xor(ck, o, 64);
  }
  if (lane == 0) {
    atomicAdd(&acc[0], sp); atomicAdd(&acc[1], cp);
    atomicAdd(&acc[2], sk); atomicAdd(&acc[3], ck);
  }
  __syncthreads();
  if (tid == 0) {
    __threadfence();
    const float done = atomicAdd(&acc[4], 1.f);
    if (done == (float)(gridDim.x - 1)) {
      const float a0 = atomicAdd(&acc[0], 0.f);
      const float a1 = atomicAdd(&acc[1], 0.f);
      const float a2 = atomicAdd(&acc[2], 0.f);
      const float a3 = atomicAdd(&acc[3], 0.f);
      out[0] = a0 / fmaxf(a1, 1.f) + a2 / fmaxf(a3, 1.f);
    }
  }
}

// ---------------------------------------------------------------------------
extern "C" void kernel_launch(void* const* d_in, const int* in_sizes, int n_in,
                              void* d_out, int out_size, void* d_ws, size_t ws_size,
                              hipStream_t stream) {
  (void)in_sizes; (void)n_in; (void)out_size; (void)ws_size;
  const float* sent    = (const float*)d_in[0];
  const int*   pitches = (const int*)d_in[1];
  const int*   kss     = (const int*)d_in[2];
  const float* mWih_f  = (const float*)d_in[5];
  const float* mWhh_f  = (const float*)d_in[6];
  const float* mbih_f  = (const float*)d_in[7];
  const float* mbhh_f  = (const float*)d_in[8];
  const float* mWih_b  = (const float*)d_in[9];
  const float* mWhh_b  = (const float*)d_in[10];
  const float* mbih_b  = (const float*)d_in[11];
  const float* mbhh_b  = (const float*)d_in[12];
  const float* hWih_f  = (const float*)d_in[13];
  const float* hWhh_f  = (const float*)d_in[14];
  const float* hbih_f  = (const float*)d_in[15];
  const float* hbhh_f  = (const float*)d_in[16];
  const float* hWih_b  = (const float*)d_in[17];
  const float* hWhh_b  = (const float*)d_in[18];
  const float* hbih_b  = (const float*)d_in[19];
  const float* hbhh_b  = (const float*)d_in[20];
  const float* Wq      = (const float*)d_in[21];
  const float* bq      = (const float*)d_in[22];
  const float* Wv      = (const float*)d_in[23];
  const float* bv      = (const float*)d_in[24];
  const float* Wp      = (const float*)d_in[25];
  const float* bp      = (const float*)d_in[26];
  const float* Wk      = (const float*)d_in[27];
  const float* bk      = (const float*)d_in[28];
  float* ws  = (float*)d_ws;
  float* out = (float*)d_out;
  unsigned short* rnn16  = (unsigned short*)(ws + OFF_RNN16);
  unsigned short* hv16   = (unsigned short*)(ws + OFF_HV16);
  unsigned short* ptpack = (unsigned short*)(ws + OFF_PTPACK);
  unsigned short* bpackL = (unsigned short*)(ws + OFF_BPACKL);
  unsigned short* bpack  = (unsigned short*)(ws + OFF_BPACK);

  k_mega<<<213, 640, 0, stream>>>(sent,
                                  mWih_f, mWhh_f, mWih_b, mWhh_b,
                                  mbih_f, mbhh_f, mbih_b, mbhh_b,
                                  hWih_f, hWhh_f, hWih_b, hWhh_b, Wp,
                                  Wq, bq, Wv, bv,
                                  rnn16, bpack, bpackL, ptpack,
                                  ws + OFF_U, ws + OFF_W, ws + OFF_C0, ws + OFF_ACC);
  k_hier_mfma<<<512, 512, 0, stream>>>(rnn16, bpack,
                                       hbih_f, hbhh_f, hbih_b, hbhh_b, hv16);
  k_attn_ctx<<<512, 256, 0, stream>>>(hv16, ptpack, ws + OFF_U, ws + OFF_W,
                                      ws + OFF_C0, Wp, bp, Wk, bk,
                                      ws + OFF_CLOG, ws + OFF_KSLOGP);
  k_loss_mfma<<<512, 256, 0, stream>>>(rnn16, bpackL, ws + OFF_CLOG, ws + OFF_KSLOGP,
                                       pitches, kss, ws + OFF_ACC, out);
}